// Round 11
// baseline (33115.149 us; speedup 1.0000x reference)
//
#include <hip/hip_runtime.h>
#include <hip/hip_bf16.h>
#include <math.h>

// ---------------------------------------------------------------------------
// FreqCA: B=8, C=256, H=W=128, NHEADS=8, GROUPS=32.
// Front end (GN -> dw -> pw -> l2norm -> rfft2 -> amp/phase) in FULL fp64
// (correctness-critical: phase softmax is winner-take-all; self-conjugate
// rfft2 bins forced to im=+0.0 to match pocketfft's exact-zero convention).
// Round 11 change: tail convs (ao/f1/f2/f3) moved from fp32 VALU GEMM
// (~32 TF, MfmaUtil=0) to bf16 MFMA implicit GEMM (fp32 accumulate).
// Layout identical to round 10 (168.8 MB per batch, NB adaptive).
// ---------------------------------------------------------------------------

#define TWO_PI_D 6.283185307179586476925286766559
#define ATTN_SCALE_D 0.17677669529663688110021109052621  // 1/sqrt(32)

typedef __attribute__((ext_vector_type(8))) short short8;
typedef __attribute__((ext_vector_type(4))) float f32x4;

__device__ inline short f2bf(float f) {
    __hip_bfloat16 h = __float2bfloat16(f);
    return *reinterpret_cast<short*>(&h);
}

// ---------------- GroupNorm fp64: one block per (lb,g) ---------------------
__global__ __launch_bounds__(256) void gn64_kernel(
    const float* __restrict__ x, const float* __restrict__ gw,
    const float* __restrict__ gb, double* __restrict__ out, int b0)
{
    int t = threadIdx.x;
    int lb = blockIdx.x >> 5;
    int g  = blockIdx.x & 31;
    size_t src = ((size_t)(b0 + lb) * 32 + g) * 131072;
    size_t dst = (size_t)blockIdx.x * 131072;
    const float* xp = x + src;
    double s = 0.0, ss = 0.0;
    for (int i = t; i < 131072; i += 256) { double v = xp[i]; s += v; ss += v*v; }
    __shared__ double rs[256], rss[256];
    rs[t] = s; rss[t] = ss;
    __syncthreads();
    for (int k = 128; k > 0; k >>= 1) {
        if (t < k) { rs[t] += rs[t+k]; rss[t] += rss[t+k]; }
        __syncthreads();
    }
    double mean = rs[0] * (1.0/131072.0);
    double inv  = 1.0 / sqrt(rss[0] * (1.0/131072.0) - mean*mean + 1e-5);
    for (int i = t; i < 131072; i += 256) {
        int c = (g << 3) + (i >> 14);
        out[dst + i] = ((double)xp[i] - mean) * inv * (double)gw[c] + (double)gb[c];
    }
}

// ---------------- Depthwise 3x3 fp64 ---------------------------------------
__global__ __launch_bounds__(256) void dw64_kernel(
    const double* __restrict__ in, const float* __restrict__ w,
    double* __restrict__ out)
{
    int t = threadIdx.x;
    int bc = blockIdx.x >> 6;
    int y  = ((blockIdx.x & 63) << 1) + (t >> 7);
    int x  = t & 127;
    int c  = bc & 255;
    double wp[9];
    #pragma unroll
    for (int i = 0; i < 9; i++) wp[i] = (double)w[c*9 + i];
    const double* ip = in + ((size_t)bc << 14);
    double acc = 0.0;
    #pragma unroll
    for (int dy = 0; dy < 3; dy++) {
        int yy = y + dy - 1;
        if (yy < 0 || yy > 127) continue;
        const double* row = ip + (yy << 7);
        #pragma unroll
        for (int dx = 0; dx < 3; dx++) {
            int xx = x + dx - 1;
            if (xx >= 0 && xx <= 127) acc += wp[dy*3+dx] * row[xx];
        }
    }
    out[((size_t)bc << 14) + (y << 7) + x] = acc;
}

// ---------------- fp64 1x1-conv GEMM: 64co x 64px tile, Cin=256 ------------
__global__ __launch_bounds__(256) void gemm64_kernel(
    const double* __restrict__ X, const float* __restrict__ W,
    const float* __restrict__ bias, double* __restrict__ C)
{
    int pBase  = blockIdx.x << 6;
    int coBase = blockIdx.y << 6;
    int lb = blockIdx.z;
    int t = threadIdx.x;
    int pxL = (t & 15) << 2;
    int coL = (t >> 4) << 2;
    __shared__ double Ws[16][64];
    __shared__ double Xs[16][66];
    double acc[4][4];
    #pragma unroll
    for (int i = 0; i < 4; i++)
        #pragma unroll
        for (int j = 0; j < 4; j++) acc[i][j] = 0.0;
    size_t xb = ((size_t)lb * 256) << 14;
    for (int k0 = 0; k0 < 256; k0 += 16) {
        __syncthreads();
        for (int i = t; i < 1024; i += 256) {
            int k = i >> 6, co = i & 63;
            Ws[k][co] = (double)W[(size_t)(coBase+co)*256 + k0 + k];
        }
        for (int i = t; i < 1024; i += 256) {
            int k = i >> 6, px = i & 63;
            Xs[k][px] = X[xb + (((size_t)(k0+k)) << 14) + pBase + px];
        }
        __syncthreads();
        for (int k = 0; k < 16; k++) {
            #pragma unroll
            for (int i = 0; i < 4; i++) {
                double wv = Ws[k][coL+i];
                #pragma unroll
                for (int j = 0; j < 4; j++) acc[i][j] += wv * Xs[k][pxL+j];
            }
        }
    }
    #pragma unroll
    for (int i = 0; i < 4; i++) {
        int co = coBase + coL + i;
        double vb = (double)bias[co];
        size_t ob = (((size_t)(lb*256 + co)) << 14) + pBase + pxL;
        #pragma unroll
        for (int j = 0; j < 4; j++) C[ob + j] = acc[i][j] + vb;
    }
}

// ---------------- L2 norm over 256 channels fp64, in place -----------------
__global__ __launch_bounds__(256) void l2n64_kernel(double* __restrict__ q)
{
    int p  = ((blockIdx.x & 63) << 8) + threadIdx.x;
    int lb = blockIdx.x >> 6;
    double* base = q + (((size_t)lb * 256) << 14) + p;
    double ss = 0.0;
    for (int c = 0; c < 256; c++) { double v = base[(size_t)c << 14]; ss += v*v; }
    double inv = 1.0 / fmax(sqrt(ss), 1e-12);
    for (int c = 0; c < 256; c++) base[(size_t)c << 14] *= inv;
}

// ---------------- Forward FFT stage 1 fp64: row DFT ------------------------
__global__ __launch_bounds__(256) void fftrow64_kernel(
    const double* __restrict__ in, double* __restrict__ rre,
    double* __restrict__ rim, int chunkBase)
{
    int rc  = blockIdx.x;          // 16-row chunk 0..7
    int loc = blockIdx.y;          // chunk-local plane
    int gp  = chunkBase + loc;
    int t   = threadIdx.x;
    __shared__ double xs[16][128];
    __shared__ double ct[128], st[128];
    if (t < 128) { double s, c; sincos(TWO_PI_D * t / 128.0, &s, &c); st[t]=s; ct[t]=c; }
    const double* src = in + ((size_t)gp << 14) + ((size_t)rc << 11);
    for (int i = t; i < 2048; i += 256) ((double*)xs)[i] = src[i];
    __syncthreads();
    for (int o = t; o < 1040; o += 256) {
        int r = o / 65, k = o - r*65;
        const double* xr = xs[r];
        double re = 0.0, im = 0.0;
        int m = 0;
        for (int w = 0; w < 128; w++) {
            double xv = xr[w];
            re += xv * ct[m];
            im -= xv * st[m];
            m = (m + k) & 127;
        }
        size_t oi = ((size_t)loc*128 + rc*16 + r)*65 + k;
        rre[oi] = re * 0.0078125;
        rim[oi] = im * 0.0078125;
    }
}

// ---------------- Forward FFT stage 2 fp64 -> fp32 amp/phase slots ---------
__global__ __launch_bounds__(256) void fftcol64_kernel(
    const double* __restrict__ rre, const double* __restrict__ rim,
    float* __restrict__ ampSlot, float* __restrict__ phSlot, int chunkBase)
{
    int kb  = blockIdx.x * 13;
    int loc = blockIdx.y;
    int gp  = chunkBase + loc;     // plane index within slot
    int t   = threadIdx.x;
    __shared__ double cr[128][13], ci[128][13];
    __shared__ double ct[128], st[128];
    if (t < 128) { double s, c; sincos(TWO_PI_D * t / 128.0, &s, &c); st[t]=s; ct[t]=c; }
    for (int i = t; i < 1664; i += 256) {
        int r = i / 13, k = i - r*13;
        size_t si = ((size_t)loc*128 + r)*65 + kb + k;
        cr[r][k] = rre[si];
        ci[r][k] = rim[si];
    }
    __syncthreads();
    float* aD = ampSlot + (size_t)gp * 8320;
    float* pD = phSlot  + (size_t)gp * 8320;
    for (int o = t; o < 1664; o += 256) {
        int k1 = o / 13, k = o - k1*13;
        double re = 0.0, im = 0.0;
        int m = 0;
        for (int r = 0; r < 128; r++) {
            double cc = ct[m], sn = st[m];
            double a = cr[r][k], b = ci[r][k];
            re += a*cc + b*sn;
            im += b*cc - a*sn;
            m = (m + k1) & 127;
        }
        int kxv = kb + k;
        // Self-conjugate bins of rfft2: im is structurally zero. pocketfft
        // yields exact +-0.0 -> angle in {0, +pi}; our sincos twiddles leak
        // ~1e-16 random-signed garbage -> atan2 flips to -pi. Force +0.0.
        if ((k1 == 0 || k1 == 64) && (kxv == 0 || kxv == 64)) im = 0.0;
        int oi = k1*65 + kxv;
        aD[oi] = (float)sqrt(re*re + im*im);
        pD[oi] = (float)atan2(im, re);
    }
}

// ---------------- Fused channel attention: fp32 in, fp64 accum -------------
__global__ __launch_bounds__(256) void attn_fused_kernel(
    const float* __restrict__ qA, const float* __restrict__ kA,
    const float* __restrict__ vA, float* __restrict__ outA)
{
    int bh = blockIdx.x;
    int t  = threadIdx.x;
    const float* qb = qA + (size_t)bh * 32 * 8320;
    const float* kb = kA + (size_t)bh * 32 * 8320;
    const float* vb = vA + (size_t)bh * 32 * 8320;
    float* ob       = outA + (size_t)bh * 32 * 8320;

    __shared__ float qs[32][65], ks[32][65];
    __shared__ double simsh[32][33];

    double acc[4] = {0.0, 0.0, 0.0, 0.0};
    for (int nc = 0; nc < 130; nc++) {
        int n0 = nc * 64;
        for (int i = t; i < 2048; i += 256) {
            int r = i >> 6, c = i & 63;
            qs[r][c] = qb[(size_t)r*8320 + n0 + c];
            ks[r][c] = kb[(size_t)r*8320 + n0 + c];
        }
        __syncthreads();
        #pragma unroll
        for (int e = 0; e < 4; e++) {
            int p4 = t + (e << 8);
            int j = p4 >> 5, k = p4 & 31;
            double a = acc[e];
            #pragma unroll 8
            for (int c = 0; c < 64; c++) a += (double)qs[j][c] * (double)ks[k][c];
            acc[e] = a;
        }
        __syncthreads();
    }
    #pragma unroll
    for (int e = 0; e < 4; e++) {
        int p4 = t + (e << 8);
        simsh[p4 >> 5][p4 & 31] = acc[e] * ATTN_SCALE_D;
    }
    __syncthreads();
    if (t < 32) {
        double m = -1e300;
        for (int k = 0; k < 32; k++) m = fmax(m, simsh[t][k]);
        double s = 0.0;
        for (int k = 0; k < 32; k++) s += exp(simsh[t][k] - m);
        double inv = 1.0 / s;
        for (int k = 0; k < 32; k++) simsh[t][k] = exp(simsh[t][k] - m) * inv;
    }
    __syncthreads();
    for (int n = t; n < 8320; n += 256) {
        float vv[32];
        #pragma unroll
        for (int k = 0; k < 32; k++) vv[k] = vb[(size_t)k*8320 + n];
        for (int j = 0; j < 32; j++) {
            double o = 0.0;
            #pragma unroll
            for (int k = 0; k < 32; k++) o += simsh[j][k] * (double)vv[k];
            ob[(size_t)j*8320 + n] = (float)o;
        }
    }
}

// ---------------- Inverse FFT stage 1 (fp64, e^{+i}) -----------------------
__global__ __launch_bounds__(256) void ifft_col_kernel(
    const float* __restrict__ ampo, const float* __restrict__ pho,
    double* __restrict__ tre, double* __restrict__ tim)
{
    int kb    = blockIdx.x * 13;
    int plane = blockIdx.y;
    int t     = threadIdx.x;
    __shared__ double cr[128][13], cim[128][13];
    __shared__ double ct[128], st[128];
    if (t < 128) { double s, c; sincos(TWO_PI_D * t / 128.0, &s, &c); st[t]=s; ct[t]=c; }
    const float* ab = ampo + (size_t)plane * 8320;
    const float* pb = pho  + (size_t)plane * 8320;
    for (int i = t; i < 1664; i += 256) {
        int k1 = i / 13, k = i - k1*13;
        double a = ab[k1*65 + kb + k];
        double p = pb[k1*65 + kb + k];
        double sp, cp; sincos(p, &sp, &cp);
        cr[k1][k]  = a * cp;
        cim[k1][k] = a * sp;
    }
    __syncthreads();
    for (int o = t; o < 1664; o += 256) {
        int y = o / 13, k = o - y*13;
        double re = 0.0, im = 0.0;
        int m = 0;
        for (int k1 = 0; k1 < 128; k1++) {
            double c = ct[m], s = st[m];
            double a = cr[k1][k], bb = cim[k1][k];
            re += a*c - bb*s;
            im += a*s + bb*c;
            m = (m + y) & 127;
        }
        size_t oi = ((size_t)plane*128 + y)*65 + kb + k;
        tre[oi] = re;
        tim[oi] = im;
    }
}

// ---------------- Inverse FFT stage 2: Hermitian rows (fp64 -> fp32) -------
__global__ __launch_bounds__(256) void ifft_row_kernel(
    const double* __restrict__ tre, const double* __restrict__ tim,
    float* __restrict__ spat)
{
    int rc    = blockIdx.x;
    int plane = blockIdx.y;
    int t     = threadIdx.x;
    __shared__ double tr[16][65], ti[16][65];
    __shared__ double ct[128], st[128];
    if (t < 128) { double s, c; sincos(TWO_PI_D * t / 128.0, &s, &c); st[t]=s; ct[t]=c; }
    for (int i = t; i < 1040; i += 256) {
        int r = i / 65, k = i - r*65;
        size_t si = ((size_t)plane*128 + rc*16 + r)*65 + k;
        tr[r][k] = tre[si];
        ti[r][k] = tim[si];
    }
    __syncthreads();
    for (int o = t; o < 2048; o += 256) {
        int r = o >> 7, x = o & 127;
        double acc = tr[r][0];
        int m = x;
        for (int k = 1; k < 64; k++) {
            acc += 2.0 * (tr[r][k]*ct[m] - ti[r][k]*st[m]);
            m = (m + x) & 127;
        }
        acc += tr[r][64]*ct[m] - ti[r][64]*st[m];
        spat[((size_t)plane << 14) + ((rc*16 + r) << 7) + x] = (float)(acc * 0.0078125);
    }
}

// ---------------- cast fp64 -> fp32 ----------------------------------------
__global__ void cast_d2f_kernel(const double* __restrict__ in,
                                float* __restrict__ out, size_t n)
{
    size_t i = (size_t)blockIdx.x * 256 + threadIdx.x;
    size_t stride = (size_t)gridDim.x * 256;
    for (; i < n; i += stride) out[i] = (float)in[i];
}

// ---------------- bf16 MFMA implicit-GEMM conv (tail) ----------------------
// out[co][p] = act(bias[co] + sum_k W[co][k] * X[k][p]) + res
// 128x128 tile, 4 waves x (64x64 via 4x4 16x16x32 fragments), fp32 accum.
// A (weights) LDS [co][kk] k-contiguous; B (im2col) LDS [px][kk]; pad to
// 40 shorts (80B rows, 16B-aligned, ~2-way bank conflicts on ds_read_b128).
template<int R>
__global__ __launch_bounds__(256) void convmf_kernel(
    const float* __restrict__ in, const float* __restrict__ wt,
    const float* __restrict__ bias, const float* __restrict__ res,
    float* __restrict__ out, int Cin, int Cout, int act,
    int in_b0, int res_b0, int out_b0)
{
    const int K = Cin * R * R;
    int pBase  = blockIdx.x << 7;
    int coBase = blockIdx.y << 7;
    int lb = blockIdx.z;
    int t = threadIdx.x;
    int lane = t & 63;
    int wave = t >> 6;
    int wm = (wave >> 1) << 6;     // wave M (co) offset in block
    int wn = (wave & 1) << 6;      // wave N (px) offset

    __shared__ short As[128][40];  // [co][kk]
    __shared__ short Bs[128][40];  // [px][kk]

    f32x4 acc[4][4];
    #pragma unroll
    for (int i = 0; i < 4; i++)
        #pragma unroll
        for (int j = 0; j < 4; j++) acc[i][j] = (f32x4){0.f, 0.f, 0.f, 0.f};

    const size_t inb = ((size_t)(in_b0 + lb) * Cin) << 14;
    int lr = lane & 15;            // row/col within 16-group
    int kg = (lane >> 4) << 3;     // k offset: 0,8,16,24

    for (int k0 = 0; k0 < K; k0 += 32) {
        __syncthreads();
        // stage A: 128co x 32kk (global: 32-contig runs per co -> coalesced)
        for (int i = t; i < 4096; i += 256) {
            int co = i >> 5, kk = i & 31;
            As[co][kk] = f2bf(wt[(size_t)(coBase + co) * K + k0 + kk]);
        }
        // stage B: 32kk x 128px -> Bs[px][kk] (global: 128-contig per kk row)
        for (int i = t; i < 4096; i += 256) {
            int kr = i >> 7, px = i & 127;
            int k = k0 + kr;
            float v;
            if (R == 3) {
                int ci = k / 9; int rr = k - ci*9; int dy = rr / 3; int dx = rr - dy*3;
                int pg = pBase + px;
                int yy = (pg >> 7) + dy - 1;
                int xx = (pg & 127) + dx - 1;
                v = (yy >= 0 && yy < 128 && xx >= 0 && xx < 128)
                    ? in[inb + ((size_t)ci << 14) + (yy << 7) + xx] : 0.f;
            } else {
                v = in[inb + ((size_t)k << 14) + pBase + px];
            }
            Bs[px][kr] = f2bf(v);
        }
        __syncthreads();
        short8 af[4], bf[4];
        #pragma unroll
        for (int i = 0; i < 4; i++)
            af[i] = *(const short8*)&As[wm + i*16 + lr][kg];
        #pragma unroll
        for (int j = 0; j < 4; j++)
            bf[j] = *(const short8*)&Bs[wn + j*16 + lr][kg];
        #pragma unroll
        for (int i = 0; i < 4; i++)
            #pragma unroll
            for (int j = 0; j < 4; j++)
                acc[i][j] = __builtin_amdgcn_mfma_f32_16x16x32_bf16(
                    af[i], bf[j], acc[i][j], 0, 0, 0);
    }

    // epilogue: D[m][n] -> m=(lane>>4)*4+r, n=lane&15 per 16x16 fragment
    int mr = (lane >> 4) << 2;
    #pragma unroll
    for (int i = 0; i < 4; i++) {
        #pragma unroll
        for (int r = 0; r < 4; r++) {
            int co = coBase + wm + i*16 + mr + r;
            float vb = bias ? bias[co] : 0.f;
            size_t rowo = (((size_t)(out_b0 + lb) * Cout + co) << 14);
            size_t rowr = (((size_t)(res_b0 + lb) * Cout + co) << 14);
            #pragma unroll
            for (int j = 0; j < 4; j++) {
                int px = pBase + wn + j*16 + lr;
                float v = acc[i][j][r] + vb;
                if (act == 1) v = v / (1.f + expf(-v));
                if (res) v += res[rowr + px];
                out[rowo + px] = v;
            }
        }
    }
}

// ---------------------------------------------------------------------------
extern "C" void kernel_launch(void* const* d_in, const int* in_sizes, int n_in,
                              void* d_out, int out_size, void* d_ws, size_t ws_size,
                              hipStream_t stream) {
    (void)in_sizes; (void)n_in; (void)out_size;
    const float* x    = (const float*)d_in[0];
    const float* gn_w = (const float*)d_in[1];
    const float* gn_b = (const float*)d_in[2];
    const float* dw_w = (const float*)d_in[3];
    const float* pw_w = (const float*)d_in[4];
    const float* pw_b = (const float*)d_in[5];
    const float* ao_w = (const float*)d_in[6];
    const float* ao_b = (const float*)d_in[7];
    const float* f1_w = (const float*)d_in[8];
    const float* f2_w = (const float*)d_in[9];
    const float* f3_w = (const float*)d_in[10];
    const float* f3_b = (const float*)d_in[11];
    float* outp = (float*)d_out;

    // per-batch region sizes in float-equivalents
    const size_t F_XND  = 8388608;    // xn_d (doubles)
    const size_t F_B    = 8388608;    // dw_d -> spat + xn_f
    const size_t F_C    = 8388608;    // qkvT_d -> h1
    const size_t F_SLOT = 2129920;    // fp32 spec slot
    const size_t F_SPEC = 6 * F_SLOT; // 12,779,520
    const size_t F_E    = 4259840;    // rre/rim doubles -> h2
    const size_t F_TOT  = F_XND + F_B + F_C + F_SPEC + F_E; // 42,205,184

    int NB = 0;
    for (int cand : {8, 4, 2, 1}) {
        if ((size_t)cand * F_TOT * 4 <= ws_size) { NB = cand; break; }
    }
    if (NB == 0) return;   // workspace too small: clean failure, no OOB crash

    float*  wsf  = (float*)d_ws;
    double* xn_d = (double*)wsf;                               // [A]
    float*  Breg = wsf + (size_t)NB * F_XND;                   // [B]
    double* dw_d = (double*)Breg;
    float*  spat = Breg;                                       // lower half of B
    float*  xn_f = Breg + (size_t)NB * 4194304;                // upper half of B
    float*  Creg = Breg + (size_t)NB * F_B;                    // [C]
    double* qkvT = (double*)Creg;
    float*  h1   = Creg;
    float*  spec = Creg + (size_t)NB * F_C;                    // [D]
    size_t  ss   = (size_t)NB * F_SLOT;
    double* tre  = (double*)(spec + 2*ss);                     // slots 2-3
    double* tim  = (double*)(spec + 4*ss);                     // slots 4-5
    float*  Ereg = spec + 6*ss;                                // [E]
    double* rre  = (double*)Ereg;
    double* rim  = rre + (size_t)NB * 1064960;                 // NB*128*8320
    float*  h2   = Ereg;

    const int passes = 8 / NB;
    for (int p = 0; p < passes; p++) {
        int b0 = p * NB;
        // 1. GroupNorm fp64 -> xn_d
        gn64_kernel<<<NB*32, 256, 0, stream>>>(x, gn_w, gn_b, xn_d, b0);
        // 2. depthwise 3x3 fp64 -> dw_d
        dw64_kernel<<<NB*256*64, 256, 0, stream>>>(xn_d, dw_w, dw_d);
        // 3. per-T: pointwise fp64 GEMM -> qkvT_d, l2norm fp64, rfft2 fp64
        for (int T = 0; T < 3; T++) {
            gemm64_kernel<<<dim3(256, 4, NB), 256, 0, stream>>>(
                dw_d, pw_w + (size_t)T*65536, pw_b + T*256, qkvT);
            l2n64_kernel<<<NB*64, 256, 0, stream>>>(qkvT);
            for (int chunk = 0; chunk < 2; chunk++) {
                fftrow64_kernel<<<dim3(8, NB*128), 256, 0, stream>>>(
                    qkvT, rre, rim, chunk*NB*128);
                fftcol64_kernel<<<dim3(5, NB*128), 256, 0, stream>>>(
                    rre, rim, spec + (size_t)(2*T)*ss, spec + (size_t)(2*T+1)*ss,
                    chunk*NB*128);
            }
        }
        // 4. channel attention: amp (0,2,4 -> 0), phase (1,3,5 -> 1)
        attn_fused_kernel<<<NB*8, 256, 0, stream>>>(spec + 0*ss, spec + 2*ss,
                                                    spec + 4*ss, spec + 0*ss);
        attn_fused_kernel<<<NB*8, 256, 0, stream>>>(spec + 1*ss, spec + 3*ss,
                                                    spec + 5*ss, spec + 1*ss);
        // 5. irfft2: slots 0,1 -> tre/tim (slots 2-5) -> spat
        ifft_col_kernel<<<dim3(5, NB*256), 256, 0, stream>>>(spec + 0*ss, spec + 1*ss,
                                                             tre, tim);
        ifft_row_kernel<<<dim3(8, NB*256), 256, 0, stream>>>(tre, tim, spat);
        // 6. cast xn_d -> xn_f for the ao residual
        cast_d2f_kernel<<<2048, 256, 0, stream>>>(xn_d, xn_f, (size_t)NB * 4194304);
        // 7. ao 1x1 (+bias) + xn residual -> attn (in d_out)   [bf16 MFMA]
        convmf_kernel<1><<<dim3(128, 2, NB), 256, 0, stream>>>(
            spat, ao_w, ao_b, xn_f, outp, 256, 256, 0, 0, 0, b0);
        // 8. f1 3x3 256->512 + SiLU                            [bf16 MFMA]
        convmf_kernel<3><<<dim3(128, 4, NB), 256, 0, stream>>>(
            outp, f1_w, nullptr, nullptr, h1, 256, 512, 1, b0, 0, 0);
        // 9. f2 3x3 512->256                                   [bf16 MFMA]
        convmf_kernel<3><<<dim3(128, 2, NB), 256, 0, stream>>>(
            h1, f2_w, nullptr, nullptr, h2, 512, 256, 0, 0, 0, 0);
        // 10. f3 1x1 (+bias) + attn residual, in place         [bf16 MFMA]
        convmf_kernel<1><<<dim3(128, 2, NB), 256, 0, stream>>>(
            h2, f3_w, f3_b, outp, outp, 256, 256, 0, 0, b0, b0);
    }
}

// Round 12
// 15668.629 us; speedup vs baseline: 2.1135x; 2.1135x over previous
//
#include <hip/hip_runtime.h>
#include <hip/hip_bf16.h>
#include <math.h>

// ---------------------------------------------------------------------------
// FreqCA: B=8, C=256, H=W=128, NHEADS=8, GROUPS=32.
// Round 12: front end back to fp32 (rounds 3-8 proved fp32 vs fp64 output
// is bit-identical in bf16 space -- the only correctness-critical item is the
// +-pi convention at the 4 self-conjugate rfft2 bins, handled via im=+0.0).
// Attention logits/softmax stay fp64 (winner-take-all), split-K parallel.
// Tail convs (ao/f1/f2/f3) bf16 MFMA.
// Per-batch float layout (NB adaptive):
//   qkv  12,582,912  (later h1 8,388,608 + h2 4,194,304)
//   spec 6 x 2,129,920  (slot2->tre, slot3->tim, slots4-5->spat after attn)
//   xn    4,194,304
//   ebuf  6,389,760  (dw 4,194,304 -> rre/rim 2 x 3,194,880)
//   simp    262,144  (131,072 doubles)
// total 36,208,640 floats = 144.8 MB per batch
// ---------------------------------------------------------------------------

#define TWO_PI_D 6.283185307179586476925286766559
#define ATTN_SCALE_D 0.17677669529663688110021109052621  // 1/sqrt(32)

typedef __attribute__((ext_vector_type(8))) short short8;
typedef __attribute__((ext_vector_type(4))) float f32x4;

__device__ inline short f2bf(float f) {
    __hip_bfloat16 h = __float2bfloat16(f);
    return *reinterpret_cast<short*>(&h);
}

// ---------------- GroupNorm: fp64 stats, fp32 out --------------------------
__global__ __launch_bounds__(256) void groupnorm_kernel(
    const float* __restrict__ x, const float* __restrict__ gw,
    const float* __restrict__ gb, float* __restrict__ out, int b0)
{
    int t = threadIdx.x;
    int lb = blockIdx.x >> 5;
    int g  = blockIdx.x & 31;
    size_t src = ((size_t)(b0 + lb) * 32 + g) * 131072;
    size_t dst = (size_t)blockIdx.x * 131072;
    const float* xp = x + src;
    double s = 0.0, ss = 0.0;
    for (int i = t; i < 131072; i += 256) { double v = xp[i]; s += v; ss += v*v; }
    __shared__ double rs[256], rss[256];
    rs[t] = s; rss[t] = ss;
    __syncthreads();
    for (int k = 128; k > 0; k >>= 1) {
        if (t < k) { rs[t] += rs[t+k]; rss[t] += rss[t+k]; }
        __syncthreads();
    }
    __shared__ float smean, sinv;
    if (t == 0) {
        double mean = rs[0] * (1.0/131072.0);
        double var  = rss[0] * (1.0/131072.0) - mean*mean;
        smean = (float)mean;
        sinv  = (float)(1.0 / sqrt(var + 1e-5));
    }
    __syncthreads();
    float mean = smean, inv = sinv;
    for (int i = t; i < 131072; i += 256) {
        int c = (g << 3) + (i >> 14);
        out[dst + i] = (xp[i] - mean) * inv * gw[c] + gb[c];
    }
}

// ---------------- Depthwise 3x3 fp32 ---------------------------------------
__global__ __launch_bounds__(256) void dwconv_kernel(
    const float* __restrict__ in, const float* __restrict__ w, float* __restrict__ out)
{
    int t = threadIdx.x;
    int bc = blockIdx.x >> 6;
    int y  = ((blockIdx.x & 63) << 1) + (t >> 7);
    int x  = t & 127;
    int c  = bc & 255;
    const float* wp = w + c*9;
    const float* ip = in + ((size_t)bc << 14);
    float acc = 0.f;
    #pragma unroll
    for (int dy = 0; dy < 3; dy++) {
        int yy = y + dy - 1;
        if (yy < 0 || yy > 127) continue;
        const float* row = ip + (yy << 7);
        #pragma unroll
        for (int dx = 0; dx < 3; dx++) {
            int xx = x + dx - 1;
            if (xx >= 0 && xx <= 127) acc += wp[dy*3+dx] * row[xx];
        }
    }
    out[((size_t)bc << 14) + (y << 7) + x] = acc;
}

// ---------------- fp32 tiled implicit-GEMM conv (pw) -----------------------
template<int R>
__global__ __launch_bounds__(256) void conv_kernel(
    const float* __restrict__ in, const float* __restrict__ wt,
    const float* __restrict__ bias, const float* __restrict__ res,
    float* __restrict__ out, int Cin, int Cout, int act,
    int in_b0, int res_b0, int out_b0)
{
    const int K = Cin * R * R;
    int pBase  = blockIdx.x << 7;
    int coBase = blockIdx.y << 7;
    int lb = blockIdx.z;
    int t = threadIdx.x;
    int tx = t & 15, ty = t >> 4;

    __shared__ float As[8][128];
    __shared__ float Bs[8][128];

    float acc[8][8];
    #pragma unroll
    for (int i = 0; i < 8; i++)
        #pragma unroll
        for (int j = 0; j < 8; j++) acc[i][j] = 0.f;

    int a_co = t >> 1;
    int a_k  = (t & 1) << 2;
    int b_k  = t >> 5;
    int b_p  = (t & 31) << 2;
    const float* wrow = wt + (size_t)(coBase + a_co) * K + a_k;
    const size_t inb = ((size_t)(in_b0 + lb) * Cin) << 14;

    for (int k0 = 0; k0 < K; k0 += 8) {
        float4 av = *(const float4*)(wrow + k0);
        int kk = k0 + b_k;
        float4 bv;
        if (R == 3) {
            int ci = kk / 9; int rr = kk - ci*9; int dy = rr / 3; int dx = rr - dy*3;
            const float* ip = in + inb + ((size_t)ci << 14);
            float tmp[4];
            #pragma unroll
            for (int j = 0; j < 4; j++) {
                int pg = pBase + b_p + j;
                int yy = (pg >> 7) + dy - 1;
                int xx = (pg & 127) + dx - 1;
                tmp[j] = (yy >= 0 && yy < 128 && xx >= 0 && xx < 128) ? ip[(yy << 7) + xx] : 0.f;
            }
            bv = make_float4(tmp[0], tmp[1], tmp[2], tmp[3]);
        } else {
            bv = *(const float4*)(in + inb + ((size_t)kk << 14) + pBase + b_p);
        }
        __syncthreads();
        As[a_k+0][a_co] = av.x; As[a_k+1][a_co] = av.y;
        As[a_k+2][a_co] = av.z; As[a_k+3][a_co] = av.w;
        *(float4*)&Bs[b_k][b_p] = bv;
        __syncthreads();
        #pragma unroll
        for (int k2 = 0; k2 < 8; k2++) {
            float4 A1 = *(const float4*)&As[k2][ty << 2];
            float4 A2 = *(const float4*)&As[k2][64 + (ty << 2)];
            float4 B1 = *(const float4*)&Bs[k2][tx << 2];
            float4 B2 = *(const float4*)&Bs[k2][64 + (tx << 2)];
            float a0[8] = {A1.x,A1.y,A1.z,A1.w,A2.x,A2.y,A2.z,A2.w};
            float b0v[8] = {B1.x,B1.y,B1.z,B1.w,B2.x,B2.y,B2.z,B2.w};
            #pragma unroll
            for (int i = 0; i < 8; i++)
                #pragma unroll
                for (int j = 0; j < 8; j++) acc[i][j] += a0[i] * b0v[j];
        }
    }

    #pragma unroll
    for (int i = 0; i < 8; i++) {
        int co = coBase + ((i < 4) ? ((ty << 2) + i) : (64 + (ty << 2) + i - 4));
        size_t rbo = (((size_t)(out_b0 + lb) * Cout + co) << 14) + pBase;
        size_t rbr = (((size_t)(res_b0 + lb) * Cout + co) << 14) + pBase;
        float vb = bias ? bias[co] : 0.f;
        #pragma unroll
        for (int jh = 0; jh < 2; jh++) {
            int colo = (jh == 0) ? (tx << 2) : (64 + (tx << 2));
            float4 v;
            v.x = acc[i][jh*4+0] + vb;
            v.y = acc[i][jh*4+1] + vb;
            v.z = acc[i][jh*4+2] + vb;
            v.w = acc[i][jh*4+3] + vb;
            if (act == 1) {
                v.x = v.x / (1.f + expf(-v.x));
                v.y = v.y / (1.f + expf(-v.y));
                v.z = v.z / (1.f + expf(-v.z));
                v.w = v.w / (1.f + expf(-v.w));
            }
            if (res) {
                float4 r4 = *(const float4*)(res + rbr + colo);
                v.x += r4.x; v.y += r4.y; v.z += r4.z; v.w += r4.w;
            }
            *(float4*)(out + rbo + colo) = v;
        }
    }
}

// ---------------- L2 norm over channel dim (fp64 accum, fp32 data) ---------
__global__ __launch_bounds__(256) void l2norm_kernel(float* __restrict__ qkv)
{
    int p  = ((blockIdx.x & 63) << 8) + threadIdx.x;
    int bT = blockIdx.x >> 6;
    int lb = bT / 3, T = bT - 3*lb;
    float* base = qkv + (((size_t)(lb*768 + T*256)) << 14) + p;
    double ss = 0.0;
    for (int c = 0; c < 256; c++) { double v = base[(size_t)c << 14]; ss += v*v; }
    float inv = 1.f / fmaxf((float)sqrt(ss), 1e-12f);
    for (int c = 0; c < 256; c++) base[(size_t)c << 14] *= inv;
}

// ---------------- Forward FFT stage 1: fp32 row DFT ------------------------
__global__ __launch_bounds__(256) void fft_row_kernel(
    const float* __restrict__ in, float* __restrict__ rre, float* __restrict__ rim,
    int chunkBase)
{
    int rc  = blockIdx.x;          // 16-row chunk 0..7
    int loc = blockIdx.y;          // chunk-local plane
    int gp  = chunkBase + loc;
    int t   = threadIdx.x;
    __shared__ float xs[16][128];
    __shared__ float ct[128], st[128];
    if (t < 128) { double s, c; sincos(TWO_PI_D * t / 128.0, &s, &c);
                   st[t] = (float)s; ct[t] = (float)c; }
    const float4* src = (const float4*)(in + ((size_t)gp << 14) + ((size_t)rc << 11));
    float4* xd = (float4*)xs;
    for (int i = t; i < 512; i += 256) xd[i] = src[i];
    __syncthreads();
    for (int o = t; o < 1040; o += 256) {
        int r = o / 65, k = o - r*65;
        const float* xr = xs[r];
        float re = 0.f, im = 0.f;
        int m = 0;
        for (int w = 0; w < 128; w++) {
            float xv = xr[w];
            re += xv * ct[m];
            im -= xv * st[m];
            m = (m + k) & 127;
        }
        size_t oi = ((size_t)loc*128 + rc*16 + r)*65 + k;
        rre[oi] = re * 0.0078125f;
        rim[oi] = im * 0.0078125f;
    }
}

// ---------------- Forward FFT stage 2: fp32 col DFT -> amp/phase -----------
__global__ __launch_bounds__(256) void fft_col_kernel(
    const float* __restrict__ rre, const float* __restrict__ rim,
    float* __restrict__ spec, int chunkBase, size_t slotStride)
{
    int kb  = blockIdx.x * 13;
    int loc = blockIdx.y;
    int gp  = chunkBase + loc;
    int t   = threadIdx.x;
    __shared__ float cr[128][13], ci[128][13];
    __shared__ float ct[128], st[128];
    if (t < 128) { double s, c; sincos(TWO_PI_D * t / 128.0, &s, &c);
                   st[t] = (float)s; ct[t] = (float)c; }
    for (int i = t; i < 1664; i += 256) {
        int r = i / 13, k = i - r*13;
        size_t si = ((size_t)loc*128 + r)*65 + kb + k;
        cr[r][k] = rre[si];
        ci[r][k] = rim[si];
    }
    __syncthreads();
    int lb = gp / 768; int ch = gp - lb*768;
    int T = ch >> 8;  int c  = ch & 255;
    float* aD = spec + (size_t)(2*T)   * slotStride + ((size_t)(lb*256 + c))*8320;
    float* pD = spec + (size_t)(2*T+1) * slotStride + ((size_t)(lb*256 + c))*8320;
    for (int o = t; o < 1664; o += 256) {
        int k1 = o / 13, k = o - k1*13;
        float re = 0.f, im = 0.f;
        int m = 0;
        for (int r = 0; r < 128; r++) {
            float cc = ct[m], sn = st[m];
            float a = cr[r][k], b = ci[r][k];
            re += a*cc + b*sn;
            im += b*cc - a*sn;
            m = (m + k1) & 127;
        }
        int kxv = kb + k;
        // Self-conjugate rfft2 bins: im is structurally zero; pocketfft gives
        // exact +0.0 -> angle in {0, +pi}. Noise here flips atan2 to -pi and
        // decorrelates the winner-take-all phase attention. Force +0.0.
        if ((k1 == 0 || k1 == 64) && (kxv == 0 || kxv == 64)) im = 0.f;
        int oi = k1*65 + kxv;
        aD[oi] = sqrtf(re*re + im*im);
        pD[oi] = atan2f(im, re);
    }
}

// ---------------- Attention: split-K partial sims (fp64 accum) -------------
__global__ __launch_bounds__(256) void attn_sim_kernel(
    const float* __restrict__ qA, const float* __restrict__ kA,
    double* __restrict__ simpart)
{
    int sp = blockIdx.x;           // 0..15
    int bh = blockIdx.y;           // lb*8 + h
    int lb = bh >> 3, h = bh & 7;
    int t = threadIdx.x;
    __shared__ float qs[32][130], ks[32][130];
    const float* qb = qA + ((size_t)(lb*256 + h*32)) * 8320;
    const float* kb = kA + ((size_t)(lb*256 + h*32)) * 8320;
    double acc[4] = {0.0, 0.0, 0.0, 0.0};
    for (int sub = 0; sub < 4; sub++) {
        int n0 = sp*520 + sub*130;
        for (int i = t; i < 4160; i += 256) {
            int j = i / 130, nn = i - j*130;
            qs[j][nn] = qb[(size_t)j*8320 + n0 + nn];
            ks[j][nn] = kb[(size_t)j*8320 + n0 + nn];
        }
        __syncthreads();
        #pragma unroll
        for (int e4 = 0; e4 < 4; e4++) {
            int e = t + (e4 << 8);
            int j = e >> 5, kq = e & 31;
            double a = acc[e4];
            for (int nn = 0; nn < 130; nn++)
                a += (double)qs[j][nn] * (double)ks[kq][nn];
            acc[e4] = a;
        }
        __syncthreads();
    }
    double* dst = simpart + ((size_t)bh*16 + sp) * 1024;
    dst[t]       = acc[0];
    dst[t + 256] = acc[1];
    dst[t + 512] = acc[2];
    dst[t + 768] = acc[3];
}

// ---------------- Attention: reduce + softmax + PV (fp64 weights) ----------
__global__ __launch_bounds__(256) void attn_out_kernel(
    const double* __restrict__ simpart, const float* __restrict__ vA,
    float* __restrict__ outA)
{
    int nb = blockIdx.x << 8;
    int bh = blockIdx.y;
    int lb = bh >> 3, h = bh & 7;
    int t = threadIdx.x;
    __shared__ double sim[32][32];
    for (int e = t; e < 1024; e += 256) {
        double s = 0.0;
        const double* pp = simpart + (size_t)bh*16384 + e;
        #pragma unroll
        for (int sp = 0; sp < 16; sp++) s += pp[sp*1024];
        sim[e >> 5][e & 31] = s * ATTN_SCALE_D;
    }
    __syncthreads();
    if (t < 32) {
        double m = -1e300;
        for (int k = 0; k < 32; k++) m = fmax(m, sim[t][k]);
        double s = 0.0;
        for (int k = 0; k < 32; k++) s += exp(sim[t][k] - m);
        double inv = 1.0 / s;
        for (int k = 0; k < 32; k++) sim[t][k] = exp(sim[t][k] - m) * inv;
    }
    __syncthreads();
    int n = nb + t;
    if (n >= 8320) return;
    const float* vb = vA + ((size_t)(lb*256 + h*32)) * 8320 + n;
    float vv[32];
    #pragma unroll
    for (int k = 0; k < 32; k++) vv[k] = vb[(size_t)k * 8320];
    float* ob = outA + ((size_t)(lb*256 + h*32)) * 8320 + n;
    for (int j = 0; j < 32; j++) {
        double o = 0.0;
        #pragma unroll
        for (int k = 0; k < 32; k++) o += sim[j][k] * (double)vv[k];
        ob[(size_t)j * 8320] = (float)o;
    }
}

// ---------------- Inverse FFT stage 1: fp32 column inverse (e^{+i}) --------
__global__ __launch_bounds__(256) void ifft_col_kernel(
    const float* __restrict__ ampo, const float* __restrict__ pho,
    float* __restrict__ tre, float* __restrict__ tim)
{
    int kb    = blockIdx.x * 13;
    int plane = blockIdx.y;
    int t     = threadIdx.x;
    __shared__ float cr[128][13], cim[128][13];
    __shared__ float ct[128], st[128];
    if (t < 128) { double s, c; sincos(TWO_PI_D * t / 128.0, &s, &c);
                   st[t] = (float)s; ct[t] = (float)c; }
    const float* ab = ampo + (size_t)plane * 8320;
    const float* pb = pho  + (size_t)plane * 8320;
    for (int i = t; i < 1664; i += 256) {
        int k1 = i / 13, k = i - k1*13;
        float a = ab[k1*65 + kb + k];
        float p = pb[k1*65 + kb + k];
        float sp, cp; sincosf(p, &sp, &cp);
        cr[k1][k]  = a * cp;
        cim[k1][k] = a * sp;
    }
    __syncthreads();
    for (int o = t; o < 1664; o += 256) {
        int y = o / 13, k = o - y*13;
        float re = 0.f, im = 0.f;
        int m = 0;
        for (int k1 = 0; k1 < 128; k1++) {
            float c = ct[m], s = st[m];
            float a = cr[k1][k], bb = cim[k1][k];
            re += a*c - bb*s;
            im += a*s + bb*c;
            m = (m + y) & 127;
        }
        size_t oi = ((size_t)plane*128 + y)*65 + kb + k;
        tre[oi] = re;
        tim[oi] = im;
    }
}

// ---------------- Inverse FFT stage 2: fp32 Hermitian rows -----------------
__global__ __launch_bounds__(256) void ifft_row_kernel(
    const float* __restrict__ tre, const float* __restrict__ tim,
    float* __restrict__ spat)
{
    int rc    = blockIdx.x;
    int plane = blockIdx.y;
    int t     = threadIdx.x;
    __shared__ float tr[16][65], ti[16][65];
    __shared__ float ct[128], st[128];
    if (t < 128) { double s, c; sincos(TWO_PI_D * t / 128.0, &s, &c);
                   st[t] = (float)s; ct[t] = (float)c; }
    for (int i = t; i < 1040; i += 256) {
        int r = i / 65, k = i - r*65;
        size_t si = ((size_t)plane*128 + rc*16 + r)*65 + k;
        tr[r][k] = tre[si];
        ti[r][k] = tim[si];
    }
    __syncthreads();
    for (int o = t; o < 2048; o += 256) {
        int r = o >> 7, x = o & 127;
        float acc = tr[r][0];
        int m = x;
        for (int k = 1; k < 64; k++) {
            acc += 2.f * (tr[r][k]*ct[m] - ti[r][k]*st[m]);
            m = (m + x) & 127;
        }
        acc += tr[r][64]*ct[m] - ti[r][64]*st[m];
        spat[((size_t)plane << 14) + ((rc*16 + r) << 7) + x] = acc * 0.0078125f;
    }
}

// ---------------- bf16 MFMA implicit-GEMM conv (tail) ----------------------
template<int R>
__global__ __launch_bounds__(256) void convmf_kernel(
    const float* __restrict__ in, const float* __restrict__ wt,
    const float* __restrict__ bias, const float* __restrict__ res,
    float* __restrict__ out, int Cin, int Cout, int act,
    int in_b0, int res_b0, int out_b0)
{
    const int K = Cin * R * R;
    int pBase  = blockIdx.x << 7;
    int coBase = blockIdx.y << 7;
    int lb = blockIdx.z;
    int t = threadIdx.x;
    int lane = t & 63;
    int wave = t >> 6;
    int wm = (wave >> 1) << 6;
    int wn = (wave & 1) << 6;

    __shared__ short As[128][40];
    __shared__ short Bs[128][40];

    f32x4 acc[4][4];
    #pragma unroll
    for (int i = 0; i < 4; i++)
        #pragma unroll
        for (int j = 0; j < 4; j++) acc[i][j] = (f32x4){0.f, 0.f, 0.f, 0.f};

    const size_t inb = ((size_t)(in_b0 + lb) * Cin) << 14;
    int lr = lane & 15;
    int kg = (lane >> 4) << 3;

    for (int k0 = 0; k0 < K; k0 += 32) {
        __syncthreads();
        for (int i = t; i < 4096; i += 256) {
            int co = i >> 5, kk = i & 31;
            As[co][kk] = f2bf(wt[(size_t)(coBase + co) * K + k0 + kk]);
        }
        for (int i = t; i < 4096; i += 256) {
            int kr = i >> 7, px = i & 127;
            int k = k0 + kr;
            float v;
            if (R == 3) {
                int ci = k / 9; int rr = k - ci*9; int dy = rr / 3; int dx = rr - dy*3;
                int pg = pBase + px;
                int yy = (pg >> 7) + dy - 1;
                int xx = (pg & 127) + dx - 1;
                v = (yy >= 0 && yy < 128 && xx >= 0 && xx < 128)
                    ? in[inb + ((size_t)ci << 14) + (yy << 7) + xx] : 0.f;
            } else {
                v = in[inb + ((size_t)k << 14) + pBase + px];
            }
            Bs[px][kr] = f2bf(v);
        }
        __syncthreads();
        short8 af[4], bf[4];
        #pragma unroll
        for (int i = 0; i < 4; i++)
            af[i] = *(const short8*)&As[wm + i*16 + lr][kg];
        #pragma unroll
        for (int j = 0; j < 4; j++)
            bf[j] = *(const short8*)&Bs[wn + j*16 + lr][kg];
        #pragma unroll
        for (int i = 0; i < 4; i++)
            #pragma unroll
            for (int j = 0; j < 4; j++)
                acc[i][j] = __builtin_amdgcn_mfma_f32_16x16x32_bf16(
                    af[i], bf[j], acc[i][j], 0, 0, 0);
    }

    int mr = (lane >> 4) << 2;
    #pragma unroll
    for (int i = 0; i < 4; i++) {
        #pragma unroll
        for (int r = 0; r < 4; r++) {
            int co = coBase + wm + i*16 + mr + r;
            float vb = bias ? bias[co] : 0.f;
            size_t rowo = (((size_t)(out_b0 + lb) * Cout + co) << 14);
            size_t rowr = (((size_t)(res_b0 + lb) * Cout + co) << 14);
            #pragma unroll
            for (int j = 0; j < 4; j++) {
                int px = pBase + wn + j*16 + lr;
                float v = acc[i][j][r] + vb;
                if (act == 1) v = v / (1.f + expf(-v));
                if (res) v += res[rowr + px];
                out[rowo + px] = v;
            }
        }
    }
}

// ---------------------------------------------------------------------------
extern "C" void kernel_launch(void* const* d_in, const int* in_sizes, int n_in,
                              void* d_out, int out_size, void* d_ws, size_t ws_size,
                              hipStream_t stream) {
    (void)in_sizes; (void)n_in; (void)out_size;
    const float* x    = (const float*)d_in[0];
    const float* gn_w = (const float*)d_in[1];
    const float* gn_b = (const float*)d_in[2];
    const float* dw_w = (const float*)d_in[3];
    const float* pw_w = (const float*)d_in[4];
    const float* pw_b = (const float*)d_in[5];
    const float* ao_w = (const float*)d_in[6];
    const float* ao_b = (const float*)d_in[7];
    const float* f1_w = (const float*)d_in[8];
    const float* f2_w = (const float*)d_in[9];
    const float* f3_w = (const float*)d_in[10];
    const float* f3_b = (const float*)d_in[11];
    float* outp = (float*)d_out;

    // per-batch region sizes in floats
    const size_t F_QKV  = 12582912;   // qkv; later h1 (8,388,608) + h2 (4,194,304)
    const size_t F_SLOT = 2129920;    // one fp32 spec slot
    const size_t F_SPEC = 6 * F_SLOT;
    const size_t F_XN   = 4194304;
    const size_t F_E    = 6389760;    // max(dw, rre+rim)
    const size_t F_SIMP = 262144;     // 131,072 doubles
    const size_t F_TOT  = F_QKV + F_SPEC + F_XN + F_E + F_SIMP; // 36,208,640

    int NB = 0;
    for (int cand : {8, 4, 2, 1}) {
        if ((size_t)cand * F_TOT * 4 <= ws_size) { NB = cand; break; }
    }
    if (NB == 0) return;

    float* wsf  = (float*)d_ws;
    float* qkv  = wsf;                                  // also h1, h2
    float* h1   = wsf;
    float* h2   = wsf + (size_t)NB * 8388608;
    float* spec = wsf + (size_t)NB * F_QKV;
    size_t ss   = (size_t)NB * F_SLOT;                  // slot stride (floats)
    float* tre  = spec + 2*ss;                          // slot 2 (fp32 now)
    float* tim  = spec + 3*ss;                          // slot 3
    float* spat = spec + 4*ss;                          // slots 4-5
    float* xn   = spec + 6*ss;
    float* ebuf = xn + (size_t)NB * F_XN;               // dw, then rre/rim
    float* dw   = ebuf;
    float* rre  = ebuf;
    float* rim  = ebuf + (size_t)NB * 3194880;
    double* simp = (double*)(ebuf + (size_t)NB * F_E);

    const int passes = 8 / NB;
    for (int p = 0; p < passes; p++) {
        int b0 = p * NB;
        // 1. GroupNorm -> xn (fp32)
        groupnorm_kernel<<<NB*32, 256, 0, stream>>>(x, gn_w, gn_b, xn, b0);
        // 2. depthwise 3x3 fp32: xn -> dw
        dwconv_kernel<<<NB*256*64, 256, 0, stream>>>(xn, dw_w, dw);
        // 3. pointwise 256->768 (+bias) fp32: dw -> qkv
        conv_kernel<1><<<dim3(128, 6, NB), 256, 0, stream>>>(
            dw, pw_w, pw_b, nullptr, qkv, 256, 768, 0, 0, 0, 0);
        // 4. per-pixel L2 norm of q,k,v in place
        l2norm_kernel<<<NB*3*64, 256, 0, stream>>>(qkv);
        // 5. rfft2 fp32 -> amp/phase spec slots, 2 chunks of NB*384 planes
        for (int chunk = 0; chunk < 2; chunk++) {
            fft_row_kernel<<<dim3(8, NB*384), 256, 0, stream>>>(qkv, rre, rim, chunk*NB*384);
            fft_col_kernel<<<dim3(5, NB*384), 256, 0, stream>>>(rre, rim, spec, chunk*NB*384, ss);
        }
        // 6. channel attention (split-K, fp64 logits): amp -> slot0, phase -> slot1
        attn_sim_kernel<<<dim3(16, NB*8), 256, 0, stream>>>(spec + 0*ss, spec + 2*ss, simp);
        attn_out_kernel<<<dim3(33, NB*8), 256, 0, stream>>>(simp, spec + 4*ss, spec + 0*ss);
        attn_sim_kernel<<<dim3(16, NB*8), 256, 0, stream>>>(spec + 1*ss, spec + 3*ss, simp);
        attn_out_kernel<<<dim3(33, NB*8), 256, 0, stream>>>(simp, spec + 5*ss, spec + 1*ss);
        // 7. irfft2 fp32: slots 0,1 -> tre/tim (slots 2,3) -> spat (slots 4-5)
        ifft_col_kernel<<<dim3(5, NB*256), 256, 0, stream>>>(spec + 0*ss, spec + 1*ss,
                                                             tre, tim);
        ifft_row_kernel<<<dim3(8, NB*256), 256, 0, stream>>>(tre, tim, spat);
        // 8. ao 1x1 (+bias) + xn residual -> attn (d_out)      [bf16 MFMA]
        convmf_kernel<1><<<dim3(128, 2, NB), 256, 0, stream>>>(
            spat, ao_w, ao_b, xn, outp, 256, 256, 0, 0, 0, b0);
        // 9. f1 3x3 256->512 + SiLU                            [bf16 MFMA]
        convmf_kernel<3><<<dim3(128, 4, NB), 256, 0, stream>>>(
            outp, f1_w, nullptr, nullptr, h1, 256, 512, 1, b0, 0, 0);
        // 10. f2 3x3 512->256                                  [bf16 MFMA]
        convmf_kernel<3><<<dim3(128, 2, NB), 256, 0, stream>>>(
            h1, f2_w, nullptr, nullptr, h2, 512, 256, 0, 0, 0, 0);
        // 11. f3 1x1 (+bias) + attn residual, in place         [bf16 MFMA]
        convmf_kernel<1><<<dim3(128, 2, NB), 256, 0, stream>>>(
            h2, f3_w, f3_b, outp, outp, 256, 256, 0, 0, b0, b0);
    }
}

// Round 13
// 9664.615 us; speedup vs baseline: 3.4264x; 1.6212x over previous
//
#include <hip/hip_runtime.h>
#include <hip/hip_bf16.h>
#include <math.h>

// ---------------------------------------------------------------------------
// FreqCA: B=8, C=256, H=W=128, NHEADS=8, GROUPS=32.
// Round 13: (1) convmf v2 -- weights pre-transformed to bf16 [R^2][Cout][Cin],
// conv as 9 shifted 1x1 GEMMs (no idiv / scalar gather in staging);
// (2) l2norm folded into fft_row via inverse-norm map (l2inv);
// (3) DFT stages register-tiled 4-wide sharing twiddle streams.
// fp32 front end + fp64 attention logits; self-conjugate rfft2 bins im=+0.0.
// Per-batch float layout: qkv 12,582,912 (later h1+h2) | spec 6x2,129,920
// (2,3->tre/tim, 4-5->spat) | xn 4,194,304 | ebuf 4,259,840 (dw -> rre/rim,
// 3 chunks of NB*256 planes) | simp 262,144 (invn then fp64 simpart).
// F_TOT = 34,078,720 floats; + fixed 2,490,368-short bf16 weight buffer.
// ---------------------------------------------------------------------------

#define TWO_PI_D 6.283185307179586476925286766559
#define ATTN_SCALE_D 0.17677669529663688110021109052621  // 1/sqrt(32)

typedef __attribute__((ext_vector_type(8))) short short8;
typedef __attribute__((ext_vector_type(4))) float f32x4;

__device__ inline short f2bf(float f) {
    __hip_bfloat16 h = __float2bfloat16(f);
    return *reinterpret_cast<short*>(&h);
}

// ---------------- GroupNorm: fp64 stats, fp32 out --------------------------
__global__ __launch_bounds__(256) void groupnorm_kernel(
    const float* __restrict__ x, const float* __restrict__ gw,
    const float* __restrict__ gb, float* __restrict__ out, int b0)
{
    int t = threadIdx.x;
    int lb = blockIdx.x >> 5;
    int g  = blockIdx.x & 31;
    size_t src = ((size_t)(b0 + lb) * 32 + g) * 131072;
    size_t dst = (size_t)blockIdx.x * 131072;
    const float* xp = x + src;
    double s = 0.0, ss = 0.0;
    for (int i = t; i < 131072; i += 256) { double v = xp[i]; s += v; ss += v*v; }
    __shared__ double rs[256], rss[256];
    rs[t] = s; rss[t] = ss;
    __syncthreads();
    for (int k = 128; k > 0; k >>= 1) {
        if (t < k) { rs[t] += rs[t+k]; rss[t] += rss[t+k]; }
        __syncthreads();
    }
    __shared__ float smean, sinv;
    if (t == 0) {
        double mean = rs[0] * (1.0/131072.0);
        double var  = rss[0] * (1.0/131072.0) - mean*mean;
        smean = (float)mean;
        sinv  = (float)(1.0 / sqrt(var + 1e-5));
    }
    __syncthreads();
    float mean = smean, inv = sinv;
    for (int i = t; i < 131072; i += 256) {
        int c = (g << 3) + (i >> 14);
        out[dst + i] = (xp[i] - mean) * inv * gw[c] + gb[c];
    }
}

// ---------------- Depthwise 3x3 fp32 ---------------------------------------
__global__ __launch_bounds__(256) void dwconv_kernel(
    const float* __restrict__ in, const float* __restrict__ w, float* __restrict__ out)
{
    int t = threadIdx.x;
    int bc = blockIdx.x >> 6;
    int y  = ((blockIdx.x & 63) << 1) + (t >> 7);
    int x  = t & 127;
    int c  = bc & 255;
    const float* wp = w + c*9;
    const float* ip = in + ((size_t)bc << 14);
    float acc = 0.f;
    #pragma unroll
    for (int dy = 0; dy < 3; dy++) {
        int yy = y + dy - 1;
        if (yy < 0 || yy > 127) continue;
        const float* row = ip + (yy << 7);
        #pragma unroll
        for (int dx = 0; dx < 3; dx++) {
            int xx = x + dx - 1;
            if (xx >= 0 && xx <= 127) acc += wp[dy*3+dx] * row[xx];
        }
    }
    out[((size_t)bc << 14) + (y << 7) + x] = acc;
}

// ---------------- fp32 tiled implicit-GEMM conv (pw only) ------------------
template<int R>
__global__ __launch_bounds__(256) void conv_kernel(
    const float* __restrict__ in, const float* __restrict__ wt,
    const float* __restrict__ bias, const float* __restrict__ res,
    float* __restrict__ out, int Cin, int Cout, int act,
    int in_b0, int res_b0, int out_b0)
{
    const int K = Cin * R * R;
    int pBase  = blockIdx.x << 7;
    int coBase = blockIdx.y << 7;
    int lb = blockIdx.z;
    int t = threadIdx.x;
    int tx = t & 15, ty = t >> 4;

    __shared__ float As[8][128];
    __shared__ float Bs[8][128];

    float acc[8][8];
    #pragma unroll
    for (int i = 0; i < 8; i++)
        #pragma unroll
        for (int j = 0; j < 8; j++) acc[i][j] = 0.f;

    int a_co = t >> 1;
    int a_k  = (t & 1) << 2;
    int b_k  = t >> 5;
    int b_p  = (t & 31) << 2;
    const float* wrow = wt + (size_t)(coBase + a_co) * K + a_k;
    const size_t inb = ((size_t)(in_b0 + lb) * Cin) << 14;

    for (int k0 = 0; k0 < K; k0 += 8) {
        float4 av = *(const float4*)(wrow + k0);
        int kk = k0 + b_k;
        float4 bv;
        if (R == 3) {
            int ci = kk / 9; int rr = kk - ci*9; int dy = rr / 3; int dx = rr - dy*3;
            const float* ip = in + inb + ((size_t)ci << 14);
            float tmp[4];
            #pragma unroll
            for (int j = 0; j < 4; j++) {
                int pg = pBase + b_p + j;
                int yy = (pg >> 7) + dy - 1;
                int xx = (pg & 127) + dx - 1;
                tmp[j] = (yy >= 0 && yy < 128 && xx >= 0 && xx < 128) ? ip[(yy << 7) + xx] : 0.f;
            }
            bv = make_float4(tmp[0], tmp[1], tmp[2], tmp[3]);
        } else {
            bv = *(const float4*)(in + inb + ((size_t)kk << 14) + pBase + b_p);
        }
        __syncthreads();
        As[a_k+0][a_co] = av.x; As[a_k+1][a_co] = av.y;
        As[a_k+2][a_co] = av.z; As[a_k+3][a_co] = av.w;
        *(float4*)&Bs[b_k][b_p] = bv;
        __syncthreads();
        #pragma unroll
        for (int k2 = 0; k2 < 8; k2++) {
            float4 A1 = *(const float4*)&As[k2][ty << 2];
            float4 A2 = *(const float4*)&As[k2][64 + (ty << 2)];
            float4 B1 = *(const float4*)&Bs[k2][tx << 2];
            float4 B2 = *(const float4*)&Bs[k2][64 + (tx << 2)];
            float a0[8] = {A1.x,A1.y,A1.z,A1.w,A2.x,A2.y,A2.z,A2.w};
            float b0v[8] = {B1.x,B1.y,B1.z,B1.w,B2.x,B2.y,B2.z,B2.w};
            #pragma unroll
            for (int i = 0; i < 8; i++)
                #pragma unroll
                for (int j = 0; j < 8; j++) acc[i][j] += a0[i] * b0v[j];
        }
    }

    #pragma unroll
    for (int i = 0; i < 8; i++) {
        int co = coBase + ((i < 4) ? ((ty << 2) + i) : (64 + (ty << 2) + i - 4));
        size_t rbo = (((size_t)(out_b0 + lb) * Cout + co) << 14) + pBase;
        size_t rbr = (((size_t)(res_b0 + lb) * Cout + co) << 14) + pBase;
        float vb = bias ? bias[co] : 0.f;
        #pragma unroll
        for (int jh = 0; jh < 2; jh++) {
            int colo = (jh == 0) ? (tx << 2) : (64 + (tx << 2));
            float4 v;
            v.x = acc[i][jh*4+0] + vb;
            v.y = acc[i][jh*4+1] + vb;
            v.z = acc[i][jh*4+2] + vb;
            v.w = acc[i][jh*4+3] + vb;
            if (act == 1) {
                v.x = v.x / (1.f + expf(-v.x));
                v.y = v.y / (1.f + expf(-v.y));
                v.z = v.z / (1.f + expf(-v.z));
                v.w = v.w / (1.f + expf(-v.w));
            }
            if (res) {
                float4 r4 = *(const float4*)(res + rbr + colo);
                v.x += r4.x; v.y += r4.y; v.z += r4.z; v.w += r4.w;
            }
            *(float4*)(out + rbo + colo) = v;
        }
    }
}

// ---------------- inverse L2 norms per pixel (no write-back) ---------------
__global__ __launch_bounds__(256) void l2inv_kernel(
    const float* __restrict__ qkv, float* __restrict__ invn)
{
    int p  = ((blockIdx.x & 63) << 8) + threadIdx.x;
    int bT = blockIdx.x >> 6;          // lb*3 + T
    int lb = bT / 3, T = bT - 3*lb;
    const float* base = qkv + (((size_t)(lb*768 + T*256)) << 14) + p;
    double ss = 0.0;
    for (int c = 0; c < 256; c++) { double v = base[(size_t)c << 14]; ss += v*v; }
    invn[((size_t)bT << 14) + p] = 1.f / fmaxf((float)sqrt(ss), 1e-12f);
}

// ---------------- FFT stage 1: row DFT, invn applied, 4-row tiled ----------
__global__ __launch_bounds__(256) void fft_row_kernel(
    const float* __restrict__ qkv, const float* __restrict__ invn,
    float* __restrict__ rre, float* __restrict__ rim, int chunkBase)
{
    int rc  = blockIdx.x;          // 16-row chunk 0..7
    int loc = blockIdx.y;
    int gp  = chunkBase + loc;
    int t   = threadIdx.x;
    __shared__ float xs[16][128];
    __shared__ float ct[128], st[128];
    if (t < 128) { double s, c; sincos(TWO_PI_D * t / 128.0, &s, &c);
                   st[t] = (float)s; ct[t] = (float)c; }
    int lb = gp / 768, chn = gp - lb*768, T = chn >> 8;
    const float4* src = (const float4*)(qkv + ((size_t)gp << 14) + ((size_t)rc << 11));
    const float4* ivp = (const float4*)(invn + (((size_t)(lb*3 + T)) << 14) + ((size_t)rc << 11));
    float4* xd = (float4*)xs;
    for (int i = t; i < 512; i += 256) {
        float4 v = src[i], w = ivp[i];
        v.x *= w.x; v.y *= w.y; v.z *= w.z; v.w *= w.w;
        xd[i] = v;
    }
    __syncthreads();
    for (int oo = t; oo < 260; oo += 256) {
        int k = oo % 65, rq = oo / 65;
        const float* x0 = xs[rq*4+0];
        const float* x1 = xs[rq*4+1];
        const float* x2 = xs[rq*4+2];
        const float* x3 = xs[rq*4+3];
        float re0=0,re1=0,re2=0,re3=0, im0=0,im1=0,im2=0,im3=0;
        int m = 0;
        for (int w = 0; w < 128; w++) {
            float cc = ct[m], sn = st[m];
            float a0 = x0[w], a1 = x1[w], a2 = x2[w], a3 = x3[w];
            re0 += a0*cc; im0 -= a0*sn;
            re1 += a1*cc; im1 -= a1*sn;
            re2 += a2*cc; im2 -= a2*sn;
            re3 += a3*cc; im3 -= a3*sn;
            m = (m + k) & 127;
        }
        size_t base = ((size_t)loc*128 + rc*16 + rq*4)*65 + k;
        rre[base]       = re0*0.0078125f; rim[base]       = im0*0.0078125f;
        rre[base + 65]  = re1*0.0078125f; rim[base + 65]  = im1*0.0078125f;
        rre[base + 130] = re2*0.0078125f; rim[base + 130] = im2*0.0078125f;
        rre[base + 195] = re3*0.0078125f; rim[base + 195] = im3*0.0078125f;
    }
}

// ---------------- FFT stage 2: col DFT -> amp/phase, 4-kx float4 tiled -----
__global__ __launch_bounds__(256) void fft_col_kernel(
    const float* __restrict__ rre, const float* __restrict__ rim,
    float* __restrict__ spec, int chunkBase, size_t slotStride)
{
    int kb  = blockIdx.x * 13;
    int loc = blockIdx.y;
    int gp  = chunkBase + loc;
    int t   = threadIdx.x;
    __shared__ float cr[128][16], ci_[128][16];
    __shared__ float ct[128], st[128];
    if (t < 128) { double s, c; sincos(TWO_PI_D * t / 128.0, &s, &c);
                   st[t] = (float)s; ct[t] = (float)c; }
    for (int i = t; i < 2048; i += 256) {
        int r = i >> 4, k = i & 15;
        float a = 0.f, b = 0.f;
        if (k < 13) {
            size_t si = ((size_t)loc*128 + r)*65 + kb + k;
            a = rre[si]; b = rim[si];
        }
        cr[r][k] = a; ci_[r][k] = b;
    }
    __syncthreads();
    int lb = gp / 768; int chn = gp - lb*768;
    int T = chn >> 8;  int c = chn & 255;
    float* aD = spec + (size_t)(2*T)   * slotStride + ((size_t)(lb*256 + c))*8320;
    float* pD = spec + (size_t)(2*T+1) * slotStride + ((size_t)(lb*256 + c))*8320;
    for (int oo = t; oo < 512; oo += 256) {
        int k1 = oo >> 2, g4 = (oo & 3) << 2;
        float re[4] = {0,0,0,0}, im[4] = {0,0,0,0};
        int m = 0;
        for (int r = 0; r < 128; r++) {
            float cc = ct[m], sn = st[m];
            float4 a4 = *(const float4*)&cr[r][g4];
            float4 b4 = *(const float4*)&ci_[r][g4];
            re[0] += a4.x*cc + b4.x*sn; im[0] += b4.x*cc - a4.x*sn;
            re[1] += a4.y*cc + b4.y*sn; im[1] += b4.y*cc - a4.y*sn;
            re[2] += a4.z*cc + b4.z*sn; im[2] += b4.z*cc - a4.z*sn;
            re[3] += a4.w*cc + b4.w*sn; im[3] += b4.w*cc - a4.w*sn;
            m = (m + k1) & 127;
        }
        #pragma unroll
        for (int j = 0; j < 4; j++) {
            int kx = g4 + j;
            if (kx < 13) {
                int kxv = kb + kx;
                float rr2 = re[j], ii2 = im[j];
                // Self-conjugate rfft2 bins: im structurally zero; pocketfft
                // gives exact +0.0 -> angle in {0,+pi}. Force +0.0 so atan2
                // never flips to -pi (decorrelates phase attention).
                if ((k1 == 0 || k1 == 64) && (kxv == 0 || kxv == 64)) ii2 = 0.f;
                int oi = k1*65 + kxv;
                aD[oi] = sqrtf(rr2*rr2 + ii2*ii2);
                pD[oi] = atan2f(ii2, rr2);
            }
        }
    }
}

// ---------------- Attention: split-K partial sims (fp64 accum) -------------
__global__ __launch_bounds__(256) void attn_sim_kernel(
    const float* __restrict__ qA, const float* __restrict__ kA,
    double* __restrict__ simpart)
{
    int sp = blockIdx.x;           // 0..15
    int bh = blockIdx.y;           // lb*8 + h
    int lb = bh >> 3, h = bh & 7;
    int t = threadIdx.x;
    __shared__ float qs[32][130], ks[32][130];
    const float* qb = qA + ((size_t)(lb*256 + h*32)) * 8320;
    const float* kb = kA + ((size_t)(lb*256 + h*32)) * 8320;
    double acc[4] = {0.0, 0.0, 0.0, 0.0};
    for (int sub = 0; sub < 4; sub++) {
        int n0 = sp*520 + sub*130;
        for (int i = t; i < 4160; i += 256) {
            int j = i / 130, nn = i - j*130;
            qs[j][nn] = qb[(size_t)j*8320 + n0 + nn];
            ks[j][nn] = kb[(size_t)j*8320 + n0 + nn];
        }
        __syncthreads();
        #pragma unroll
        for (int e4 = 0; e4 < 4; e4++) {
            int e = t + (e4 << 8);
            int j = e >> 5, kq = e & 31;
            double a = acc[e4];
            for (int nn = 0; nn < 130; nn++)
                a += (double)qs[j][nn] * (double)ks[kq][nn];
            acc[e4] = a;
        }
        __syncthreads();
    }
    double* dst = simpart + ((size_t)bh*16 + sp) * 1024;
    dst[t]       = acc[0];
    dst[t + 256] = acc[1];
    dst[t + 512] = acc[2];
    dst[t + 768] = acc[3];
}

// ---------------- Attention: reduce + softmax + PV (fp64 weights) ----------
__global__ __launch_bounds__(256) void attn_out_kernel(
    const double* __restrict__ simpart, const float* __restrict__ vA,
    float* __restrict__ outA)
{
    int nb = blockIdx.x << 8;
    int bh = blockIdx.y;
    int lb = bh >> 3, h = bh & 7;
    int t = threadIdx.x;
    __shared__ double sim[32][32];
    for (int e = t; e < 1024; e += 256) {
        double s = 0.0;
        const double* pp = simpart + (size_t)bh*16384 + e;
        #pragma unroll
        for (int sp = 0; sp < 16; sp++) s += pp[sp*1024];
        sim[e >> 5][e & 31] = s * ATTN_SCALE_D;
    }
    __syncthreads();
    if (t < 32) {
        double m = -1e300;
        for (int k = 0; k < 32; k++) m = fmax(m, sim[t][k]);
        double s = 0.0;
        for (int k = 0; k < 32; k++) s += exp(sim[t][k] - m);
        double inv = 1.0 / s;
        for (int k = 0; k < 32; k++) sim[t][k] = exp(sim[t][k] - m) * inv;
    }
    __syncthreads();
    int n = nb + t;
    if (n >= 8320) return;
    const float* vb = vA + ((size_t)(lb*256 + h*32)) * 8320 + n;
    float vv[32];
    #pragma unroll
    for (int k = 0; k < 32; k++) vv[k] = vb[(size_t)k * 8320];
    float* ob = outA + ((size_t)(lb*256 + h*32)) * 8320 + n;
    for (int j = 0; j < 32; j++) {
        double o = 0.0;
        #pragma unroll
        for (int k = 0; k < 32; k++) o += sim[j][k] * (double)vv[k];
        ob[(size_t)j * 8320] = (float)o;
    }
}

// ---------------- iFFT stage 1: col inverse, 4-kx float4 tiled -------------
__global__ __launch_bounds__(256) void ifft_col_kernel(
    const float* __restrict__ ampo, const float* __restrict__ pho,
    float* __restrict__ tre, float* __restrict__ tim)
{
    int kb    = blockIdx.x * 13;
    int plane = blockIdx.y;
    int t     = threadIdx.x;
    __shared__ float cr[128][16], ci_[128][16];
    __shared__ float ct[128], st[128];
    if (t < 128) { double s, c; sincos(TWO_PI_D * t / 128.0, &s, &c);
                   st[t] = (float)s; ct[t] = (float)c; }
    const float* ab = ampo + (size_t)plane * 8320;
    const float* pb = pho  + (size_t)plane * 8320;
    for (int i = t; i < 2048; i += 256) {
        int k1 = i >> 4, k = i & 15;
        float xr = 0.f, xi = 0.f;
        if (k < 13) {
            float a = ab[k1*65 + kb + k];
            float p = pb[k1*65 + kb + k];
            float sp, cp; sincosf(p, &sp, &cp);
            xr = a * cp; xi = a * sp;
        }
        cr[k1][k] = xr; ci_[k1][k] = xi;
    }
    __syncthreads();
    for (int oo = t; oo < 512; oo += 256) {
        int y = oo >> 2, g4 = (oo & 3) << 2;
        float re[4] = {0,0,0,0}, im[4] = {0,0,0,0};
        int m = 0;
        for (int k1 = 0; k1 < 128; k1++) {
            float cc = ct[m], sn = st[m];
            float4 a4 = *(const float4*)&cr[k1][g4];
            float4 b4 = *(const float4*)&ci_[k1][g4];
            re[0] += a4.x*cc - b4.x*sn; im[0] += a4.x*sn + b4.x*cc;
            re[1] += a4.y*cc - b4.y*sn; im[1] += a4.y*sn + b4.y*cc;
            re[2] += a4.z*cc - b4.z*sn; im[2] += a4.z*sn + b4.z*cc;
            re[3] += a4.w*cc - b4.w*sn; im[3] += a4.w*sn + b4.w*cc;
            m = (m + y) & 127;
        }
        #pragma unroll
        for (int j = 0; j < 4; j++) {
            int kx = g4 + j;
            if (kx < 13) {
                size_t oi = ((size_t)plane*128 + y)*65 + kb + kx;
                tre[oi] = re[j];
                tim[oi] = im[j];
            }
        }
    }
}

// ---------------- iFFT stage 2: Hermitian rows, 4-row tiled ----------------
__global__ __launch_bounds__(256) void ifft_row_kernel(
    const float* __restrict__ tre, const float* __restrict__ tim,
    float* __restrict__ spat)
{
    int rc    = blockIdx.x;        // 0..7
    int plane = blockIdx.y;
    int t     = threadIdx.x;
    __shared__ float tr[16][65], ti[16][65];
    __shared__ float ct[128], st[128];
    if (t < 128) { double s, c; sincos(TWO_PI_D * t / 128.0, &s, &c);
                   st[t] = (float)s; ct[t] = (float)c; }
    for (int i = t; i < 1040; i += 256) {
        int r = i / 65, k = i - r*65;
        size_t si = ((size_t)plane*128 + rc*16 + r)*65 + k;
        tr[r][k] = tre[si];
        ti[r][k] = tim[si];
    }
    __syncthreads();
    for (int oo = t; oo < 512; oo += 256) {
        int x = oo & 127, r0 = (oo >> 7) << 2;
        float a0 = tr[r0][0], a1 = tr[r0+1][0], a2 = tr[r0+2][0], a3 = tr[r0+3][0];
        int m = x;
        for (int k = 1; k < 64; k++) {
            float cc = ct[m], sn = st[m];
            a0 += 2.f*(tr[r0  ][k]*cc - ti[r0  ][k]*sn);
            a1 += 2.f*(tr[r0+1][k]*cc - ti[r0+1][k]*sn);
            a2 += 2.f*(tr[r0+2][k]*cc - ti[r0+2][k]*sn);
            a3 += 2.f*(tr[r0+3][k]*cc - ti[r0+3][k]*sn);
            m = (m + x) & 127;
        }
        float cc = ct[m], sn = st[m];
        a0 += tr[r0  ][64]*cc - ti[r0  ][64]*sn;
        a1 += tr[r0+1][64]*cc - ti[r0+1][64]*sn;
        a2 += tr[r0+2][64]*cc - ti[r0+2][64]*sn;
        a3 += tr[r0+3][64]*cc - ti[r0+3][64]*sn;
        size_t ob = ((size_t)plane << 14) + ((rc*16 + r0) << 7) + x;
        spat[ob]       = a0*0.0078125f;
        spat[ob + 128] = a1*0.0078125f;
        spat[ob + 256] = a2*0.0078125f;
        spat[ob + 384] = a3*0.0078125f;
    }
}

// ---------------- weight pre-transform: fp32 [Co][Ci][R][R] -> bf16 [RR][Co][Ci]
__global__ __launch_bounds__(256) void wcvt_kernel(
    const float* __restrict__ w, short* __restrict__ wbf,
    int Cout, int Cin, int RR)
{
    int i = blockIdx.x * 256 + threadIdx.x;
    int total = Cout * Cin * RR;
    if (i >= total) return;
    int rr = i % RR;
    int ci = (i / RR) % Cin;
    int co = i / (RR * Cin);
    wbf[((size_t)rr * Cout + co) * Cin + ci] = f2bf(w[i]);
}

// ---------------- bf16 MFMA conv v2: R*R shifted 1x1 GEMMs -----------------
// wbf layout [R*R][Cout][Cin] bf16. Block = 128co x 128px (one image row y).
template<int R>
__global__ __launch_bounds__(256) void convmf2_kernel(
    const float* __restrict__ in, const short* __restrict__ wbf,
    const float* __restrict__ bias, const float* __restrict__ res,
    float* __restrict__ out, int Cin, int Cout, int act,
    int in_b0, int res_b0, int out_b0)
{
    int y      = blockIdx.x;       // image row (pBase = y*128)
    int coBase = blockIdx.y << 7;
    int lb = blockIdx.z;
    int t = threadIdx.x;
    int lane = t & 63;
    int wave = t >> 6;
    int wm = (wave >> 1) << 6;
    int wn = (wave & 1) << 6;

    __shared__ short As[128][40];  // [co][kk]  kk = ci - ci0
    __shared__ short Bs[128][40];  // [px][kk]

    f32x4 acc[4][4];
    #pragma unroll
    for (int i = 0; i < 4; i++)
        #pragma unroll
        for (int j = 0; j < 4; j++) acc[i][j] = (f32x4){0.f, 0.f, 0.f, 0.f};

    const size_t inb = ((size_t)(in_b0 + lb) * Cin) << 14;
    int lr = lane & 15;
    int kg = (lane >> 4) << 3;

    for (int rr = 0; rr < R*R; rr++) {
        int dy = (R == 3) ? (rr / 3) : 0;
        int dx = (R == 3) ? (rr - dy*3) : 0;
        int yy = (R == 3) ? (y + dy - 1) : y;
        if (R == 3 && (yy < 0 || yy > 127)) continue;
        const float* inrow = in + inb + (yy << 7);
        const short* wslice = wbf + ((size_t)rr * Cout + coBase) * Cin;
        for (int ci0 = 0; ci0 < Cin; ci0 += 32) {
            __syncthreads();
            // stage A: 128 co x 32 kk, vectorized short8
            #pragma unroll
            for (int u = 0; u < 2; u++) {
                int ii = t + (u << 8);
                int co = ii >> 2, cg = ii & 3;
                *(short8*)&As[co][cg << 3] =
                    *(const short8*)&wslice[(size_t)co * Cin + ci0 + (cg << 3)];
            }
            // stage B: 32 kk x 128 px (shifted row), pack 2 ci per 4B write
            for (int i = t; i < 2048; i += 256) {
                int px = i & 127, chp = i >> 7;       // chp 0..15
                int ci = ci0 + (chp << 1);
                float v0 = 0.f, v1 = 0.f;
                int xx = (R == 3) ? (px + dx - 1) : px;
                if (R != 3 || (xx >= 0 && xx < 128)) {
                    v0 = inrow[((size_t)ci << 14) + xx];
                    v1 = inrow[((size_t)(ci + 1) << 14) + xx];
                }
                unsigned u2 = (unsigned)(unsigned short)f2bf(v0)
                            | ((unsigned)(unsigned short)f2bf(v1) << 16);
                *(unsigned*)&Bs[px][chp << 1] = u2;
            }
            __syncthreads();
            short8 af[4], bf[4];
            #pragma unroll
            for (int i = 0; i < 4; i++)
                af[i] = *(const short8*)&As[wm + i*16 + lr][kg];
            #pragma unroll
            for (int j = 0; j < 4; j++)
                bf[j] = *(const short8*)&Bs[wn + j*16 + lr][kg];
            #pragma unroll
            for (int i = 0; i < 4; i++)
                #pragma unroll
                for (int j = 0; j < 4; j++)
                    acc[i][j] = __builtin_amdgcn_mfma_f32_16x16x32_bf16(
                        af[i], bf[j], acc[i][j], 0, 0, 0);
        }
    }

    int pBase = y << 7;
    int mr = (lane >> 4) << 2;
    #pragma unroll
    for (int i = 0; i < 4; i++) {
        #pragma unroll
        for (int r = 0; r < 4; r++) {
            int co = coBase + wm + i*16 + mr + r;
            float vb = bias ? bias[co] : 0.f;
            size_t rowo = (((size_t)(out_b0 + lb) * Cout + co) << 14);
            size_t rowr = (((size_t)(res_b0 + lb) * Cout + co) << 14);
            #pragma unroll
            for (int j = 0; j < 4; j++) {
                int px = pBase + wn + j*16 + lr;
                float v = acc[i][j][r] + vb;
                if (act == 1) v = v / (1.f + expf(-v));
                if (res) v += res[rowr + px];
                out[rowo + px] = v;
            }
        }
    }
}

// ---------------------------------------------------------------------------
extern "C" void kernel_launch(void* const* d_in, const int* in_sizes, int n_in,
                              void* d_out, int out_size, void* d_ws, size_t ws_size,
                              hipStream_t stream) {
    (void)in_sizes; (void)n_in; (void)out_size;
    const float* x    = (const float*)d_in[0];
    const float* gn_w = (const float*)d_in[1];
    const float* gn_b = (const float*)d_in[2];
    const float* dw_w = (const float*)d_in[3];
    const float* pw_w = (const float*)d_in[4];
    const float* pw_b = (const float*)d_in[5];
    const float* ao_w = (const float*)d_in[6];
    const float* ao_b = (const float*)d_in[7];
    const float* f1_w = (const float*)d_in[8];
    const float* f2_w = (const float*)d_in[9];
    const float* f3_w = (const float*)d_in[10];
    const float* f3_b = (const float*)d_in[11];
    float* outp = (float*)d_out;

    // per-batch region sizes in floats
    const size_t F_QKV  = 12582912;   // qkv; later h1 (8,388,608) + h2 (4,194,304)
    const size_t F_SLOT = 2129920;
    const size_t F_SPEC = 6 * F_SLOT;
    const size_t F_XN   = 4194304;
    const size_t F_E    = 4259840;    // max(dw 4,194,304; rre+rim 2x2,129,920)
    const size_t F_SIMP = 262144;     // invn (NB*49,152) then fp64 simpart
    const size_t F_TOT  = F_QKV + F_SPEC + F_XN + F_E + F_SIMP; // 34,078,720
    const size_t F_WB   = 1245184;    // 2,490,368 bf16 weights (fixed, not xNB)

    int NB = 0;
    for (int cand : {8, 4, 2, 1}) {
        if (((size_t)cand * F_TOT + F_WB) * 4 <= ws_size) { NB = cand; break; }
    }
    if (NB == 0) return;

    float* wsf  = (float*)d_ws;
    float* qkv  = wsf;                                  // also h1, h2
    float* h1   = wsf;
    float* h2   = wsf + (size_t)NB * 8388608;
    float* spec = wsf + (size_t)NB * F_QKV;
    size_t ss   = (size_t)NB * F_SLOT;
    float* tre  = spec + 2*ss;
    float* tim  = spec + 3*ss;
    float* spat = spec + 4*ss;
    float* xn   = spec + 6*ss;
    float* ebuf = xn + (size_t)NB * F_XN;               // dw, then rre/rim
    float* dw   = ebuf;
    float* rre  = ebuf;
    float* rim  = ebuf + (size_t)NB * 2129920;
    float* simpf = ebuf + (size_t)NB * F_E;             // invn (floats)
    double* simp = (double*)simpf;                      // fp64 simpart (later)
    float* invn  = simpf;
    short* wb    = (short*)(wsf + (size_t)NB * F_TOT);
    short* wb_ao = wb;
    short* wb_f1 = wb + 65536;
    short* wb_f2 = wb + 1245184;
    short* wb_f3 = wb + 2424832;

    // one-time weight pre-transforms (bf16, [RR][Cout][Cin])
    wcvt_kernel<<<256,  256, 0, stream>>>(ao_w, wb_ao, 256, 256, 1);
    wcvt_kernel<<<4608, 256, 0, stream>>>(f1_w, wb_f1, 512, 256, 9);
    wcvt_kernel<<<4608, 256, 0, stream>>>(f2_w, wb_f2, 256, 512, 9);
    wcvt_kernel<<<256,  256, 0, stream>>>(f3_w, wb_f3, 256, 256, 1);

    const int passes = 8 / NB;
    for (int p = 0; p < passes; p++) {
        int b0 = p * NB;
        // 1. GroupNorm -> xn
        groupnorm_kernel<<<NB*32, 256, 0, stream>>>(x, gn_w, gn_b, xn, b0);
        // 2. depthwise 3x3: xn -> dw
        dwconv_kernel<<<NB*256*64, 256, 0, stream>>>(xn, dw_w, dw);
        // 3. pointwise 256->768 (+bias) fp32: dw -> qkv
        conv_kernel<1><<<dim3(128, 6, NB), 256, 0, stream>>>(
            dw, pw_w, pw_b, nullptr, qkv, 256, 768, 0, 0, 0, 0);
        // 4. inverse L2 norms (scale applied inside fft_row)
        l2inv_kernel<<<NB*3*64, 256, 0, stream>>>(qkv, invn);
        // 5. rfft2 -> amp/phase spec slots, 3 chunks of NB*256 planes
        for (int chunk = 0; chunk < 3; chunk++) {
            fft_row_kernel<<<dim3(8, NB*256), 256, 0, stream>>>(
                qkv, invn, rre, rim, chunk*NB*256);
            fft_col_kernel<<<dim3(5, NB*256), 256, 0, stream>>>(
                rre, rim, spec, chunk*NB*256, ss);
        }
        // 6. channel attention (split-K, fp64 logits)
        attn_sim_kernel<<<dim3(16, NB*8), 256, 0, stream>>>(spec + 0*ss, spec + 2*ss, simp);
        attn_out_kernel<<<dim3(33, NB*8), 256, 0, stream>>>(simp, spec + 4*ss, spec + 0*ss);
        attn_sim_kernel<<<dim3(16, NB*8), 256, 0, stream>>>(spec + 1*ss, spec + 3*ss, simp);
        attn_out_kernel<<<dim3(33, NB*8), 256, 0, stream>>>(simp, spec + 5*ss, spec + 1*ss);
        // 7. irfft2: slots 0,1 -> tre/tim (slots 2,3) -> spat (slots 4-5)
        ifft_col_kernel<<<dim3(5, NB*256), 256, 0, stream>>>(spec + 0*ss, spec + 1*ss,
                                                             tre, tim);
        ifft_row_kernel<<<dim3(8, NB*256), 256, 0, stream>>>(tre, tim, spat);
        // 8. ao 1x1 (+bias) + xn residual -> attn (d_out)      [bf16 MFMA v2]
        convmf2_kernel<1><<<dim3(128, 2, NB), 256, 0, stream>>>(
            spat, wb_ao, ao_b, xn, outp, 256, 256, 0, 0, 0, b0);
        // 9. f1 3x3 256->512 + SiLU                            [bf16 MFMA v2]
        convmf2_kernel<3><<<dim3(128, 4, NB), 256, 0, stream>>>(
            outp, wb_f1, nullptr, nullptr, h1, 256, 512, 1, b0, 0, 0);
        // 10. f2 3x3 512->256                                  [bf16 MFMA v2]
        convmf2_kernel<3><<<dim3(128, 2, NB), 256, 0, stream>>>(
            h1, wb_f2, nullptr, nullptr, h2, 512, 256, 0, 0, 0, 0);
        // 11. f3 1x1 (+bias) + attn residual, in place         [bf16 MFMA v2]
        convmf2_kernel<1><<<dim3(128, 2, NB), 256, 0, stream>>>(
            h2, wb_f3, f3_b, outp, outp, 256, 256, 0, 0, b0, b0);
    }
}

// Round 14
// 8586.337 us; speedup vs baseline: 3.8567x; 1.1256x over previous
//
#include <hip/hip_runtime.h>
#include <hip/hip_bf16.h>
#include <math.h>

// ---------------------------------------------------------------------------
// FreqCA: B=8, C=256, H=W=128, NHEADS=8, GROUPS=32.
// Round 14: (1) attention fp32 (proven bit-identical to fp64 in bf16 space)
// with float4 LDS tiling; (2) convmf3 -- direct-load bf16 MFMA (no LDS) for
// f1/f2/f3 chained via bf16-transposed activations; ao (convmf2) also emits
// the bf16-T buffer. Front-end DFT/conv unchanged from round 13.
// Per-batch float layout: qkv 12,582,912 (later abuf/h1t/h2t bf16T) |
// spec 6x2,129,920 (2,3->tre/tim, 4-5->spat) | xn 4,194,304 |
// ebuf 4,259,840 (dw -> rre/rim) | simp 262,144 (invn / fp32 simpart).
// ---------------------------------------------------------------------------

#define TWO_PI_D 6.283185307179586476925286766559
#define ATTN_SCALE 0.17677669529663687f  // 1/sqrt(32)

typedef __attribute__((ext_vector_type(8))) short short8;
typedef __attribute__((ext_vector_type(4))) short short4v;
typedef __attribute__((ext_vector_type(4))) float f32x4;

__device__ inline short f2bf(float f) {
    __hip_bfloat16 h = __float2bfloat16(f);
    return *reinterpret_cast<short*>(&h);
}

// ---------------- GroupNorm: fp64 stats, fp32 out --------------------------
__global__ __launch_bounds__(256) void groupnorm_kernel(
    const float* __restrict__ x, const float* __restrict__ gw,
    const float* __restrict__ gb, float* __restrict__ out, int b0)
{
    int t = threadIdx.x;
    int lb = blockIdx.x >> 5;
    int g  = blockIdx.x & 31;
    size_t src = ((size_t)(b0 + lb) * 32 + g) * 131072;
    size_t dst = (size_t)blockIdx.x * 131072;
    const float* xp = x + src;
    double s = 0.0, ss = 0.0;
    for (int i = t; i < 131072; i += 256) { double v = xp[i]; s += v; ss += v*v; }
    __shared__ double rs[256], rss[256];
    rs[t] = s; rss[t] = ss;
    __syncthreads();
    for (int k = 128; k > 0; k >>= 1) {
        if (t < k) { rs[t] += rs[t+k]; rss[t] += rss[t+k]; }
        __syncthreads();
    }
    __shared__ float smean, sinv;
    if (t == 0) {
        double mean = rs[0] * (1.0/131072.0);
        double var  = rss[0] * (1.0/131072.0) - mean*mean;
        smean = (float)mean;
        sinv  = (float)(1.0 / sqrt(var + 1e-5));
    }
    __syncthreads();
    float mean = smean, inv = sinv;
    for (int i = t; i < 131072; i += 256) {
        int c = (g << 3) + (i >> 14);
        out[dst + i] = (xp[i] - mean) * inv * gw[c] + gb[c];
    }
}

// ---------------- Depthwise 3x3 fp32 ---------------------------------------
__global__ __launch_bounds__(256) void dwconv_kernel(
    const float* __restrict__ in, const float* __restrict__ w, float* __restrict__ out)
{
    int t = threadIdx.x;
    int bc = blockIdx.x >> 6;
    int y  = ((blockIdx.x & 63) << 1) + (t >> 7);
    int x  = t & 127;
    int c  = bc & 255;
    const float* wp = w + c*9;
    const float* ip = in + ((size_t)bc << 14);
    float acc = 0.f;
    #pragma unroll
    for (int dy = 0; dy < 3; dy++) {
        int yy = y + dy - 1;
        if (yy < 0 || yy > 127) continue;
        const float* row = ip + (yy << 7);
        #pragma unroll
        for (int dx = 0; dx < 3; dx++) {
            int xx = x + dx - 1;
            if (xx >= 0 && xx <= 127) acc += wp[dy*3+dx] * row[xx];
        }
    }
    out[((size_t)bc << 14) + (y << 7) + x] = acc;
}

// ---------------- fp32 tiled implicit-GEMM conv (pw only, R=1) -------------
template<int R>
__global__ __launch_bounds__(256) void conv_kernel(
    const float* __restrict__ in, const float* __restrict__ wt,
    const float* __restrict__ bias, const float* __restrict__ res,
    float* __restrict__ out, int Cin, int Cout, int act,
    int in_b0, int res_b0, int out_b0)
{
    const int K = Cin * R * R;
    int pBase  = blockIdx.x << 7;
    int coBase = blockIdx.y << 7;
    int lb = blockIdx.z;
    int t = threadIdx.x;
    int tx = t & 15, ty = t >> 4;

    __shared__ float As[8][128];
    __shared__ float Bs[8][128];

    float acc[8][8];
    #pragma unroll
    for (int i = 0; i < 8; i++)
        #pragma unroll
        for (int j = 0; j < 8; j++) acc[i][j] = 0.f;

    int a_co = t >> 1;
    int a_k  = (t & 1) << 2;
    int b_k  = t >> 5;
    int b_p  = (t & 31) << 2;
    const float* wrow = wt + (size_t)(coBase + a_co) * K + a_k;
    const size_t inb = ((size_t)(in_b0 + lb) * Cin) << 14;

    for (int k0 = 0; k0 < K; k0 += 8) {
        float4 av = *(const float4*)(wrow + k0);
        int kk = k0 + b_k;
        float4 bv = *(const float4*)(in + inb + ((size_t)kk << 14) + pBase + b_p);
        __syncthreads();
        As[a_k+0][a_co] = av.x; As[a_k+1][a_co] = av.y;
        As[a_k+2][a_co] = av.z; As[a_k+3][a_co] = av.w;
        *(float4*)&Bs[b_k][b_p] = bv;
        __syncthreads();
        #pragma unroll
        for (int k2 = 0; k2 < 8; k2++) {
            float4 A1 = *(const float4*)&As[k2][ty << 2];
            float4 A2 = *(const float4*)&As[k2][64 + (ty << 2)];
            float4 B1 = *(const float4*)&Bs[k2][tx << 2];
            float4 B2 = *(const float4*)&Bs[k2][64 + (tx << 2)];
            float a0[8] = {A1.x,A1.y,A1.z,A1.w,A2.x,A2.y,A2.z,A2.w};
            float b0v[8] = {B1.x,B1.y,B1.z,B1.w,B2.x,B2.y,B2.z,B2.w};
            #pragma unroll
            for (int i = 0; i < 8; i++)
                #pragma unroll
                for (int j = 0; j < 8; j++) acc[i][j] += a0[i] * b0v[j];
        }
    }

    #pragma unroll
    for (int i = 0; i < 8; i++) {
        int co = coBase + ((i < 4) ? ((ty << 2) + i) : (64 + (ty << 2) + i - 4));
        size_t rbo = (((size_t)(out_b0 + lb) * Cout + co) << 14) + pBase;
        size_t rbr = (((size_t)(res_b0 + lb) * Cout + co) << 14) + pBase;
        float vb = bias ? bias[co] : 0.f;
        #pragma unroll
        for (int jh = 0; jh < 2; jh++) {
            int colo = (jh == 0) ? (tx << 2) : (64 + (tx << 2));
            float4 v;
            v.x = acc[i][jh*4+0] + vb;
            v.y = acc[i][jh*4+1] + vb;
            v.z = acc[i][jh*4+2] + vb;
            v.w = acc[i][jh*4+3] + vb;
            if (act == 1) {
                v.x = v.x / (1.f + expf(-v.x));
                v.y = v.y / (1.f + expf(-v.y));
                v.z = v.z / (1.f + expf(-v.z));
                v.w = v.w / (1.f + expf(-v.w));
            }
            if (res) {
                float4 r4 = *(const float4*)(res + rbr + colo);
                v.x += r4.x; v.y += r4.y; v.z += r4.z; v.w += r4.w;
            }
            *(float4*)(out + rbo + colo) = v;
        }
    }
}

// ---------------- inverse L2 norms per pixel (no write-back) ---------------
__global__ __launch_bounds__(256) void l2inv_kernel(
    const float* __restrict__ qkv, float* __restrict__ invn)
{
    int p  = ((blockIdx.x & 63) << 8) + threadIdx.x;
    int bT = blockIdx.x >> 6;          // lb*3 + T
    int lb = bT / 3, T = bT - 3*lb;
    const float* base = qkv + (((size_t)(lb*768 + T*256)) << 14) + p;
    double ss = 0.0;
    for (int c = 0; c < 256; c++) { double v = base[(size_t)c << 14]; ss += v*v; }
    invn[((size_t)bT << 14) + p] = 1.f / fmaxf((float)sqrt(ss), 1e-12f);
}

// ---------------- FFT stage 1: row DFT, invn applied, 4-row tiled ----------
__global__ __launch_bounds__(256) void fft_row_kernel(
    const float* __restrict__ qkv, const float* __restrict__ invn,
    float* __restrict__ rre, float* __restrict__ rim, int chunkBase)
{
    int rc  = blockIdx.x;
    int loc = blockIdx.y;
    int gp  = chunkBase + loc;
    int t   = threadIdx.x;
    __shared__ float xs[16][128];
    __shared__ float ct[128], st[128];
    if (t < 128) { double s, c; sincos(TWO_PI_D * t / 128.0, &s, &c);
                   st[t] = (float)s; ct[t] = (float)c; }
    int lb = gp / 768, chn = gp - lb*768, T = chn >> 8;
    const float4* src = (const float4*)(qkv + ((size_t)gp << 14) + ((size_t)rc << 11));
    const float4* ivp = (const float4*)(invn + (((size_t)(lb*3 + T)) << 14) + ((size_t)rc << 11));
    float4* xd = (float4*)xs;
    for (int i = t; i < 512; i += 256) {
        float4 v = src[i], w = ivp[i];
        v.x *= w.x; v.y *= w.y; v.z *= w.z; v.w *= w.w;
        xd[i] = v;
    }
    __syncthreads();
    for (int oo = t; oo < 260; oo += 256) {
        int k = oo % 65, rq = oo / 65;
        const float* x0 = xs[rq*4+0];
        const float* x1 = xs[rq*4+1];
        const float* x2 = xs[rq*4+2];
        const float* x3 = xs[rq*4+3];
        float re0=0,re1=0,re2=0,re3=0, im0=0,im1=0,im2=0,im3=0;
        int m = 0;
        for (int w = 0; w < 128; w++) {
            float cc = ct[m], sn = st[m];
            float a0 = x0[w], a1 = x1[w], a2 = x2[w], a3 = x3[w];
            re0 += a0*cc; im0 -= a0*sn;
            re1 += a1*cc; im1 -= a1*sn;
            re2 += a2*cc; im2 -= a2*sn;
            re3 += a3*cc; im3 -= a3*sn;
            m = (m + k) & 127;
        }
        size_t base = ((size_t)loc*128 + rc*16 + rq*4)*65 + k;
        rre[base]       = re0*0.0078125f; rim[base]       = im0*0.0078125f;
        rre[base + 65]  = re1*0.0078125f; rim[base + 65]  = im1*0.0078125f;
        rre[base + 130] = re2*0.0078125f; rim[base + 130] = im2*0.0078125f;
        rre[base + 195] = re3*0.0078125f; rim[base + 195] = im3*0.0078125f;
    }
}

// ---------------- FFT stage 2: col DFT -> amp/phase, 4-kx float4 tiled -----
__global__ __launch_bounds__(256) void fft_col_kernel(
    const float* __restrict__ rre, const float* __restrict__ rim,
    float* __restrict__ spec, int chunkBase, size_t slotStride)
{
    int kb  = blockIdx.x * 13;
    int loc = blockIdx.y;
    int gp  = chunkBase + loc;
    int t   = threadIdx.x;
    __shared__ float cr[128][16], ci_[128][16];
    __shared__ float ct[128], st[128];
    if (t < 128) { double s, c; sincos(TWO_PI_D * t / 128.0, &s, &c);
                   st[t] = (float)s; ct[t] = (float)c; }
    for (int i = t; i < 2048; i += 256) {
        int r = i >> 4, k = i & 15;
        float a = 0.f, b = 0.f;
        if (k < 13) {
            size_t si = ((size_t)loc*128 + r)*65 + kb + k;
            a = rre[si]; b = rim[si];
        }
        cr[r][k] = a; ci_[r][k] = b;
    }
    __syncthreads();
    int lb = gp / 768; int chn = gp - lb*768;
    int T = chn >> 8;  int c = chn & 255;
    float* aD = spec + (size_t)(2*T)   * slotStride + ((size_t)(lb*256 + c))*8320;
    float* pD = spec + (size_t)(2*T+1) * slotStride + ((size_t)(lb*256 + c))*8320;
    for (int oo = t; oo < 512; oo += 256) {
        int k1 = oo >> 2, g4 = (oo & 3) << 2;
        float re[4] = {0,0,0,0}, im[4] = {0,0,0,0};
        int m = 0;
        for (int r = 0; r < 128; r++) {
            float cc = ct[m], sn = st[m];
            float4 a4 = *(const float4*)&cr[r][g4];
            float4 b4 = *(const float4*)&ci_[r][g4];
            re[0] += a4.x*cc + b4.x*sn; im[0] += b4.x*cc - a4.x*sn;
            re[1] += a4.y*cc + b4.y*sn; im[1] += b4.y*cc - a4.y*sn;
            re[2] += a4.z*cc + b4.z*sn; im[2] += b4.z*cc - a4.z*sn;
            re[3] += a4.w*cc + b4.w*sn; im[3] += b4.w*cc - a4.w*sn;
            m = (m + k1) & 127;
        }
        #pragma unroll
        for (int j = 0; j < 4; j++) {
            int kx = g4 + j;
            if (kx < 13) {
                int kxv = kb + kx;
                float rr2 = re[j], ii2 = im[j];
                // Self-conjugate rfft2 bins: im structurally zero; pocketfft
                // gives exact +0.0 -> angle in {0,+pi}. Force +0.0 so atan2
                // never flips to -pi (decorrelates phase attention).
                if ((k1 == 0 || k1 == 64) && (kxv == 0 || kxv == 64)) ii2 = 0.f;
                int oi = k1*65 + kxv;
                aD[oi] = sqrtf(rr2*rr2 + ii2*ii2);
                pD[oi] = atan2f(ii2, rr2);
            }
        }
    }
}

// ---------------- Attention: split-K partial sims (fp32, float4 LDS) -------
__global__ __launch_bounds__(256) void attn_sim_kernel(
    const float* __restrict__ qA, const float* __restrict__ kA,
    float* __restrict__ simpart)
{
    int sp = blockIdx.x;           // 0..15
    int bh = blockIdx.y;           // lb*8 + h
    int lb = bh >> 3, h = bh & 7;
    int t = threadIdx.x;
    __shared__ float qs[32][132], ks[32][132];
    const float* qb = qA + ((size_t)(lb*256 + h*32)) * 8320;
    const float* kb = kA + ((size_t)(lb*256 + h*32)) * 8320;
    float acc[4] = {0.f, 0.f, 0.f, 0.f};
    int j0 = t >> 5;
    int kq = t & 31;
    for (int sub = 0; sub < 4; sub++) {
        int n0 = sp*520 + sub*130;
        __syncthreads();
        for (int i = t; i < 4160; i += 256) {
            int j = i / 130, nn = i - j*130;
            qs[j][nn] = qb[(size_t)j*8320 + n0 + nn];
            ks[j][nn] = kb[(size_t)j*8320 + n0 + nn];
        }
        __syncthreads();
        for (int nn = 0; nn < 128; nn += 4) {
            float4 kv = *(const float4*)&ks[kq][nn];
            #pragma unroll
            for (int e = 0; e < 4; e++) {
                float4 qv = *(const float4*)&qs[j0 + e*8][nn];
                acc[e] += qv.x*kv.x + qv.y*kv.y + qv.z*kv.z + qv.w*kv.w;
            }
        }
        {
            float2 kv = *(const float2*)&ks[kq][128];
            #pragma unroll
            for (int e = 0; e < 4; e++) {
                float2 qv = *(const float2*)&qs[j0 + e*8][128];
                acc[e] += qv.x*kv.x + qv.y*kv.y;
            }
        }
    }
    float* dst = simpart + ((size_t)bh*16 + sp) * 1024;
    dst[t]       = acc[0];
    dst[t + 256] = acc[1];
    dst[t + 512] = acc[2];
    dst[t + 768] = acc[3];
}

// ---------------- Attention: reduce + softmax + PV (fp32) ------------------
__global__ __launch_bounds__(256) void attn_out_kernel(
    const float* __restrict__ simpart, const float* __restrict__ vA,
    float* __restrict__ outA)
{
    int nb = blockIdx.x << 8;
    int bh = blockIdx.y;
    int lb = bh >> 3, h = bh & 7;
    int t = threadIdx.x;
    __shared__ float sim[32][32];
    for (int e = t; e < 1024; e += 256) {
        float s = 0.f;
        const float* pp = simpart + (size_t)bh*16384 + e;
        #pragma unroll
        for (int sp = 0; sp < 16; sp++) s += pp[sp*1024];
        sim[e >> 5][e & 31] = s * ATTN_SCALE;
    }
    __syncthreads();
    if (t < 32) {
        float m = -1e30f;
        for (int k = 0; k < 32; k++) m = fmaxf(m, sim[t][k]);
        float s = 0.f;
        for (int k = 0; k < 32; k++) s += expf(sim[t][k] - m);
        float inv = 1.f / s;
        for (int k = 0; k < 32; k++) sim[t][k] = expf(sim[t][k] - m) * inv;
    }
    __syncthreads();
    int n = nb + t;
    if (n >= 8320) return;
    const float* vb = vA + ((size_t)(lb*256 + h*32)) * 8320 + n;
    float vv[32];
    #pragma unroll
    for (int k = 0; k < 32; k++) vv[k] = vb[(size_t)k * 8320];
    float* ob = outA + ((size_t)(lb*256 + h*32)) * 8320 + n;
    for (int j = 0; j < 32; j++) {
        float o = 0.f;
        #pragma unroll
        for (int k = 0; k < 32; k++) o += sim[j][k] * vv[k];
        ob[(size_t)j * 8320] = o;
    }
}

// ---------------- iFFT stage 1: col inverse, 4-kx float4 tiled -------------
__global__ __launch_bounds__(256) void ifft_col_kernel(
    const float* __restrict__ ampo, const float* __restrict__ pho,
    float* __restrict__ tre, float* __restrict__ tim)
{
    int kb    = blockIdx.x * 13;
    int plane = blockIdx.y;
    int t     = threadIdx.x;
    __shared__ float cr[128][16], ci_[128][16];
    __shared__ float ct[128], st[128];
    if (t < 128) { double s, c; sincos(TWO_PI_D * t / 128.0, &s, &c);
                   st[t] = (float)s; ct[t] = (float)c; }
    const float* ab = ampo + (size_t)plane * 8320;
    const float* pb = pho  + (size_t)plane * 8320;
    for (int i = t; i < 2048; i += 256) {
        int k1 = i >> 4, k = i & 15;
        float xr = 0.f, xi = 0.f;
        if (k < 13) {
            float a = ab[k1*65 + kb + k];
            float p = pb[k1*65 + kb + k];
            float sp, cp; sincosf(p, &sp, &cp);
            xr = a * cp; xi = a * sp;
        }
        cr[k1][k] = xr; ci_[k1][k] = xi;
    }
    __syncthreads();
    for (int oo = t; oo < 512; oo += 256) {
        int y = oo >> 2, g4 = (oo & 3) << 2;
        float re[4] = {0,0,0,0}, im[4] = {0,0,0,0};
        int m = 0;
        for (int k1 = 0; k1 < 128; k1++) {
            float cc = ct[m], sn = st[m];
            float4 a4 = *(const float4*)&cr[k1][g4];
            float4 b4 = *(const float4*)&ci_[k1][g4];
            re[0] += a4.x*cc - b4.x*sn; im[0] += a4.x*sn + b4.x*cc;
            re[1] += a4.y*cc - b4.y*sn; im[1] += a4.y*sn + b4.y*cc;
            re[2] += a4.z*cc - b4.z*sn; im[2] += a4.z*sn + b4.z*cc;
            re[3] += a4.w*cc - b4.w*sn; im[3] += a4.w*sn + b4.w*cc;
            m = (m + y) & 127;
        }
        #pragma unroll
        for (int j = 0; j < 4; j++) {
            int kx = g4 + j;
            if (kx < 13) {
                size_t oi = ((size_t)plane*128 + y)*65 + kb + kx;
                tre[oi] = re[j];
                tim[oi] = im[j];
            }
        }
    }
}

// ---------------- iFFT stage 2: Hermitian rows, 4-row tiled ----------------
__global__ __launch_bounds__(256) void ifft_row_kernel(
    const float* __restrict__ tre, const float* __restrict__ tim,
    float* __restrict__ spat)
{
    int rc    = blockIdx.x;
    int plane = blockIdx.y;
    int t     = threadIdx.x;
    __shared__ float tr[16][65], ti[16][65];
    __shared__ float ct[128], st[128];
    if (t < 128) { double s, c; sincos(TWO_PI_D * t / 128.0, &s, &c);
                   st[t] = (float)s; ct[t] = (float)c; }
    for (int i = t; i < 1040; i += 256) {
        int r = i / 65, k = i - r*65;
        size_t si = ((size_t)plane*128 + rc*16 + r)*65 + k;
        tr[r][k] = tre[si];
        ti[r][k] = tim[si];
    }
    __syncthreads();
    for (int oo = t; oo < 512; oo += 256) {
        int x = oo & 127, r0 = (oo >> 7) << 2;
        float a0 = tr[r0][0], a1 = tr[r0+1][0], a2 = tr[r0+2][0], a3 = tr[r0+3][0];
        int m = x;
        for (int k = 1; k < 64; k++) {
            float cc = ct[m], sn = st[m];
            a0 += 2.f*(tr[r0  ][k]*cc - ti[r0  ][k]*sn);
            a1 += 2.f*(tr[r0+1][k]*cc - ti[r0+1][k]*sn);
            a2 += 2.f*(tr[r0+2][k]*cc - ti[r0+2][k]*sn);
            a3 += 2.f*(tr[r0+3][k]*cc - ti[r0+3][k]*sn);
            m = (m + x) & 127;
        }
        float cc = ct[m], sn = st[m];
        a0 += tr[r0  ][64]*cc - ti[r0  ][64]*sn;
        a1 += tr[r0+1][64]*cc - ti[r0+1][64]*sn;
        a2 += tr[r0+2][64]*cc - ti[r0+2][64]*sn;
        a3 += tr[r0+3][64]*cc - ti[r0+3][64]*sn;
        size_t ob = ((size_t)plane << 14) + ((rc*16 + r0) << 7) + x;
        spat[ob]       = a0*0.0078125f;
        spat[ob + 128] = a1*0.0078125f;
        spat[ob + 256] = a2*0.0078125f;
        spat[ob + 384] = a3*0.0078125f;
    }
}

// ---------------- weight pre-transform: fp32 [Co][Ci][R][R] -> bf16 [RR][Co][Ci]
__global__ __launch_bounds__(256) void wcvt_kernel(
    const float* __restrict__ w, short* __restrict__ wbf,
    int Cout, int Cin, int RR)
{
    int i = blockIdx.x * 256 + threadIdx.x;
    int total = Cout * Cin * RR;
    if (i >= total) return;
    int rr = i % RR;
    int ci = (i / RR) % Cin;
    int co = i / (RR * Cin);
    wbf[((size_t)rr * Cout + co) * Cin + ci] = f2bf(w[i]);
}

// ---------------- bf16 MFMA conv v2 (ao: fp32 in, LDS staged) --------------
// Adds bf16-T output (out_t, lb-local [16384][Cout]) for the f1 consumer.
__global__ __launch_bounds__(256) void convmf2_kernel(
    const float* __restrict__ in, const short* __restrict__ wbf,
    const float* __restrict__ bias, const float* __restrict__ res,
    float* __restrict__ out, short* __restrict__ out_t,
    int Cin, int Cout, int act, int in_b0, int res_b0, int out_b0)
{
    int y      = blockIdx.x;
    int coBase = blockIdx.y << 7;
    int lb = blockIdx.z;
    int t = threadIdx.x;
    int lane = t & 63;
    int wave = t >> 6;
    int wm = (wave >> 1) << 6;
    int wn = (wave & 1) << 6;

    __shared__ short As[128][40];
    __shared__ short Bs[128][40];

    f32x4 acc[4][4];
    #pragma unroll
    for (int i = 0; i < 4; i++)
        #pragma unroll
        for (int j = 0; j < 4; j++) acc[i][j] = (f32x4){0.f, 0.f, 0.f, 0.f};

    const size_t inb = ((size_t)(in_b0 + lb) * Cin) << 14;
    int lr = lane & 15;
    int kg = (lane >> 4) << 3;

    const float* inrow = in + inb + (y << 7);
    const short* wslice = wbf + (size_t)coBase * Cin;
    for (int ci0 = 0; ci0 < Cin; ci0 += 32) {
        __syncthreads();
        #pragma unroll
        for (int u = 0; u < 2; u++) {
            int ii = t + (u << 8);
            int co = ii >> 2, cg = ii & 3;
            *(short8*)&As[co][cg << 3] =
                *(const short8*)&wslice[(size_t)co * Cin + ci0 + (cg << 3)];
        }
        for (int i = t; i < 2048; i += 256) {
            int px = i & 127, chp = i >> 7;
            int ci = ci0 + (chp << 1);
            float v0 = inrow[((size_t)ci << 14) + px];
            float v1 = inrow[((size_t)(ci + 1) << 14) + px];
            unsigned u2 = (unsigned)(unsigned short)f2bf(v0)
                        | ((unsigned)(unsigned short)f2bf(v1) << 16);
            *(unsigned*)&Bs[px][chp << 1] = u2;
        }
        __syncthreads();
        short8 af[4], bf[4];
        #pragma unroll
        for (int i = 0; i < 4; i++)
            af[i] = *(const short8*)&As[wm + i*16 + lr][kg];
        #pragma unroll
        for (int j = 0; j < 4; j++)
            bf[j] = *(const short8*)&Bs[wn + j*16 + lr][kg];
        #pragma unroll
        for (int i = 0; i < 4; i++)
            #pragma unroll
            for (int j = 0; j < 4; j++)
                acc[i][j] = __builtin_amdgcn_mfma_f32_16x16x32_bf16(
                    af[i], bf[j], acc[i][j], 0, 0, 0);
    }

    int pBase = y << 7;
    int mr = (lane >> 4) << 2;
    #pragma unroll
    for (int i = 0; i < 4; i++) {
        int co0 = coBase + wm + i*16 + mr;
        #pragma unroll
        for (int j = 0; j < 4; j++) {
            int px = pBase + wn + j*16 + lr;
            float v[4];
            #pragma unroll
            for (int r = 0; r < 4; r++) {
                float vv = acc[i][j][r] + (bias ? bias[co0 + r] : 0.f);
                if (act == 1) vv = vv / (1.f + expf(-vv));
                if (res) vv += res[(((size_t)(res_b0 + lb) * Cout + co0 + r) << 14) + px];
                v[r] = vv;
            }
            if (out) {
                #pragma unroll
                for (int r = 0; r < 4; r++)
                    out[(((size_t)(out_b0 + lb) * Cout + co0 + r) << 14) + px] = v[r];
            }
            if (out_t) {
                short4v s4 = { f2bf(v[0]), f2bf(v[1]), f2bf(v[2]), f2bf(v[3]) };
                *(short4v*)&out_t[((size_t)(lb*16384 + px)) * Cout + co0] = s4;
            }
        }
    }
}

// ---------------- bf16 MFMA conv v3: direct-load, bf16T activations --------
// in_t: lb-local bf16T [16384][Cin]; no LDS, no barriers.
template<int R>
__global__ __launch_bounds__(256) void convmf3_kernel(
    const short* __restrict__ in_t, const short* __restrict__ wbf,
    const float* __restrict__ bias, const float* __restrict__ res,
    float* __restrict__ out, short* __restrict__ out_t,
    int Cin, int Cout, int act, int res_b0, int out_b0)
{
    int y      = blockIdx.x;
    int coBase = blockIdx.y << 7;
    int lb = blockIdx.z;
    int t = threadIdx.x;
    int lane = t & 63;
    int wave = t >> 6;
    int wm = (wave >> 1) << 6;
    int wn = (wave & 1) << 6;
    int lr = lane & 15;
    int kg = (lane >> 4) << 3;

    f32x4 acc[4][4];
    #pragma unroll
    for (int i = 0; i < 4; i++)
        #pragma unroll
        for (int j = 0; j < 4; j++) acc[i][j] = (f32x4){0.f, 0.f, 0.f, 0.f};

    const short* inb = in_t + (((size_t)lb << 14)) * Cin;
    const short8 zero8 = {0,0,0,0,0,0,0,0};

    for (int rr = 0; rr < R*R; rr++) {
        int dy = (R == 3) ? (rr / 3) : 0;
        int dx = (R == 3) ? (rr - dy*3) : 0;
        int yy = (R == 3) ? (y + dy - 1) : y;
        if (R == 3 && (yy < 0 || yy > 127)) continue;
        const short* wsl  = wbf + ((size_t)rr * Cout + coBase) * Cin;
        const short* brow = inb + ((size_t)(yy << 7)) * Cin;
        for (int ci0 = 0; ci0 < Cin; ci0 += 32) {
            short8 af[4], bf[4];
            #pragma unroll
            for (int i = 0; i < 4; i++)
                af[i] = *(const short8*)&wsl[(size_t)(wm + i*16 + lr) * Cin + ci0 + kg];
            #pragma unroll
            for (int j = 0; j < 4; j++) {
                int pxl = wn + j*16 + lr;
                int xx = (R == 3) ? (pxl + dx - 1) : pxl;
                if (R == 3 && (xx < 0 || xx > 127)) bf[j] = zero8;
                else bf[j] = *(const short8*)&brow[(size_t)xx * Cin + ci0 + kg];
            }
            #pragma unroll
            for (int i = 0; i < 4; i++)
                #pragma unroll
                for (int j = 0; j < 4; j++)
                    acc[i][j] = __builtin_amdgcn_mfma_f32_16x16x32_bf16(
                        af[i], bf[j], acc[i][j], 0, 0, 0);
        }
    }

    int pBase = y << 7;
    int mr = (lane >> 4) << 2;
    #pragma unroll
    for (int i = 0; i < 4; i++) {
        int co0 = coBase + wm + i*16 + mr;
        #pragma unroll
        for (int j = 0; j < 4; j++) {
            int px = pBase + wn + j*16 + lr;
            float v[4];
            #pragma unroll
            for (int r = 0; r < 4; r++) {
                float vv = acc[i][j][r] + (bias ? bias[co0 + r] : 0.f);
                if (act == 1) vv = vv / (1.f + expf(-vv));
                if (res) vv += res[(((size_t)(res_b0 + lb) * Cout + co0 + r) << 14) + px];
                v[r] = vv;
            }
            if (out) {
                #pragma unroll
                for (int r = 0; r < 4; r++)
                    out[(((size_t)(out_b0 + lb) * Cout + co0 + r) << 14) + px] = v[r];
            }
            if (out_t) {
                short4v s4 = { f2bf(v[0]), f2bf(v[1]), f2bf(v[2]), f2bf(v[3]) };
                *(short4v*)&out_t[((size_t)(lb*16384 + px)) * Cout + co0] = s4;
            }
        }
    }
}

// ---------------------------------------------------------------------------
extern "C" void kernel_launch(void* const* d_in, const int* in_sizes, int n_in,
                              void* d_out, int out_size, void* d_ws, size_t ws_size,
                              hipStream_t stream) {
    (void)in_sizes; (void)n_in; (void)out_size;
    const float* x    = (const float*)d_in[0];
    const float* gn_w = (const float*)d_in[1];
    const float* gn_b = (const float*)d_in[2];
    const float* dw_w = (const float*)d_in[3];
    const float* pw_w = (const float*)d_in[4];
    const float* pw_b = (const float*)d_in[5];
    const float* ao_w = (const float*)d_in[6];
    const float* ao_b = (const float*)d_in[7];
    const float* f1_w = (const float*)d_in[8];
    const float* f2_w = (const float*)d_in[9];
    const float* f3_w = (const float*)d_in[10];
    const float* f3_b = (const float*)d_in[11];
    float* outp = (float*)d_out;

    // per-batch region sizes in floats
    const size_t F_QKV  = 12582912;   // qkv; later abuf/h1t/h2t (bf16T)
    const size_t F_SLOT = 2129920;
    const size_t F_SPEC = 6 * F_SLOT;
    const size_t F_XN   = 4194304;
    const size_t F_E    = 4259840;    // max(dw; rre+rim)
    const size_t F_SIMP = 262144;     // invn / fp32 simpart
    const size_t F_TOT  = F_QKV + F_SPEC + F_XN + F_E + F_SIMP; // 34,078,720
    const size_t F_WB   = 1245184;    // bf16 weights (fixed)

    int NB = 0;
    for (int cand : {8, 4, 2, 1}) {
        if (((size_t)cand * F_TOT + F_WB) * 4 <= ws_size) { NB = cand; break; }
    }
    if (NB == 0) return;

    float* wsf  = (float*)d_ws;
    float* qkv  = wsf;
    short* abuf = (short*)wsf;                           // [NB][16384][256]
    short* h1t  = (short*)(wsf + (size_t)NB * 2097152);  // [NB][16384][512]
    short* h2t  = (short*)(wsf + (size_t)NB * 6291456);  // [NB][16384][256]
    float* spec = wsf + (size_t)NB * F_QKV;
    size_t ss   = (size_t)NB * F_SLOT;
    float* tre  = spec + 2*ss;
    float* tim  = spec + 3*ss;
    float* spat = spec + 4*ss;
    float* xn   = spec + 6*ss;
    float* ebuf = xn + (size_t)NB * F_XN;
    float* dw   = ebuf;
    float* rre  = ebuf;
    float* rim  = ebuf + (size_t)NB * 2129920;
    float* simpf = ebuf + (size_t)NB * F_E;
    float* invn  = simpf;
    float* simp  = simpf;
    short* wb    = (short*)(wsf + (size_t)NB * F_TOT);
    short* wb_ao = wb;
    short* wb_f1 = wb + 65536;
    short* wb_f2 = wb + 1245184;
    short* wb_f3 = wb + 2424832;

    wcvt_kernel<<<256,  256, 0, stream>>>(ao_w, wb_ao, 256, 256, 1);
    wcvt_kernel<<<4608, 256, 0, stream>>>(f1_w, wb_f1, 512, 256, 9);
    wcvt_kernel<<<4608, 256, 0, stream>>>(f2_w, wb_f2, 256, 512, 9);
    wcvt_kernel<<<256,  256, 0, stream>>>(f3_w, wb_f3, 256, 256, 1);

    const int passes = 8 / NB;
    for (int p = 0; p < passes; p++) {
        int b0 = p * NB;
        // 1. GroupNorm -> xn
        groupnorm_kernel<<<NB*32, 256, 0, stream>>>(x, gn_w, gn_b, xn, b0);
        // 2. depthwise 3x3: xn -> dw
        dwconv_kernel<<<NB*256*64, 256, 0, stream>>>(xn, dw_w, dw);
        // 3. pointwise 256->768 (+bias) fp32: dw -> qkv
        conv_kernel<1><<<dim3(128, 6, NB), 256, 0, stream>>>(
            dw, pw_w, pw_b, nullptr, qkv, 256, 768, 0, 0, 0, 0);
        // 4. inverse L2 norms (applied inside fft_row)
        l2inv_kernel<<<NB*3*64, 256, 0, stream>>>(qkv, invn);
        // 5. rfft2 -> amp/phase spec slots, 3 chunks of NB*256 planes
        for (int chunk = 0; chunk < 3; chunk++) {
            fft_row_kernel<<<dim3(8, NB*256), 256, 0, stream>>>(
                qkv, invn, rre, rim, chunk*NB*256);
            fft_col_kernel<<<dim3(5, NB*256), 256, 0, stream>>>(
                rre, rim, spec, chunk*NB*256, ss);
        }
        // 6. channel attention (split-K, fp32)
        attn_sim_kernel<<<dim3(16, NB*8), 256, 0, stream>>>(spec + 0*ss, spec + 2*ss, simp);
        attn_out_kernel<<<dim3(33, NB*8), 256, 0, stream>>>(simp, spec + 4*ss, spec + 0*ss);
        attn_sim_kernel<<<dim3(16, NB*8), 256, 0, stream>>>(spec + 1*ss, spec + 3*ss, simp);
        attn_out_kernel<<<dim3(33, NB*8), 256, 0, stream>>>(simp, spec + 5*ss, spec + 1*ss);
        // 7. irfft2: slots 0,1 -> tre/tim (slots 2,3) -> spat (slots 4-5)
        ifft_col_kernel<<<dim3(5, NB*256), 256, 0, stream>>>(spec + 0*ss, spec + 1*ss,
                                                             tre, tim);
        ifft_row_kernel<<<dim3(8, NB*256), 256, 0, stream>>>(tre, tim, spat);
        // 8. ao 1x1 (+bias) + xn residual -> d_out fp32 + abuf bf16T
        convmf2_kernel<<<dim3(128, 2, NB), 256, 0, stream>>>(
            spat, wb_ao, ao_b, xn, outp, abuf, 256, 256, 0, 0, 0, b0);
        // 9. f1 3x3 256->512 + SiLU: abuf -> h1t (bf16T only)   [direct-load]
        convmf3_kernel<3><<<dim3(128, 4, NB), 256, 0, stream>>>(
            abuf, wb_f1, nullptr, nullptr, nullptr, h1t, 256, 512, 1, 0, 0);
        // 10. f2 3x3 512->256: h1t -> h2t                        [direct-load]
        convmf3_kernel<3><<<dim3(128, 2, NB), 256, 0, stream>>>(
            h1t, wb_f2, nullptr, nullptr, nullptr, h2t, 512, 256, 0, 0, 0);
        // 11. f3 1x1 (+bias) + attn residual -> d_out fp32       [direct-load]
        convmf3_kernel<1><<<dim3(128, 2, NB), 256, 0, stream>>>(
            h2t, wb_f3, f3_b, outp, outp, nullptr, 256, 256, 0, b0, b0);
    }
}

// Round 15
// 7163.754 us; speedup vs baseline: 4.6226x; 1.1986x over previous
//
#include <hip/hip_runtime.h>
#include <hip/hip_bf16.h>
#include <math.h>

// ---------------------------------------------------------------------------
// FreqCA: B=8, C=256, H=W=128, NHEADS=8, GROUPS=32.
// Round 15: DFT factorizations. fft_row real-input even/odd fold (2x);
// ifft_row Hermitian output fold (2x); fft_col/ifft_col radix-16x8 two-stage
// (5.3x). Attention fp32 split-K, tail bf16 MFMA (convmf2/convmf3), fp32 pw.
// Self-conjugate rfft2 bins forced im=+0.0 (pocketfft +pi convention).
// Layout identical to round 14.
// ---------------------------------------------------------------------------

#define TWO_PI_D 6.283185307179586476925286766559
#define ATTN_SCALE 0.17677669529663687f  // 1/sqrt(32)

typedef __attribute__((ext_vector_type(8))) short short8;
typedef __attribute__((ext_vector_type(4))) short short4v;
typedef __attribute__((ext_vector_type(4))) float f32x4;

__device__ inline short f2bf(float f) {
    __hip_bfloat16 h = __float2bfloat16(f);
    return *reinterpret_cast<short*>(&h);
}

// ---------------- GroupNorm: fp64 stats, fp32 out --------------------------
__global__ __launch_bounds__(256) void groupnorm_kernel(
    const float* __restrict__ x, const float* __restrict__ gw,
    const float* __restrict__ gb, float* __restrict__ out, int b0)
{
    int t = threadIdx.x;
    int lb = blockIdx.x >> 5;
    int g  = blockIdx.x & 31;
    size_t src = ((size_t)(b0 + lb) * 32 + g) * 131072;
    size_t dst = (size_t)blockIdx.x * 131072;
    const float* xp = x + src;
    double s = 0.0, ss = 0.0;
    for (int i = t; i < 131072; i += 256) { double v = xp[i]; s += v; ss += v*v; }
    __shared__ double rs[256], rss[256];
    rs[t] = s; rss[t] = ss;
    __syncthreads();
    for (int k = 128; k > 0; k >>= 1) {
        if (t < k) { rs[t] += rs[t+k]; rss[t] += rss[t+k]; }
        __syncthreads();
    }
    __shared__ float smean, sinv;
    if (t == 0) {
        double mean = rs[0] * (1.0/131072.0);
        double var  = rss[0] * (1.0/131072.0) - mean*mean;
        smean = (float)mean;
        sinv  = (float)(1.0 / sqrt(var + 1e-5));
    }
    __syncthreads();
    float mean = smean, inv = sinv;
    for (int i = t; i < 131072; i += 256) {
        int c = (g << 3) + (i >> 14);
        out[dst + i] = (xp[i] - mean) * inv * gw[c] + gb[c];
    }
}

// ---------------- Depthwise 3x3 fp32 ---------------------------------------
__global__ __launch_bounds__(256) void dwconv_kernel(
    const float* __restrict__ in, const float* __restrict__ w, float* __restrict__ out)
{
    int t = threadIdx.x;
    int bc = blockIdx.x >> 6;
    int y  = ((blockIdx.x & 63) << 1) + (t >> 7);
    int x  = t & 127;
    int c  = bc & 255;
    const float* wp = w + c*9;
    const float* ip = in + ((size_t)bc << 14);
    float acc = 0.f;
    #pragma unroll
    for (int dy = 0; dy < 3; dy++) {
        int yy = y + dy - 1;
        if (yy < 0 || yy > 127) continue;
        const float* row = ip + (yy << 7);
        #pragma unroll
        for (int dx = 0; dx < 3; dx++) {
            int xx = x + dx - 1;
            if (xx >= 0 && xx <= 127) acc += wp[dy*3+dx] * row[xx];
        }
    }
    out[((size_t)bc << 14) + (y << 7) + x] = acc;
}

// ---------------- fp32 tiled implicit-GEMM conv (pw only, R=1) -------------
template<int R>
__global__ __launch_bounds__(256) void conv_kernel(
    const float* __restrict__ in, const float* __restrict__ wt,
    const float* __restrict__ bias, const float* __restrict__ res,
    float* __restrict__ out, int Cin, int Cout, int act,
    int in_b0, int res_b0, int out_b0)
{
    const int K = Cin * R * R;
    int pBase  = blockIdx.x << 7;
    int coBase = blockIdx.y << 7;
    int lb = blockIdx.z;
    int t = threadIdx.x;
    int tx = t & 15, ty = t >> 4;

    __shared__ float As[8][128];
    __shared__ float Bs[8][128];

    float acc[8][8];
    #pragma unroll
    for (int i = 0; i < 8; i++)
        #pragma unroll
        for (int j = 0; j < 8; j++) acc[i][j] = 0.f;

    int a_co = t >> 1;
    int a_k  = (t & 1) << 2;
    int b_k  = t >> 5;
    int b_p  = (t & 31) << 2;
    const float* wrow = wt + (size_t)(coBase + a_co) * K + a_k;
    const size_t inb = ((size_t)(in_b0 + lb) * Cin) << 14;

    for (int k0 = 0; k0 < K; k0 += 8) {
        float4 av = *(const float4*)(wrow + k0);
        int kk = k0 + b_k;
        float4 bv = *(const float4*)(in + inb + ((size_t)kk << 14) + pBase + b_p);
        __syncthreads();
        As[a_k+0][a_co] = av.x; As[a_k+1][a_co] = av.y;
        As[a_k+2][a_co] = av.z; As[a_k+3][a_co] = av.w;
        *(float4*)&Bs[b_k][b_p] = bv;
        __syncthreads();
        #pragma unroll
        for (int k2 = 0; k2 < 8; k2++) {
            float4 A1 = *(const float4*)&As[k2][ty << 2];
            float4 A2 = *(const float4*)&As[k2][64 + (ty << 2)];
            float4 B1 = *(const float4*)&Bs[k2][tx << 2];
            float4 B2 = *(const float4*)&Bs[k2][64 + (tx << 2)];
            float a0[8] = {A1.x,A1.y,A1.z,A1.w,A2.x,A2.y,A2.z,A2.w};
            float b0v[8] = {B1.x,B1.y,B1.z,B1.w,B2.x,B2.y,B2.z,B2.w};
            #pragma unroll
            for (int i = 0; i < 8; i++)
                #pragma unroll
                for (int j = 0; j < 8; j++) acc[i][j] += a0[i] * b0v[j];
        }
    }

    #pragma unroll
    for (int i = 0; i < 8; i++) {
        int co = coBase + ((i < 4) ? ((ty << 2) + i) : (64 + (ty << 2) + i - 4));
        size_t rbo = (((size_t)(out_b0 + lb) * Cout + co) << 14) + pBase;
        size_t rbr = (((size_t)(res_b0 + lb) * Cout + co) << 14) + pBase;
        float vb = bias ? bias[co] : 0.f;
        #pragma unroll
        for (int jh = 0; jh < 2; jh++) {
            int colo = (jh == 0) ? (tx << 2) : (64 + (tx << 2));
            float4 v;
            v.x = acc[i][jh*4+0] + vb;
            v.y = acc[i][jh*4+1] + vb;
            v.z = acc[i][jh*4+2] + vb;
            v.w = acc[i][jh*4+3] + vb;
            if (act == 1) {
                v.x = v.x / (1.f + expf(-v.x));
                v.y = v.y / (1.f + expf(-v.y));
                v.z = v.z / (1.f + expf(-v.z));
                v.w = v.w / (1.f + expf(-v.w));
            }
            if (res) {
                float4 r4 = *(const float4*)(res + rbr + colo);
                v.x += r4.x; v.y += r4.y; v.z += r4.z; v.w += r4.w;
            }
            *(float4*)(out + rbo + colo) = v;
        }
    }
}

// ---------------- inverse L2 norms per pixel (no write-back) ---------------
__global__ __launch_bounds__(256) void l2inv_kernel(
    const float* __restrict__ qkv, float* __restrict__ invn)
{
    int p  = ((blockIdx.x & 63) << 8) + threadIdx.x;
    int bT = blockIdx.x >> 6;          // lb*3 + T
    int lb = bT / 3, T = bT - 3*lb;
    const float* base = qkv + (((size_t)(lb*768 + T*256)) << 14) + p;
    double ss = 0.0;
    for (int c = 0; c < 256; c++) { double v = base[(size_t)c << 14]; ss += v*v; }
    invn[((size_t)bT << 14) + p] = 1.f / fmaxf((float)sqrt(ss), 1e-12f);
}

// ---------------- FFT stage 1: row DFT, even/odd folded, 4-row tiled -------
// re(k) = x0 + (-1)^k x64 + sum_{w=1}^{63} (x[w]+x[128-w]) cos(wk)
// im(k) = -sum_{w=1}^{63} (x[w]-x[128-w]) sin(wk)
__global__ __launch_bounds__(256) void fft_row_kernel(
    const float* __restrict__ qkv, const float* __restrict__ invn,
    float* __restrict__ rre, float* __restrict__ rim, int chunkBase)
{
    int rc  = blockIdx.x;          // 16-row chunk 0..7
    int loc = blockIdx.y;
    int gp  = chunkBase + loc;
    int t   = threadIdx.x;
    __shared__ float xs[16][128];
    __shared__ float ex[16][64], od[16][64];
    __shared__ float x0s[16], x64s[16];
    __shared__ float ct[128], st[128];
    if (t < 128) { double s, c; sincos(TWO_PI_D * t / 128.0, &s, &c);
                   st[t] = (float)s; ct[t] = (float)c; }
    int lb = gp / 768, chn = gp - lb*768, T = chn >> 8;
    const float4* src = (const float4*)(qkv + ((size_t)gp << 14) + ((size_t)rc << 11));
    const float4* ivp = (const float4*)(invn + (((size_t)(lb*3 + T)) << 14) + ((size_t)rc << 11));
    float4* xd = (float4*)xs;
    for (int i = t; i < 512; i += 256) {
        float4 v = src[i], w = ivp[i];
        v.x *= w.x; v.y *= w.y; v.z *= w.z; v.w *= w.w;
        xd[i] = v;
    }
    __syncthreads();
    for (int i = t; i < 1008; i += 256) {
        int r = i / 63, w = i - r*63 + 1;
        float a = xs[r][w], b = xs[r][128 - w];
        ex[r][w] = a + b;
        od[r][w] = a - b;
    }
    if (t < 16) { x0s[t] = xs[t][0]; x64s[t] = xs[t][64]; }
    __syncthreads();
    for (int oo = t; oo < 260; oo += 256) {
        int k = oo % 65, rq = oo / 65;
        int r0i = rq << 2;
        float sgn = (k & 1) ? -1.f : 1.f;
        float re0 = x0s[r0i+0] + sgn*x64s[r0i+0];
        float re1 = x0s[r0i+1] + sgn*x64s[r0i+1];
        float re2 = x0s[r0i+2] + sgn*x64s[r0i+2];
        float re3 = x0s[r0i+3] + sgn*x64s[r0i+3];
        float im0 = 0.f, im1 = 0.f, im2 = 0.f, im3 = 0.f;
        int m = k;
        for (int w = 1; w < 64; w++) {
            float cc = ct[m], sn = st[m];
            re0 += ex[r0i+0][w]*cc; im0 -= od[r0i+0][w]*sn;
            re1 += ex[r0i+1][w]*cc; im1 -= od[r0i+1][w]*sn;
            re2 += ex[r0i+2][w]*cc; im2 -= od[r0i+2][w]*sn;
            re3 += ex[r0i+3][w]*cc; im3 -= od[r0i+3][w]*sn;
            m = (m + k) & 127;
        }
        size_t base = ((size_t)loc*128 + rc*16 + (rq << 2))*65 + k;
        rre[base]       = re0*0.0078125f; rim[base]       = im0*0.0078125f;
        rre[base + 65]  = re1*0.0078125f; rim[base + 65]  = im1*0.0078125f;
        rre[base + 130] = re2*0.0078125f; rim[base + 130] = im2*0.0078125f;
        rre[base + 195] = re3*0.0078125f; rim[base + 195] = im3*0.0078125f;
    }
}

// ---------------- FFT stage 2: radix-16x8 col DFT -> amp/phase -------------
// r = 8*r1 + r0: G[r0][m] = sum_{r1<16} z[8r1+r0] e^{-2pi i r1 m/16};
// F[k1] = sum_{r0<8} G[r0][k1&15] e^{-2pi i r0 k1/128}.
__global__ __launch_bounds__(256) void fft_col_kernel(
    const float* __restrict__ rre, const float* __restrict__ rim,
    float* __restrict__ spec, int chunkBase, size_t slotStride)
{
    int kb  = blockIdx.x * 13;
    int loc = blockIdx.y;
    int gp  = chunkBase + loc;
    int t   = threadIdx.x;
    __shared__ float zr[128][14], zi[128][14];
    __shared__ float gr[8][16][14], gi[8][16][14];
    __shared__ float ct[128], st[128];
    if (t < 128) { double s, c; sincos(TWO_PI_D * t / 128.0, &s, &c);
                   st[t] = (float)s; ct[t] = (float)c; }
    for (int i = t; i < 1664; i += 256) {
        int r = i / 13, k = i - r*13;
        size_t si = ((size_t)loc*128 + r)*65 + kb + k;
        zr[r][k] = rre[si];
        zi[r][k] = rim[si];
    }
    __syncthreads();
    // stage 1: 8 r0 x 16 m x 13 kx
    for (int i = t; i < 1664; i += 256) {
        int kx = i % 13, rm = i / 13;
        int r0 = rm >> 4, m = rm & 15;
        int step = (m << 3) & 127;
        float gre = 0.f, gim = 0.f;
        int idx = 0;
        for (int r1 = 0; r1 < 16; r1++) {
            float cc = ct[idx], sn = st[idx];
            float a = zr[(r1 << 3) + r0][kx], b = zi[(r1 << 3) + r0][kx];
            gre += a*cc + b*sn;
            gim += b*cc - a*sn;
            idx = (idx + step) & 127;
        }
        gr[r0][m][kx] = gre;
        gi[r0][m][kx] = gim;
    }
    __syncthreads();
    int lb = gp / 768; int chn = gp - lb*768;
    int T = chn >> 8;  int c = chn & 255;
    float* aD = spec + (size_t)(2*T)   * slotStride + ((size_t)(lb*256 + c))*8320;
    float* pD = spec + (size_t)(2*T+1) * slotStride + ((size_t)(lb*256 + c))*8320;
    // stage 2: 128 k1 x 13 kx
    for (int i = t; i < 1664; i += 256) {
        int kx = i % 13, k1 = i / 13;
        int m = k1 & 15;
        float re = 0.f, im = 0.f;
        int idx = 0;
        for (int r0 = 0; r0 < 8; r0++) {
            float cc = ct[idx], sn = st[idx];
            float a = gr[r0][m][kx], b = gi[r0][m][kx];
            re += a*cc + b*sn;
            im += b*cc - a*sn;
            idx = (idx + k1) & 127;
        }
        int kxv = kb + kx;
        // Self-conjugate rfft2 bins: im structurally zero; pocketfft gives
        // exact +0.0 -> angle in {0,+pi}. Force +0.0 so atan2 never flips
        // to -pi (decorrelates the winner-take-all phase attention).
        if ((k1 == 0 || k1 == 64) && (kxv == 0 || kxv == 64)) im = 0.f;
        int oi = k1*65 + kxv;
        aD[oi] = sqrtf(re*re + im*im);
        pD[oi] = atan2f(im, re);
    }
}

// ---------------- Attention: split-K partial sims (fp32, float4 LDS) -------
__global__ __launch_bounds__(256) void attn_sim_kernel(
    const float* __restrict__ qA, const float* __restrict__ kA,
    float* __restrict__ simpart)
{
    int sp = blockIdx.x;           // 0..15
    int bh = blockIdx.y;           // lb*8 + h
    int lb = bh >> 3, h = bh & 7;
    int t = threadIdx.x;
    __shared__ float qs[32][132], ks[32][132];
    const float* qb = qA + ((size_t)(lb*256 + h*32)) * 8320;
    const float* kb = kA + ((size_t)(lb*256 + h*32)) * 8320;
    float acc[4] = {0.f, 0.f, 0.f, 0.f};
    int j0 = t >> 5;
    int kq = t & 31;
    for (int sub = 0; sub < 4; sub++) {
        int n0 = sp*520 + sub*130;
        __syncthreads();
        for (int i = t; i < 4160; i += 256) {
            int j = i / 130, nn = i - j*130;
            qs[j][nn] = qb[(size_t)j*8320 + n0 + nn];
            ks[j][nn] = kb[(size_t)j*8320 + n0 + nn];
        }
        __syncthreads();
        for (int nn = 0; nn < 128; nn += 4) {
            float4 kv = *(const float4*)&ks[kq][nn];
            #pragma unroll
            for (int e = 0; e < 4; e++) {
                float4 qv = *(const float4*)&qs[j0 + e*8][nn];
                acc[e] += qv.x*kv.x + qv.y*kv.y + qv.z*kv.z + qv.w*kv.w;
            }
        }
        {
            float2 kv = *(const float2*)&ks[kq][128];
            #pragma unroll
            for (int e = 0; e < 4; e++) {
                float2 qv = *(const float2*)&qs[j0 + e*8][128];
                acc[e] += qv.x*kv.x + qv.y*kv.y;
            }
        }
    }
    float* dst = simpart + ((size_t)bh*16 + sp) * 1024;
    dst[t]       = acc[0];
    dst[t + 256] = acc[1];
    dst[t + 512] = acc[2];
    dst[t + 768] = acc[3];
}

// ---------------- Attention: reduce + softmax + PV (fp32) ------------------
__global__ __launch_bounds__(256) void attn_out_kernel(
    const float* __restrict__ simpart, const float* __restrict__ vA,
    float* __restrict__ outA)
{
    int nb = blockIdx.x << 8;
    int bh = blockIdx.y;
    int lb = bh >> 3, h = bh & 7;
    int t = threadIdx.x;
    __shared__ float sim[32][32];
    for (int e = t; e < 1024; e += 256) {
        float s = 0.f;
        const float* pp = simpart + (size_t)bh*16384 + e;
        #pragma unroll
        for (int sp = 0; sp < 16; sp++) s += pp[sp*1024];
        sim[e >> 5][e & 31] = s * ATTN_SCALE;
    }
    __syncthreads();
    if (t < 32) {
        float m = -1e30f;
        for (int k = 0; k < 32; k++) m = fmaxf(m, sim[t][k]);
        float s = 0.f;
        for (int k = 0; k < 32; k++) s += expf(sim[t][k] - m);
        float inv = 1.f / s;
        for (int k = 0; k < 32; k++) sim[t][k] = expf(sim[t][k] - m) * inv;
    }
    __syncthreads();
    int n = nb + t;
    if (n >= 8320) return;
    const float* vb = vA + ((size_t)(lb*256 + h*32)) * 8320 + n;
    float vv[32];
    #pragma unroll
    for (int k = 0; k < 32; k++) vv[k] = vb[(size_t)k * 8320];
    float* ob = outA + ((size_t)(lb*256 + h*32)) * 8320 + n;
    for (int j = 0; j < 32; j++) {
        float o = 0.f;
        #pragma unroll
        for (int k = 0; k < 32; k++) o += sim[j][k] * vv[k];
        ob[(size_t)j * 8320] = o;
    }
}

// ---------------- iFFT stage 1: radix-16x8 col inverse (e^{+i}) ------------
__global__ __launch_bounds__(256) void ifft_col_kernel(
    const float* __restrict__ ampo, const float* __restrict__ pho,
    float* __restrict__ tre, float* __restrict__ tim)
{
    int kb    = blockIdx.x * 13;
    int plane = blockIdx.y;
    int t     = threadIdx.x;
    __shared__ float zr[128][14], zi[128][14];
    __shared__ float gr[8][16][14], gi[8][16][14];
    __shared__ float ct[128], st[128];
    if (t < 128) { double s, c; sincos(TWO_PI_D * t / 128.0, &s, &c);
                   st[t] = (float)s; ct[t] = (float)c; }
    const float* ab = ampo + (size_t)plane * 8320;
    const float* pb = pho  + (size_t)plane * 8320;
    for (int i = t; i < 1664; i += 256) {
        int k1 = i / 13, k = i - k1*13;
        float a = ab[k1*65 + kb + k];
        float p = pb[k1*65 + kb + k];
        float sp, cp; sincosf(p, &sp, &cp);
        zr[k1][k] = a * cp;
        zi[k1][k] = a * sp;
    }
    __syncthreads();
    // stage 1 (e^{+i}): G[r0][m] = sum_{r1} z[8r1+r0] e^{+2pi i r1 m/16}
    for (int i = t; i < 1664; i += 256) {
        int kx = i % 13, rm = i / 13;
        int r0 = rm >> 4, m = rm & 15;
        int step = (m << 3) & 127;
        float gre = 0.f, gim = 0.f;
        int idx = 0;
        for (int r1 = 0; r1 < 16; r1++) {
            float cc = ct[idx], sn = st[idx];
            float a = zr[(r1 << 3) + r0][kx], b = zi[(r1 << 3) + r0][kx];
            gre += a*cc - b*sn;
            gim += a*sn + b*cc;
            idx = (idx + step) & 127;
        }
        gr[r0][m][kx] = gre;
        gi[r0][m][kx] = gim;
    }
    __syncthreads();
    // stage 2: T[y] = sum_{r0} G[r0][y&15] e^{+2pi i r0 y/128}
    for (int i = t; i < 1664; i += 256) {
        int kx = i % 13, y = i / 13;
        int m = y & 15;
        float re = 0.f, im = 0.f;
        int idx = 0;
        for (int r0 = 0; r0 < 8; r0++) {
            float cc = ct[idx], sn = st[idx];
            float a = gr[r0][m][kx], b = gi[r0][m][kx];
            re += a*cc - b*sn;
            im += a*sn + b*cc;
            idx = (idx + y) & 127;
        }
        size_t oi = ((size_t)plane*128 + y)*65 + kb + kx;
        tre[oi] = re;
        tim[oi] = im;
    }
}

// ---------------- iFFT stage 2: Hermitian rows, output-folded, 4-row -------
// C(x) = tr0 + sum 2tr[k]cos(kx) + tr64 cos(64x); S(x) = sum 2ti[k]sin(kx)+...
// out(x) = C - S; out(128-x) = C + S.
__global__ __launch_bounds__(256) void ifft_row_kernel(
    const float* __restrict__ tre, const float* __restrict__ tim,
    float* __restrict__ spat)
{
    int rc    = blockIdx.x;        // 0..7
    int plane = blockIdx.y;
    int t     = threadIdx.x;
    __shared__ float tr[16][66], ti[16][66];
    __shared__ float ct[128], st[128];
    if (t < 128) { double s, c; sincos(TWO_PI_D * t / 128.0, &s, &c);
                   st[t] = (float)s; ct[t] = (float)c; }
    for (int i = t; i < 1040; i += 256) {
        int r = i / 65, k = i - r*65;
        size_t si = ((size_t)plane*128 + rc*16 + r)*65 + k;
        float sc = (k >= 1 && k < 64) ? 2.f : 1.f;
        tr[r][k] = tre[si] * sc;
        ti[r][k] = tim[si] * sc;
    }
    __syncthreads();
    for (int oo = t; oo < 260; oo += 256) {
        int x = oo % 65, rq = oo / 65;
        int r0i = rq << 2;
        float C0 = tr[r0i+0][0], C1 = tr[r0i+1][0], C2 = tr[r0i+2][0], C3 = tr[r0i+3][0];
        float S0 = 0.f, S1 = 0.f, S2 = 0.f, S3 = 0.f;
        int m = x;
        for (int k = 1; k <= 64; k++) {
            float cc = ct[m], sn = st[m];
            C0 += tr[r0i+0][k]*cc; S0 += ti[r0i+0][k]*sn;
            C1 += tr[r0i+1][k]*cc; S1 += ti[r0i+1][k]*sn;
            C2 += tr[r0i+2][k]*cc; S2 += ti[r0i+2][k]*sn;
            C3 += tr[r0i+3][k]*cc; S3 += ti[r0i+3][k]*sn;
            m = (m + x) & 127;
        }
        size_t ob = ((size_t)plane << 14) + ((rc*16 + r0i) << 7);
        spat[ob + x]       = (C0 - S0)*0.0078125f;
        spat[ob + 128 + x] = (C1 - S1)*0.0078125f;
        spat[ob + 256 + x] = (C2 - S2)*0.0078125f;
        spat[ob + 384 + x] = (C3 - S3)*0.0078125f;
        if (x >= 1 && x <= 63) {
            int xm = 128 - x;
            spat[ob + xm]       = (C0 + S0)*0.0078125f;
            spat[ob + 128 + xm] = (C1 + S1)*0.0078125f;
            spat[ob + 256 + xm] = (C2 + S2)*0.0078125f;
            spat[ob + 384 + xm] = (C3 + S3)*0.0078125f;
        }
    }
}

// ---------------- weight pre-transform: fp32 [Co][Ci][R][R] -> bf16 [RR][Co][Ci]
__global__ __launch_bounds__(256) void wcvt_kernel(
    const float* __restrict__ w, short* __restrict__ wbf,
    int Cout, int Cin, int RR)
{
    int i = blockIdx.x * 256 + threadIdx.x;
    int total = Cout * Cin * RR;
    if (i >= total) return;
    int rr = i % RR;
    int ci = (i / RR) % Cin;
    int co = i / (RR * Cin);
    wbf[((size_t)rr * Cout + co) * Cin + ci] = f2bf(w[i]);
}

// ---------------- bf16 MFMA conv v2 (ao: fp32 in, LDS staged) --------------
__global__ __launch_bounds__(256) void convmf2_kernel(
    const float* __restrict__ in, const short* __restrict__ wbf,
    const float* __restrict__ bias, const float* __restrict__ res,
    float* __restrict__ out, short* __restrict__ out_t,
    int Cin, int Cout, int act, int in_b0, int res_b0, int out_b0)
{
    int y      = blockIdx.x;
    int coBase = blockIdx.y << 7;
    int lb = blockIdx.z;
    int t = threadIdx.x;
    int lane = t & 63;
    int wave = t >> 6;
    int wm = (wave >> 1) << 6;
    int wn = (wave & 1) << 6;

    __shared__ short As[128][40];
    __shared__ short Bs[128][40];

    f32x4 acc[4][4];
    #pragma unroll
    for (int i = 0; i < 4; i++)
        #pragma unroll
        for (int j = 0; j < 4; j++) acc[i][j] = (f32x4){0.f, 0.f, 0.f, 0.f};

    const size_t inb = ((size_t)(in_b0 + lb) * Cin) << 14;
    int lr = lane & 15;
    int kg = (lane >> 4) << 3;

    const float* inrow = in + inb + (y << 7);
    const short* wslice = wbf + (size_t)coBase * Cin;
    for (int ci0 = 0; ci0 < Cin; ci0 += 32) {
        __syncthreads();
        #pragma unroll
        for (int u = 0; u < 2; u++) {
            int ii = t + (u << 8);
            int co = ii >> 2, cg = ii & 3;
            *(short8*)&As[co][cg << 3] =
                *(const short8*)&wslice[(size_t)co * Cin + ci0 + (cg << 3)];
        }
        for (int i = t; i < 2048; i += 256) {
            int px = i & 127, chp = i >> 7;
            int ci = ci0 + (chp << 1);
            float v0 = inrow[((size_t)ci << 14) + px];
            float v1 = inrow[((size_t)(ci + 1) << 14) + px];
            unsigned u2 = (unsigned)(unsigned short)f2bf(v0)
                        | ((unsigned)(unsigned short)f2bf(v1) << 16);
            *(unsigned*)&Bs[px][chp << 1] = u2;
        }
        __syncthreads();
        short8 af[4], bf[4];
        #pragma unroll
        for (int i = 0; i < 4; i++)
            af[i] = *(const short8*)&As[wm + i*16 + lr][kg];
        #pragma unroll
        for (int j = 0; j < 4; j++)
            bf[j] = *(const short8*)&Bs[wn + j*16 + lr][kg];
        #pragma unroll
        for (int i = 0; i < 4; i++)
            #pragma unroll
            for (int j = 0; j < 4; j++)
                acc[i][j] = __builtin_amdgcn_mfma_f32_16x16x32_bf16(
                    af[i], bf[j], acc[i][j], 0, 0, 0);
    }

    int pBase = y << 7;
    int mr = (lane >> 4) << 2;
    #pragma unroll
    for (int i = 0; i < 4; i++) {
        int co0 = coBase + wm + i*16 + mr;
        #pragma unroll
        for (int j = 0; j < 4; j++) {
            int px = pBase + wn + j*16 + lr;
            float v[4];
            #pragma unroll
            for (int r = 0; r < 4; r++) {
                float vv = acc[i][j][r] + (bias ? bias[co0 + r] : 0.f);
                if (act == 1) vv = vv / (1.f + expf(-vv));
                if (res) vv += res[(((size_t)(res_b0 + lb) * Cout + co0 + r) << 14) + px];
                v[r] = vv;
            }
            if (out) {
                #pragma unroll
                for (int r = 0; r < 4; r++)
                    out[(((size_t)(out_b0 + lb) * Cout + co0 + r) << 14) + px] = v[r];
            }
            if (out_t) {
                short4v s4 = { f2bf(v[0]), f2bf(v[1]), f2bf(v[2]), f2bf(v[3]) };
                *(short4v*)&out_t[((size_t)(lb*16384 + px)) * Cout + co0] = s4;
            }
        }
    }
}

// ---------------- bf16 MFMA conv v3: direct-load, bf16T activations --------
template<int R>
__global__ __launch_bounds__(256) void convmf3_kernel(
    const short* __restrict__ in_t, const short* __restrict__ wbf,
    const float* __restrict__ bias, const float* __restrict__ res,
    float* __restrict__ out, short* __restrict__ out_t,
    int Cin, int Cout, int act, int res_b0, int out_b0)
{
    int y      = blockIdx.x;
    int coBase = blockIdx.y << 7;
    int lb = blockIdx.z;
    int t = threadIdx.x;
    int lane = t & 63;
    int wave = t >> 6;
    int wm = (wave >> 1) << 6;
    int wn = (wave & 1) << 6;
    int lr = lane & 15;
    int kg = (lane >> 4) << 3;

    f32x4 acc[4][4];
    #pragma unroll
    for (int i = 0; i < 4; i++)
        #pragma unroll
        for (int j = 0; j < 4; j++) acc[i][j] = (f32x4){0.f, 0.f, 0.f, 0.f};

    const short* inb = in_t + (((size_t)lb << 14)) * Cin;
    const short8 zero8 = {0,0,0,0,0,0,0,0};

    for (int rr = 0; rr < R*R; rr++) {
        int dy = (R == 3) ? (rr / 3) : 0;
        int dx = (R == 3) ? (rr - dy*3) : 0;
        int yy = (R == 3) ? (y + dy - 1) : y;
        if (R == 3 && (yy < 0 || yy > 127)) continue;
        const short* wsl  = wbf + ((size_t)rr * Cout + coBase) * Cin;
        const short* brow = inb + ((size_t)(yy << 7)) * Cin;
        for (int ci0 = 0; ci0 < Cin; ci0 += 32) {
            short8 af[4], bf[4];
            #pragma unroll
            for (int i = 0; i < 4; i++)
                af[i] = *(const short8*)&wsl[(size_t)(wm + i*16 + lr) * Cin + ci0 + kg];
            #pragma unroll
            for (int j = 0; j < 4; j++) {
                int pxl = wn + j*16 + lr;
                int xx = (R == 3) ? (pxl + dx - 1) : pxl;
                if (R == 3 && (xx < 0 || xx > 127)) bf[j] = zero8;
                else bf[j] = *(const short8*)&brow[(size_t)xx * Cin + ci0 + kg];
            }
            #pragma unroll
            for (int i = 0; i < 4; i++)
                #pragma unroll
                for (int j = 0; j < 4; j++)
                    acc[i][j] = __builtin_amdgcn_mfma_f32_16x16x32_bf16(
                        af[i], bf[j], acc[i][j], 0, 0, 0);
        }
    }

    int pBase = y << 7;
    int mr = (lane >> 4) << 2;
    #pragma unroll
    for (int i = 0; i < 4; i++) {
        int co0 = coBase + wm + i*16 + mr;
        #pragma unroll
        for (int j = 0; j < 4; j++) {
            int px = pBase + wn + j*16 + lr;
            float v[4];
            #pragma unroll
            for (int r = 0; r < 4; r++) {
                float vv = acc[i][j][r] + (bias ? bias[co0 + r] : 0.f);
                if (act == 1) vv = vv / (1.f + expf(-vv));
                if (res) vv += res[(((size_t)(res_b0 + lb) * Cout + co0 + r) << 14) + px];
                v[r] = vv;
            }
            if (out) {
                #pragma unroll
                for (int r = 0; r < 4; r++)
                    out[(((size_t)(out_b0 + lb) * Cout + co0 + r) << 14) + px] = v[r];
            }
            if (out_t) {
                short4v s4 = { f2bf(v[0]), f2bf(v[1]), f2bf(v[2]), f2bf(v[3]) };
                *(short4v*)&out_t[((size_t)(lb*16384 + px)) * Cout + co0] = s4;
            }
        }
    }
}

// ---------------------------------------------------------------------------
extern "C" void kernel_launch(void* const* d_in, const int* in_sizes, int n_in,
                              void* d_out, int out_size, void* d_ws, size_t ws_size,
                              hipStream_t stream) {
    (void)in_sizes; (void)n_in; (void)out_size;
    const float* x    = (const float*)d_in[0];
    const float* gn_w = (const float*)d_in[1];
    const float* gn_b = (const float*)d_in[2];
    const float* dw_w = (const float*)d_in[3];
    const float* pw_w = (const float*)d_in[4];
    const float* pw_b = (const float*)d_in[5];
    const float* ao_w = (const float*)d_in[6];
    const float* ao_b = (const float*)d_in[7];
    const float* f1_w = (const float*)d_in[8];
    const float* f2_w = (const float*)d_in[9];
    const float* f3_w = (const float*)d_in[10];
    const float* f3_b = (const float*)d_in[11];
    float* outp = (float*)d_out;

    // per-batch region sizes in floats
    const size_t F_QKV  = 12582912;   // qkv; later abuf/h1t/h2t (bf16T)
    const size_t F_SLOT = 2129920;
    const size_t F_SPEC = 6 * F_SLOT;
    const size_t F_XN   = 4194304;
    const size_t F_E    = 4259840;    // max(dw; rre+rim)
    const size_t F_SIMP = 262144;     // invn / fp32 simpart
    const size_t F_TOT  = F_QKV + F_SPEC + F_XN + F_E + F_SIMP; // 34,078,720
    const size_t F_WB   = 1245184;    // bf16 weights (fixed)

    int NB = 0;
    for (int cand : {8, 4, 2, 1}) {
        if (((size_t)cand * F_TOT + F_WB) * 4 <= ws_size) { NB = cand; break; }
    }
    if (NB == 0) return;

    float* wsf  = (float*)d_ws;
    float* qkv  = wsf;
    short* abuf = (short*)wsf;                           // [NB][16384][256]
    short* h1t  = (short*)(wsf + (size_t)NB * 2097152);  // [NB][16384][512]
    short* h2t  = (short*)(wsf + (size_t)NB * 6291456);  // [NB][16384][256]
    float* spec = wsf + (size_t)NB * F_QKV;
    size_t ss   = (size_t)NB * F_SLOT;
    float* tre  = spec + 2*ss;
    float* tim  = spec + 3*ss;
    float* spat = spec + 4*ss;
    float* xn   = spec + 6*ss;
    float* ebuf = xn + (size_t)NB * F_XN;
    float* dw   = ebuf;
    float* rre  = ebuf;
    float* rim  = ebuf + (size_t)NB * 2129920;
    float* simpf = ebuf + (size_t)NB * F_E;
    float* invn  = simpf;
    float* simp  = simpf;
    short* wb    = (short*)(wsf + (size_t)NB * F_TOT);
    short* wb_ao = wb;
    short* wb_f1 = wb + 65536;
    short* wb_f2 = wb + 1245184;
    short* wb_f3 = wb + 2424832;

    wcvt_kernel<<<256,  256, 0, stream>>>(ao_w, wb_ao, 256, 256, 1);
    wcvt_kernel<<<4608, 256, 0, stream>>>(f1_w, wb_f1, 512, 256, 9);
    wcvt_kernel<<<4608, 256, 0, stream>>>(f2_w, wb_f2, 256, 512, 9);
    wcvt_kernel<<<256,  256, 0, stream>>>(f3_w, wb_f3, 256, 256, 1);

    const int passes = 8 / NB;
    for (int p = 0; p < passes; p++) {
        int b0 = p * NB;
        // 1. GroupNorm -> xn
        groupnorm_kernel<<<NB*32, 256, 0, stream>>>(x, gn_w, gn_b, xn, b0);
        // 2. depthwise 3x3: xn -> dw
        dwconv_kernel<<<NB*256*64, 256, 0, stream>>>(xn, dw_w, dw);
        // 3. pointwise 256->768 (+bias) fp32: dw -> qkv
        conv_kernel<1><<<dim3(128, 6, NB), 256, 0, stream>>>(
            dw, pw_w, pw_b, nullptr, qkv, 256, 768, 0, 0, 0, 0);
        // 4. inverse L2 norms (applied inside fft_row)
        l2inv_kernel<<<NB*3*64, 256, 0, stream>>>(qkv, invn);
        // 5. rfft2 -> amp/phase spec slots, 3 chunks of NB*256 planes
        for (int chunk = 0; chunk < 3; chunk++) {
            fft_row_kernel<<<dim3(8, NB*256), 256, 0, stream>>>(
                qkv, invn, rre, rim, chunk*NB*256);
            fft_col_kernel<<<dim3(5, NB*256), 256, 0, stream>>>(
                rre, rim, spec, chunk*NB*256, ss);
        }
        // 6. channel attention (split-K, fp32)
        attn_sim_kernel<<<dim3(16, NB*8), 256, 0, stream>>>(spec + 0*ss, spec + 2*ss, simp);
        attn_out_kernel<<<dim3(33, NB*8), 256, 0, stream>>>(simp, spec + 4*ss, spec + 0*ss);
        attn_sim_kernel<<<dim3(16, NB*8), 256, 0, stream>>>(spec + 1*ss, spec + 3*ss, simp);
        attn_out_kernel<<<dim3(33, NB*8), 256, 0, stream>>>(simp, spec + 5*ss, spec + 1*ss);
        // 7. irfft2: slots 0,1 -> tre/tim (slots 2,3) -> spat (slots 4-5)
        ifft_col_kernel<<<dim3(5, NB*256), 256, 0, stream>>>(spec + 0*ss, spec + 1*ss,
                                                             tre, tim);
        ifft_row_kernel<<<dim3(8, NB*256), 256, 0, stream>>>(tre, tim, spat);
        // 8. ao 1x1 (+bias) + xn residual -> d_out fp32 + abuf bf16T
        convmf2_kernel<<<dim3(128, 2, NB), 256, 0, stream>>>(
            spat, wb_ao, ao_b, xn, outp, abuf, 256, 256, 0, 0, 0, b0);
        // 9. f1 3x3 256->512 + SiLU: abuf -> h1t (bf16T only)   [direct-load]
        convmf3_kernel<3><<<dim3(128, 4, NB), 256, 0, stream>>>(
            abuf, wb_f1, nullptr, nullptr, nullptr, h1t, 256, 512, 1, 0, 0);
        // 10. f2 3x3 512->256: h1t -> h2t                        [direct-load]
        convmf3_kernel<3><<<dim3(128, 2, NB), 256, 0, stream>>>(
            h1t, wb_f2, nullptr, nullptr, nullptr, h2t, 512, 256, 0, 0, 0);
        // 11. f3 1x1 (+bias) + attn residual -> d_out fp32       [direct-load]
        convmf3_kernel<1><<<dim3(128, 2, NB), 256, 0, stream>>>(
            h2t, wb_f3, f3_b, outp, outp, nullptr, 256, 256, 0, b0, b0);
    }
}

// Round 16
// 7022.709 us; speedup vs baseline: 4.7154x; 1.0201x over previous
//
#include <hip/hip_runtime.h>
#include <hip/hip_bf16.h>
#include <math.h>

// ---------------------------------------------------------------------------
// FreqCA: B=8, C=256, H=W=128, NHEADS=8, GROUPS=32.
// Round 16: pointwise 256->768 conv moved to fp16x2 split-precision MFMA
// (hi+lo fp16 decomposition, 3 MFMA products = ~fp32 accuracy at matrix-core
// speed). DFT factorizations, fp32 attention, bf16 tail unchanged (round 15).
// Self-conjugate rfft2 bins forced im=+0.0 (pocketfft +pi convention).
// ---------------------------------------------------------------------------

#define TWO_PI_D 6.283185307179586476925286766559
#define ATTN_SCALE 0.17677669529663687f  // 1/sqrt(32)

typedef __attribute__((ext_vector_type(8))) short short8;
typedef __attribute__((ext_vector_type(4))) short short4v;
typedef __attribute__((ext_vector_type(4))) float f32x4;
typedef _Float16 half8v __attribute__((ext_vector_type(8)));

__device__ inline short f2bf(float f) {
    __hip_bfloat16 h = __float2bfloat16(f);
    return *reinterpret_cast<short*>(&h);
}
__device__ inline unsigned short h_bits(_Float16 h) {
    union { _Float16 h; unsigned short u; } c; c.h = h; return c.u;
}

// ---------------- GroupNorm: fp64 stats, fp32 out --------------------------
__global__ __launch_bounds__(256) void groupnorm_kernel(
    const float* __restrict__ x, const float* __restrict__ gw,
    const float* __restrict__ gb, float* __restrict__ out, int b0)
{
    int t = threadIdx.x;
    int lb = blockIdx.x >> 5;
    int g  = blockIdx.x & 31;
    size_t src = ((size_t)(b0 + lb) * 32 + g) * 131072;
    size_t dst = (size_t)blockIdx.x * 131072;
    const float* xp = x + src;
    double s = 0.0, ss = 0.0;
    for (int i = t; i < 131072; i += 256) { double v = xp[i]; s += v; ss += v*v; }
    __shared__ double rs[256], rss[256];
    rs[t] = s; rss[t] = ss;
    __syncthreads();
    for (int k = 128; k > 0; k >>= 1) {
        if (t < k) { rs[t] += rs[t+k]; rss[t] += rss[t+k]; }
        __syncthreads();
    }
    __shared__ float smean, sinv;
    if (t == 0) {
        double mean = rs[0] * (1.0/131072.0);
        double var  = rss[0] * (1.0/131072.0) - mean*mean;
        smean = (float)mean;
        sinv  = (float)(1.0 / sqrt(var + 1e-5));
    }
    __syncthreads();
    float mean = smean, inv = sinv;
    for (int i = t; i < 131072; i += 256) {
        int c = (g << 3) + (i >> 14);
        out[dst + i] = (xp[i] - mean) * inv * gw[c] + gb[c];
    }
}

// ---------------- Depthwise 3x3 fp32 ---------------------------------------
__global__ __launch_bounds__(256) void dwconv_kernel(
    const float* __restrict__ in, const float* __restrict__ w, float* __restrict__ out)
{
    int t = threadIdx.x;
    int bc = blockIdx.x >> 6;
    int y  = ((blockIdx.x & 63) << 1) + (t >> 7);
    int x  = t & 127;
    int c  = bc & 255;
    const float* wp = w + c*9;
    const float* ip = in + ((size_t)bc << 14);
    float acc = 0.f;
    #pragma unroll
    for (int dy = 0; dy < 3; dy++) {
        int yy = y + dy - 1;
        if (yy < 0 || yy > 127) continue;
        const float* row = ip + (yy << 7);
        #pragma unroll
        for (int dx = 0; dx < 3; dx++) {
            int xx = x + dx - 1;
            if (xx >= 0 && xx <= 127) acc += wp[dy*3+dx] * row[xx];
        }
    }
    out[((size_t)bc << 14) + (y << 7) + x] = acc;
}

// ---------------- pw weight split: fp32 [768][256] -> fp16 hi/lo -----------
__global__ __launch_bounds__(256) void wcvtpw_kernel(
    const float* __restrict__ w, _Float16* __restrict__ whi,
    _Float16* __restrict__ wlo, int total)
{
    int i = blockIdx.x * 256 + threadIdx.x;
    if (i >= total) return;
    float v = w[i];
    _Float16 h = (_Float16)v;
    _Float16 l = (_Float16)(v - (float)h);
    whi[i] = h; wlo[i] = l;
}

// ---------------- pw conv: fp16x2 split MFMA (Cin=256 -> Cout=768) ---------
// acc += Ah*Bh + Ah*Bl + Al*Bh (fp32 accumulate) ~ fp32 precision.
__global__ __launch_bounds__(256) void convpw_kernel(
    const float* __restrict__ in, const _Float16* __restrict__ whi,
    const _Float16* __restrict__ wlo, const float* __restrict__ bias,
    float* __restrict__ out)
{
    int y      = blockIdx.x;           // pixel row; pBase = y*128
    int coBase = blockIdx.y << 7;      // 0..5 x 128
    int lb     = blockIdx.z;
    int t = threadIdx.x;
    int lane = t & 63;
    int wave = t >> 6;
    int wm = (wave >> 1) << 6;
    int wn = (wave & 1) << 6;
    int lr = lane & 15;
    int kg = (lane >> 4) << 3;

    __shared__ _Float16 Ah[128][40], Al[128][40];
    __shared__ _Float16 Bh[128][40], Bl[128][40];

    f32x4 acc[4][4];
    #pragma unroll
    for (int i = 0; i < 4; i++)
        #pragma unroll
        for (int j = 0; j < 4; j++) acc[i][j] = (f32x4){0.f, 0.f, 0.f, 0.f};

    const float* inrow = in + (((size_t)lb * 256) << 14) + (y << 7);
    for (int ci0 = 0; ci0 < 256; ci0 += 32) {
        __syncthreads();
        #pragma unroll
        for (int u = 0; u < 2; u++) {
            int ii = t + (u << 8);
            int co = ii >> 2, cg = ii & 3;
            *(half8v*)&Ah[co][cg << 3] =
                *(const half8v*)&whi[(size_t)(coBase + co) * 256 + ci0 + (cg << 3)];
            *(half8v*)&Al[co][cg << 3] =
                *(const half8v*)&wlo[(size_t)(coBase + co) * 256 + ci0 + (cg << 3)];
        }
        for (int i = t; i < 2048; i += 256) {
            int px = i & 127, chp = i >> 7;
            int ci = ci0 + (chp << 1);
            float v0 = inrow[((size_t)ci << 14) + px];
            float v1 = inrow[((size_t)(ci + 1) << 14) + px];
            _Float16 h0 = (_Float16)v0, h1 = (_Float16)v1;
            _Float16 l0 = (_Float16)(v0 - (float)h0);
            _Float16 l1 = (_Float16)(v1 - (float)h1);
            unsigned uh = (unsigned)h_bits(h0) | ((unsigned)h_bits(h1) << 16);
            unsigned ul = (unsigned)h_bits(l0) | ((unsigned)h_bits(l1) << 16);
            *(unsigned*)&Bh[px][chp << 1] = uh;
            *(unsigned*)&Bl[px][chp << 1] = ul;
        }
        __syncthreads();
        half8v ah[4], al[4], bh4[4], bl4[4];
        #pragma unroll
        for (int i = 0; i < 4; i++) {
            ah[i] = *(const half8v*)&Ah[wm + i*16 + lr][kg];
            al[i] = *(const half8v*)&Al[wm + i*16 + lr][kg];
        }
        #pragma unroll
        for (int j = 0; j < 4; j++) {
            bh4[j] = *(const half8v*)&Bh[wn + j*16 + lr][kg];
            bl4[j] = *(const half8v*)&Bl[wn + j*16 + lr][kg];
        }
        #pragma unroll
        for (int i = 0; i < 4; i++)
            #pragma unroll
            for (int j = 0; j < 4; j++) {
                acc[i][j] = __builtin_amdgcn_mfma_f32_16x16x32_f16(
                    ah[i], bh4[j], acc[i][j], 0, 0, 0);
                acc[i][j] = __builtin_amdgcn_mfma_f32_16x16x32_f16(
                    ah[i], bl4[j], acc[i][j], 0, 0, 0);
                acc[i][j] = __builtin_amdgcn_mfma_f32_16x16x32_f16(
                    al[i], bh4[j], acc[i][j], 0, 0, 0);
            }
    }

    int pBase = y << 7;
    int mr = (lane >> 4) << 2;
    #pragma unroll
    for (int i = 0; i < 4; i++) {
        int co0 = coBase + wm + i*16 + mr;
        #pragma unroll
        for (int j = 0; j < 4; j++) {
            int px = pBase + wn + j*16 + lr;
            #pragma unroll
            for (int r = 0; r < 4; r++) {
                out[(((size_t)(lb*768 + co0 + r)) << 14) + px] =
                    acc[i][j][r] + bias[co0 + r];
            }
        }
    }
}

// ---------------- inverse L2 norms per pixel (no write-back) ---------------
__global__ __launch_bounds__(256) void l2inv_kernel(
    const float* __restrict__ qkv, float* __restrict__ invn)
{
    int p  = ((blockIdx.x & 63) << 8) + threadIdx.x;
    int bT = blockIdx.x >> 6;          // lb*3 + T
    int lb = bT / 3, T = bT - 3*lb;
    const float* base = qkv + (((size_t)(lb*768 + T*256)) << 14) + p;
    double ss = 0.0;
    for (int c = 0; c < 256; c++) { double v = base[(size_t)c << 14]; ss += v*v; }
    invn[((size_t)bT << 14) + p] = 1.f / fmaxf((float)sqrt(ss), 1e-12f);
}

// ---------------- FFT stage 1: row DFT, even/odd folded, 4-row tiled -------
__global__ __launch_bounds__(256) void fft_row_kernel(
    const float* __restrict__ qkv, const float* __restrict__ invn,
    float* __restrict__ rre, float* __restrict__ rim, int chunkBase)
{
    int rc  = blockIdx.x;          // 16-row chunk 0..7
    int loc = blockIdx.y;
    int gp  = chunkBase + loc;
    int t   = threadIdx.x;
    __shared__ float xs[16][128];
    __shared__ float ex[16][64], od[16][64];
    __shared__ float x0s[16], x64s[16];
    __shared__ float ct[128], st[128];
    if (t < 128) { double s, c; sincos(TWO_PI_D * t / 128.0, &s, &c);
                   st[t] = (float)s; ct[t] = (float)c; }
    int lb = gp / 768, chn = gp - lb*768, T = chn >> 8;
    const float4* src = (const float4*)(qkv + ((size_t)gp << 14) + ((size_t)rc << 11));
    const float4* ivp = (const float4*)(invn + (((size_t)(lb*3 + T)) << 14) + ((size_t)rc << 11));
    float4* xd = (float4*)xs;
    for (int i = t; i < 512; i += 256) {
        float4 v = src[i], w = ivp[i];
        v.x *= w.x; v.y *= w.y; v.z *= w.z; v.w *= w.w;
        xd[i] = v;
    }
    __syncthreads();
    for (int i = t; i < 1008; i += 256) {
        int r = i / 63, w = i - r*63 + 1;
        float a = xs[r][w], b = xs[r][128 - w];
        ex[r][w] = a + b;
        od[r][w] = a - b;
    }
    if (t < 16) { x0s[t] = xs[t][0]; x64s[t] = xs[t][64]; }
    __syncthreads();
    for (int oo = t; oo < 260; oo += 256) {
        int k = oo % 65, rq = oo / 65;
        int r0i = rq << 2;
        float sgn = (k & 1) ? -1.f : 1.f;
        float re0 = x0s[r0i+0] + sgn*x64s[r0i+0];
        float re1 = x0s[r0i+1] + sgn*x64s[r0i+1];
        float re2 = x0s[r0i+2] + sgn*x64s[r0i+2];
        float re3 = x0s[r0i+3] + sgn*x64s[r0i+3];
        float im0 = 0.f, im1 = 0.f, im2 = 0.f, im3 = 0.f;
        int m = k;
        for (int w = 1; w < 64; w++) {
            float cc = ct[m], sn = st[m];
            re0 += ex[r0i+0][w]*cc; im0 -= od[r0i+0][w]*sn;
            re1 += ex[r0i+1][w]*cc; im1 -= od[r0i+1][w]*sn;
            re2 += ex[r0i+2][w]*cc; im2 -= od[r0i+2][w]*sn;
            re3 += ex[r0i+3][w]*cc; im3 -= od[r0i+3][w]*sn;
            m = (m + k) & 127;
        }
        size_t base = ((size_t)loc*128 + rc*16 + (rq << 2))*65 + k;
        rre[base]       = re0*0.0078125f; rim[base]       = im0*0.0078125f;
        rre[base + 65]  = re1*0.0078125f; rim[base + 65]  = im1*0.0078125f;
        rre[base + 130] = re2*0.0078125f; rim[base + 130] = im2*0.0078125f;
        rre[base + 195] = re3*0.0078125f; rim[base + 195] = im3*0.0078125f;
    }
}

// ---------------- FFT stage 2: radix-16x8 col DFT -> amp/phase -------------
__global__ __launch_bounds__(256) void fft_col_kernel(
    const float* __restrict__ rre, const float* __restrict__ rim,
    float* __restrict__ spec, int chunkBase, size_t slotStride)
{
    int kb  = blockIdx.x * 13;
    int loc = blockIdx.y;
    int gp  = chunkBase + loc;
    int t   = threadIdx.x;
    __shared__ float zr[128][14], zi[128][14];
    __shared__ float gr[8][16][14], gi[8][16][14];
    __shared__ float ct[128], st[128];
    if (t < 128) { double s, c; sincos(TWO_PI_D * t / 128.0, &s, &c);
                   st[t] = (float)s; ct[t] = (float)c; }
    for (int i = t; i < 1664; i += 256) {
        int r = i / 13, k = i - r*13;
        size_t si = ((size_t)loc*128 + r)*65 + kb + k;
        zr[r][k] = rre[si];
        zi[r][k] = rim[si];
    }
    __syncthreads();
    for (int i = t; i < 1664; i += 256) {
        int kx = i % 13, rm = i / 13;
        int r0 = rm >> 4, m = rm & 15;
        int step = (m << 3) & 127;
        float gre = 0.f, gim = 0.f;
        int idx = 0;
        for (int r1 = 0; r1 < 16; r1++) {
            float cc = ct[idx], sn = st[idx];
            float a = zr[(r1 << 3) + r0][kx], b = zi[(r1 << 3) + r0][kx];
            gre += a*cc + b*sn;
            gim += b*cc - a*sn;
            idx = (idx + step) & 127;
        }
        gr[r0][m][kx] = gre;
        gi[r0][m][kx] = gim;
    }
    __syncthreads();
    int lb = gp / 768; int chn = gp - lb*768;
    int T = chn >> 8;  int c = chn & 255;
    float* aD = spec + (size_t)(2*T)   * slotStride + ((size_t)(lb*256 + c))*8320;
    float* pD = spec + (size_t)(2*T+1) * slotStride + ((size_t)(lb*256 + c))*8320;
    for (int i = t; i < 1664; i += 256) {
        int kx = i % 13, k1 = i / 13;
        int m = k1 & 15;
        float re = 0.f, im = 0.f;
        int idx = 0;
        for (int r0 = 0; r0 < 8; r0++) {
            float cc = ct[idx], sn = st[idx];
            float a = gr[r0][m][kx], b = gi[r0][m][kx];
            re += a*cc + b*sn;
            im += b*cc - a*sn;
            idx = (idx + k1) & 127;
        }
        int kxv = kb + kx;
        // Self-conjugate rfft2 bins: im structurally zero; pocketfft gives
        // exact +0.0 -> angle in {0,+pi}. Force +0.0 so atan2 never flips
        // to -pi (decorrelates the winner-take-all phase attention).
        if ((k1 == 0 || k1 == 64) && (kxv == 0 || kxv == 64)) im = 0.f;
        int oi = k1*65 + kxv;
        aD[oi] = sqrtf(re*re + im*im);
        pD[oi] = atan2f(im, re);
    }
}

// ---------------- Attention: split-K partial sims (fp32, float4 LDS) -------
__global__ __launch_bounds__(256) void attn_sim_kernel(
    const float* __restrict__ qA, const float* __restrict__ kA,
    float* __restrict__ simpart)
{
    int sp = blockIdx.x;           // 0..15
    int bh = blockIdx.y;           // lb*8 + h
    int lb = bh >> 3, h = bh & 7;
    int t = threadIdx.x;
    __shared__ float qs[32][132], ks[32][132];
    const float* qb = qA + ((size_t)(lb*256 + h*32)) * 8320;
    const float* kb = kA + ((size_t)(lb*256 + h*32)) * 8320;
    float acc[4] = {0.f, 0.f, 0.f, 0.f};
    int j0 = t >> 5;
    int kq = t & 31;
    for (int sub = 0; sub < 4; sub++) {
        int n0 = sp*520 + sub*130;
        __syncthreads();
        for (int i = t; i < 4160; i += 256) {
            int j = i / 130, nn = i - j*130;
            qs[j][nn] = qb[(size_t)j*8320 + n0 + nn];
            ks[j][nn] = kb[(size_t)j*8320 + n0 + nn];
        }
        __syncthreads();
        for (int nn = 0; nn < 128; nn += 4) {
            float4 kv = *(const float4*)&ks[kq][nn];
            #pragma unroll
            for (int e = 0; e < 4; e++) {
                float4 qv = *(const float4*)&qs[j0 + e*8][nn];
                acc[e] += qv.x*kv.x + qv.y*kv.y + qv.z*kv.z + qv.w*kv.w;
            }
        }
        {
            float2 kv = *(const float2*)&ks[kq][128];
            #pragma unroll
            for (int e = 0; e < 4; e++) {
                float2 qv = *(const float2*)&qs[j0 + e*8][128];
                acc[e] += qv.x*kv.x + qv.y*kv.y;
            }
        }
    }
    float* dst = simpart + ((size_t)bh*16 + sp) * 1024;
    dst[t]       = acc[0];
    dst[t + 256] = acc[1];
    dst[t + 512] = acc[2];
    dst[t + 768] = acc[3];
}

// ---------------- Attention: reduce + softmax + PV (fp32) ------------------
__global__ __launch_bounds__(256) void attn_out_kernel(
    const float* __restrict__ simpart, const float* __restrict__ vA,
    float* __restrict__ outA)
{
    int nb = blockIdx.x << 8;
    int bh = blockIdx.y;
    int lb = bh >> 3, h = bh & 7;
    int t = threadIdx.x;
    __shared__ float sim[32][32];
    for (int e = t; e < 1024; e += 256) {
        float s = 0.f;
        const float* pp = simpart + (size_t)bh*16384 + e;
        #pragma unroll
        for (int sp = 0; sp < 16; sp++) s += pp[sp*1024];
        sim[e >> 5][e & 31] = s * ATTN_SCALE;
    }
    __syncthreads();
    if (t < 32) {
        float m = -1e30f;
        for (int k = 0; k < 32; k++) m = fmaxf(m, sim[t][k]);
        float s = 0.f;
        for (int k = 0; k < 32; k++) s += expf(sim[t][k] - m);
        float inv = 1.f / s;
        for (int k = 0; k < 32; k++) sim[t][k] = expf(sim[t][k] - m) * inv;
    }
    __syncthreads();
    int n = nb + t;
    if (n >= 8320) return;
    const float* vb = vA + ((size_t)(lb*256 + h*32)) * 8320 + n;
    float vv[32];
    #pragma unroll
    for (int k = 0; k < 32; k++) vv[k] = vb[(size_t)k * 8320];
    float* ob = outA + ((size_t)(lb*256 + h*32)) * 8320 + n;
    for (int j = 0; j < 32; j++) {
        float o = 0.f;
        #pragma unroll
        for (int k = 0; k < 32; k++) o += sim[j][k] * vv[k];
        ob[(size_t)j * 8320] = o;
    }
}

// ---------------- iFFT stage 1: radix-16x8 col inverse (e^{+i}) ------------
__global__ __launch_bounds__(256) void ifft_col_kernel(
    const float* __restrict__ ampo, const float* __restrict__ pho,
    float* __restrict__ tre, float* __restrict__ tim)
{
    int kb    = blockIdx.x * 13;
    int plane = blockIdx.y;
    int t     = threadIdx.x;
    __shared__ float zr[128][14], zi[128][14];
    __shared__ float gr[8][16][14], gi[8][16][14];
    __shared__ float ct[128], st[128];
    if (t < 128) { double s, c; sincos(TWO_PI_D * t / 128.0, &s, &c);
                   st[t] = (float)s; ct[t] = (float)c; }
    const float* ab = ampo + (size_t)plane * 8320;
    const float* pb = pho  + (size_t)plane * 8320;
    for (int i = t; i < 1664; i += 256) {
        int k1 = i / 13, k = i - k1*13;
        float a = ab[k1*65 + kb + k];
        float p = pb[k1*65 + kb + k];
        float sp, cp; sincosf(p, &sp, &cp);
        zr[k1][k] = a * cp;
        zi[k1][k] = a * sp;
    }
    __syncthreads();
    for (int i = t; i < 1664; i += 256) {
        int kx = i % 13, rm = i / 13;
        int r0 = rm >> 4, m = rm & 15;
        int step = (m << 3) & 127;
        float gre = 0.f, gim = 0.f;
        int idx = 0;
        for (int r1 = 0; r1 < 16; r1++) {
            float cc = ct[idx], sn = st[idx];
            float a = zr[(r1 << 3) + r0][kx], b = zi[(r1 << 3) + r0][kx];
            gre += a*cc - b*sn;
            gim += a*sn + b*cc;
            idx = (idx + step) & 127;
        }
        gr[r0][m][kx] = gre;
        gi[r0][m][kx] = gim;
    }
    __syncthreads();
    for (int i = t; i < 1664; i += 256) {
        int kx = i % 13, y = i / 13;
        int m = y & 15;
        float re = 0.f, im = 0.f;
        int idx = 0;
        for (int r0 = 0; r0 < 8; r0++) {
            float cc = ct[idx], sn = st[idx];
            float a = gr[r0][m][kx], b = gi[r0][m][kx];
            re += a*cc - b*sn;
            im += a*sn + b*cc;
            idx = (idx + y) & 127;
        }
        size_t oi = ((size_t)plane*128 + y)*65 + kb + kx;
        tre[oi] = re;
        tim[oi] = im;
    }
}

// ---------------- iFFT stage 2: Hermitian rows, output-folded, 4-row -------
__global__ __launch_bounds__(256) void ifft_row_kernel(
    const float* __restrict__ tre, const float* __restrict__ tim,
    float* __restrict__ spat)
{
    int rc    = blockIdx.x;        // 0..7
    int plane = blockIdx.y;
    int t     = threadIdx.x;
    __shared__ float tr[16][66], ti[16][66];
    __shared__ float ct[128], st[128];
    if (t < 128) { double s, c; sincos(TWO_PI_D * t / 128.0, &s, &c);
                   st[t] = (float)s; ct[t] = (float)c; }
    for (int i = t; i < 1040; i += 256) {
        int r = i / 65, k = i - r*65;
        size_t si = ((size_t)plane*128 + rc*16 + r)*65 + k;
        float sc = (k >= 1 && k < 64) ? 2.f : 1.f;
        tr[r][k] = tre[si] * sc;
        ti[r][k] = tim[si] * sc;
    }
    __syncthreads();
    for (int oo = t; oo < 260; oo += 256) {
        int x = oo % 65, rq = oo / 65;
        int r0i = rq << 2;
        float C0 = tr[r0i+0][0], C1 = tr[r0i+1][0], C2 = tr[r0i+2][0], C3 = tr[r0i+3][0];
        float S0 = 0.f, S1 = 0.f, S2 = 0.f, S3 = 0.f;
        int m = x;
        for (int k = 1; k <= 64; k++) {
            float cc = ct[m], sn = st[m];
            C0 += tr[r0i+0][k]*cc; S0 += ti[r0i+0][k]*sn;
            C1 += tr[r0i+1][k]*cc; S1 += ti[r0i+1][k]*sn;
            C2 += tr[r0i+2][k]*cc; S2 += ti[r0i+2][k]*sn;
            C3 += tr[r0i+3][k]*cc; S3 += ti[r0i+3][k]*sn;
            m = (m + x) & 127;
        }
        size_t ob = ((size_t)plane << 14) + ((rc*16 + r0i) << 7);
        spat[ob + x]       = (C0 - S0)*0.0078125f;
        spat[ob + 128 + x] = (C1 - S1)*0.0078125f;
        spat[ob + 256 + x] = (C2 - S2)*0.0078125f;
        spat[ob + 384 + x] = (C3 - S3)*0.0078125f;
        if (x >= 1 && x <= 63) {
            int xm = 128 - x;
            spat[ob + xm]       = (C0 + S0)*0.0078125f;
            spat[ob + 128 + xm] = (C1 + S1)*0.0078125f;
            spat[ob + 256 + xm] = (C2 + S2)*0.0078125f;
            spat[ob + 384 + xm] = (C3 + S3)*0.0078125f;
        }
    }
}

// ---------------- weight pre-transform: fp32 [Co][Ci][R][R] -> bf16 [RR][Co][Ci]
__global__ __launch_bounds__(256) void wcvt_kernel(
    const float* __restrict__ w, short* __restrict__ wbf,
    int Cout, int Cin, int RR)
{
    int i = blockIdx.x * 256 + threadIdx.x;
    int total = Cout * Cin * RR;
    if (i >= total) return;
    int rr = i % RR;
    int ci = (i / RR) % Cin;
    int co = i / (RR * Cin);
    wbf[((size_t)rr * Cout + co) * Cin + ci] = f2bf(w[i]);
}

// ---------------- bf16 MFMA conv v2 (ao: fp32 in, LDS staged) --------------
__global__ __launch_bounds__(256) void convmf2_kernel(
    const float* __restrict__ in, const short* __restrict__ wbf,
    const float* __restrict__ bias, const float* __restrict__ res,
    float* __restrict__ out, short* __restrict__ out_t,
    int Cin, int Cout, int act, int in_b0, int res_b0, int out_b0)
{
    int y      = blockIdx.x;
    int coBase = blockIdx.y << 7;
    int lb = blockIdx.z;
    int t = threadIdx.x;
    int lane = t & 63;
    int wave = t >> 6;
    int wm = (wave >> 1) << 6;
    int wn = (wave & 1) << 6;

    __shared__ short As[128][40];
    __shared__ short Bs[128][40];

    f32x4 acc[4][4];
    #pragma unroll
    for (int i = 0; i < 4; i++)
        #pragma unroll
        for (int j = 0; j < 4; j++) acc[i][j] = (f32x4){0.f, 0.f, 0.f, 0.f};

    const size_t inb = ((size_t)(in_b0 + lb) * Cin) << 14;
    int lr = lane & 15;
    int kg = (lane >> 4) << 3;

    const float* inrow = in + inb + (y << 7);
    const short* wslice = wbf + (size_t)coBase * Cin;
    for (int ci0 = 0; ci0 < Cin; ci0 += 32) {
        __syncthreads();
        #pragma unroll
        for (int u = 0; u < 2; u++) {
            int ii = t + (u << 8);
            int co = ii >> 2, cg = ii & 3;
            *(short8*)&As[co][cg << 3] =
                *(const short8*)&wslice[(size_t)co * Cin + ci0 + (cg << 3)];
        }
        for (int i = t; i < 2048; i += 256) {
            int px = i & 127, chp = i >> 7;
            int ci = ci0 + (chp << 1);
            float v0 = inrow[((size_t)ci << 14) + px];
            float v1 = inrow[((size_t)(ci + 1) << 14) + px];
            unsigned u2 = (unsigned)(unsigned short)f2bf(v0)
                        | ((unsigned)(unsigned short)f2bf(v1) << 16);
            *(unsigned*)&Bs[px][chp << 1] = u2;
        }
        __syncthreads();
        short8 af[4], bf[4];
        #pragma unroll
        for (int i = 0; i < 4; i++)
            af[i] = *(const short8*)&As[wm + i*16 + lr][kg];
        #pragma unroll
        for (int j = 0; j < 4; j++)
            bf[j] = *(const short8*)&Bs[wn + j*16 + lr][kg];
        #pragma unroll
        for (int i = 0; i < 4; i++)
            #pragma unroll
            for (int j = 0; j < 4; j++)
                acc[i][j] = __builtin_amdgcn_mfma_f32_16x16x32_bf16(
                    af[i], bf[j], acc[i][j], 0, 0, 0);
    }

    int pBase = y << 7;
    int mr = (lane >> 4) << 2;
    #pragma unroll
    for (int i = 0; i < 4; i++) {
        int co0 = coBase + wm + i*16 + mr;
        #pragma unroll
        for (int j = 0; j < 4; j++) {
            int px = pBase + wn + j*16 + lr;
            float v[4];
            #pragma unroll
            for (int r = 0; r < 4; r++) {
                float vv = acc[i][j][r] + (bias ? bias[co0 + r] : 0.f);
                if (act == 1) vv = vv / (1.f + expf(-vv));
                if (res) vv += res[(((size_t)(res_b0 + lb) * Cout + co0 + r) << 14) + px];
                v[r] = vv;
            }
            if (out) {
                #pragma unroll
                for (int r = 0; r < 4; r++)
                    out[(((size_t)(out_b0 + lb) * Cout + co0 + r) << 14) + px] = v[r];
            }
            if (out_t) {
                short4v s4 = { f2bf(v[0]), f2bf(v[1]), f2bf(v[2]), f2bf(v[3]) };
                *(short4v*)&out_t[((size_t)(lb*16384 + px)) * Cout + co0] = s4;
            }
        }
    }
}

// ---------------- bf16 MFMA conv v3: direct-load, bf16T activations --------
template<int R>
__global__ __launch_bounds__(256) void convmf3_kernel(
    const short* __restrict__ in_t, const short* __restrict__ wbf,
    const float* __restrict__ bias, const float* __restrict__ res,
    float* __restrict__ out, short* __restrict__ out_t,
    int Cin, int Cout, int act, int res_b0, int out_b0)
{
    int y      = blockIdx.x;
    int coBase = blockIdx.y << 7;
    int lb = blockIdx.z;
    int t = threadIdx.x;
    int lane = t & 63;
    int wave = t >> 6;
    int wm = (wave >> 1) << 6;
    int wn = (wave & 1) << 6;
    int lr = lane & 15;
    int kg = (lane >> 4) << 3;

    f32x4 acc[4][4];
    #pragma unroll
    for (int i = 0; i < 4; i++)
        #pragma unroll
        for (int j = 0; j < 4; j++) acc[i][j] = (f32x4){0.f, 0.f, 0.f, 0.f};

    const short* inb = in_t + (((size_t)lb << 14)) * Cin;
    const short8 zero8 = {0,0,0,0,0,0,0,0};

    for (int rr = 0; rr < R*R; rr++) {
        int dy = (R == 3) ? (rr / 3) : 0;
        int dx = (R == 3) ? (rr - dy*3) : 0;
        int yy = (R == 3) ? (y + dy - 1) : y;
        if (R == 3 && (yy < 0 || yy > 127)) continue;
        const short* wsl  = wbf + ((size_t)rr * Cout + coBase) * Cin;
        const short* brow = inb + ((size_t)(yy << 7)) * Cin;
        for (int ci0 = 0; ci0 < Cin; ci0 += 32) {
            short8 af[4], bf[4];
            #pragma unroll
            for (int i = 0; i < 4; i++)
                af[i] = *(const short8*)&wsl[(size_t)(wm + i*16 + lr) * Cin + ci0 + kg];
            #pragma unroll
            for (int j = 0; j < 4; j++) {
                int pxl = wn + j*16 + lr;
                int xx = (R == 3) ? (pxl + dx - 1) : pxl;
                if (R == 3 && (xx < 0 || xx > 127)) bf[j] = zero8;
                else bf[j] = *(const short8*)&brow[(size_t)xx * Cin + ci0 + kg];
            }
            #pragma unroll
            for (int i = 0; i < 4; i++)
                #pragma unroll
                for (int j = 0; j < 4; j++)
                    acc[i][j] = __builtin_amdgcn_mfma_f32_16x16x32_bf16(
                        af[i], bf[j], acc[i][j], 0, 0, 0);
        }
    }

    int pBase = y << 7;
    int mr = (lane >> 4) << 2;
    #pragma unroll
    for (int i = 0; i < 4; i++) {
        int co0 = coBase + wm + i*16 + mr;
        #pragma unroll
        for (int j = 0; j < 4; j++) {
            int px = pBase + wn + j*16 + lr;
            float v[4];
            #pragma unroll
            for (int r = 0; r < 4; r++) {
                float vv = acc[i][j][r] + (bias ? bias[co0 + r] : 0.f);
                if (act == 1) vv = vv / (1.f + expf(-vv));
                if (res) vv += res[(((size_t)(res_b0 + lb) * Cout + co0 + r) << 14) + px];
                v[r] = vv;
            }
            if (out) {
                #pragma unroll
                for (int r = 0; r < 4; r++)
                    out[(((size_t)(out_b0 + lb) * Cout + co0 + r) << 14) + px] = v[r];
            }
            if (out_t) {
                short4v s4 = { f2bf(v[0]), f2bf(v[1]), f2bf(v[2]), f2bf(v[3]) };
                *(short4v*)&out_t[((size_t)(lb*16384 + px)) * Cout + co0] = s4;
            }
        }
    }
}

// ---------------------------------------------------------------------------
extern "C" void kernel_launch(void* const* d_in, const int* in_sizes, int n_in,
                              void* d_out, int out_size, void* d_ws, size_t ws_size,
                              hipStream_t stream) {
    (void)in_sizes; (void)n_in; (void)out_size;
    const float* x    = (const float*)d_in[0];
    const float* gn_w = (const float*)d_in[1];
    const float* gn_b = (const float*)d_in[2];
    const float* dw_w = (const float*)d_in[3];
    const float* pw_w = (const float*)d_in[4];
    const float* pw_b = (const float*)d_in[5];
    const float* ao_w = (const float*)d_in[6];
    const float* ao_b = (const float*)d_in[7];
    const float* f1_w = (const float*)d_in[8];
    const float* f2_w = (const float*)d_in[9];
    const float* f3_w = (const float*)d_in[10];
    const float* f3_b = (const float*)d_in[11];
    float* outp = (float*)d_out;

    // per-batch region sizes in floats
    const size_t F_QKV  = 12582912;   // qkv; later abuf/h1t/h2t (bf16T)
    const size_t F_SLOT = 2129920;
    const size_t F_SPEC = 6 * F_SLOT;
    const size_t F_XN   = 4194304;
    const size_t F_E    = 4259840;    // max(dw; rre+rim)
    const size_t F_SIMP = 262144;     // invn / fp32 simpart
    const size_t F_TOT  = F_QKV + F_SPEC + F_XN + F_E + F_SIMP; // 34,078,720
    const size_t F_WB   = 1441792;    // bf16 weights + pw fp16 hi/lo (fixed)

    int NB = 0;
    for (int cand : {8, 4, 2, 1}) {
        if (((size_t)cand * F_TOT + F_WB) * 4 <= ws_size) { NB = cand; break; }
    }
    if (NB == 0) return;

    float* wsf  = (float*)d_ws;
    float* qkv  = wsf;
    short* abuf = (short*)wsf;                           // [NB][16384][256]
    short* h1t  = (short*)(wsf + (size_t)NB * 2097152);  // [NB][16384][512]
    short* h2t  = (short*)(wsf + (size_t)NB * 6291456);  // [NB][16384][256]
    float* spec = wsf + (size_t)NB * F_QKV;
    size_t ss   = (size_t)NB * F_SLOT;
    float* tre  = spec + 2*ss;
    float* tim  = spec + 3*ss;
    float* spat = spec + 4*ss;
    float* xn   = spec + 6*ss;
    float* ebuf = xn + (size_t)NB * F_XN;
    float* dw   = ebuf;
    float* rre  = ebuf;
    float* rim  = ebuf + (size_t)NB * 2129920;
    float* simpf = ebuf + (size_t)NB * F_E;
    float* invn  = simpf;
    float* simp  = simpf;
    short* wb    = (short*)(wsf + (size_t)NB * F_TOT);
    short* wb_ao = wb;
    short* wb_f1 = wb + 65536;
    short* wb_f2 = wb + 1245184;
    short* wb_f3 = wb + 2424832;
    _Float16* wb_pw_hi = (_Float16*)(wb + 2490368);
    _Float16* wb_pw_lo = (_Float16*)(wb + 2686976);

    wcvt_kernel<<<256,  256, 0, stream>>>(ao_w, wb_ao, 256, 256, 1);
    wcvt_kernel<<<4608, 256, 0, stream>>>(f1_w, wb_f1, 512, 256, 9);
    wcvt_kernel<<<4608, 256, 0, stream>>>(f2_w, wb_f2, 256, 512, 9);
    wcvt_kernel<<<256,  256, 0, stream>>>(f3_w, wb_f3, 256, 256, 1);
    wcvtpw_kernel<<<768, 256, 0, stream>>>(pw_w, wb_pw_hi, wb_pw_lo, 196608);

    const int passes = 8 / NB;
    for (int p = 0; p < passes; p++) {
        int b0 = p * NB;
        // 1. GroupNorm -> xn
        groupnorm_kernel<<<NB*32, 256, 0, stream>>>(x, gn_w, gn_b, xn, b0);
        // 2. depthwise 3x3: xn -> dw
        dwconv_kernel<<<NB*256*64, 256, 0, stream>>>(xn, dw_w, dw);
        // 3. pointwise 256->768 (+bias): fp16x2 split MFMA -> qkv
        convpw_kernel<<<dim3(128, 6, NB), 256, 0, stream>>>(
            dw, wb_pw_hi, wb_pw_lo, pw_b, qkv);
        // 4. inverse L2 norms (applied inside fft_row)
        l2inv_kernel<<<NB*3*64, 256, 0, stream>>>(qkv, invn);
        // 5. rfft2 -> amp/phase spec slots, 3 chunks of NB*256 planes
        for (int chunk = 0; chunk < 3; chunk++) {
            fft_row_kernel<<<dim3(8, NB*256), 256, 0, stream>>>(
                qkv, invn, rre, rim, chunk*NB*256);
            fft_col_kernel<<<dim3(5, NB*256), 256, 0, stream>>>(
                rre, rim, spec, chunk*NB*256, ss);
        }
        // 6. channel attention (split-K, fp32)
        attn_sim_kernel<<<dim3(16, NB*8), 256, 0, stream>>>(spec + 0*ss, spec + 2*ss, simp);
        attn_out_kernel<<<dim3(33, NB*8), 256, 0, stream>>>(simp, spec + 4*ss, spec + 0*ss);
        attn_sim_kernel<<<dim3(16, NB*8), 256, 0, stream>>>(spec + 1*ss, spec + 3*ss, simp);
        attn_out_kernel<<<dim3(33, NB*8), 256, 0, stream>>>(simp, spec + 5*ss, spec + 1*ss);
        // 7. irfft2: slots 0,1 -> tre/tim (slots 2,3) -> spat (slots 4-5)
        ifft_col_kernel<<<dim3(5, NB*256), 256, 0, stream>>>(spec + 0*ss, spec + 1*ss,
                                                             tre, tim);
        ifft_row_kernel<<<dim3(8, NB*256), 256, 0, stream>>>(tre, tim, spat);
        // 8. ao 1x1 (+bias) + xn residual -> d_out fp32 + abuf bf16T
        convmf2_kernel<<<dim3(128, 2, NB), 256, 0, stream>>>(
            spat, wb_ao, ao_b, xn, outp, abuf, 256, 256, 0, 0, 0, b0);
        // 9. f1 3x3 256->512 + SiLU: abuf -> h1t (bf16T only)   [direct-load]
        convmf3_kernel<3><<<dim3(128, 4, NB), 256, 0, stream>>>(
            abuf, wb_f1, nullptr, nullptr, nullptr, h1t, 256, 512, 1, 0, 0);
        // 10. f2 3x3 512->256: h1t -> h2t                        [direct-load]
        convmf3_kernel<3><<<dim3(128, 2, NB), 256, 0, stream>>>(
            h1t, wb_f2, nullptr, nullptr, nullptr, h2t, 512, 256, 0, 0, 0);
        // 11. f3 1x1 (+bias) + attn residual -> d_out fp32       [direct-load]
        convmf3_kernel<1><<<dim3(128, 2, NB), 256, 0, stream>>>(
            h2t, wb_f3, f3_b, outp, outp, nullptr, 256, 256, 0, b0, b0);
    }
}

// Round 17
// 6460.435 us; speedup vs baseline: 5.1258x; 1.0870x over previous
//
#include <hip/hip_runtime.h>
#include <hip/hip_bf16.h>
#include <math.h>

// ---------------------------------------------------------------------------
// FreqCA: B=8, C=256, H=W=128, NHEADS=8, GROUPS=32.
// Round 17: row DFT -> fp16x2 split-precision MFMA GEMM against a constant
// hi/lo twiddle matrix (scale 1/128 folded in; invn applied at staging).
// Rest unchanged from round 16 (radix-16x8 col DFTs, fp32 attention,
// fp16x2 pw conv, bf16 MFMA tail; self-conjugate rfft2 bins im=+0.0).
// ---------------------------------------------------------------------------

#define TWO_PI_D 6.283185307179586476925286766559
#define ATTN_SCALE 0.17677669529663687f  // 1/sqrt(32)

typedef __attribute__((ext_vector_type(8))) short short8;
typedef __attribute__((ext_vector_type(4))) short short4v;
typedef __attribute__((ext_vector_type(4))) float f32x4;
typedef _Float16 half8v __attribute__((ext_vector_type(8)));

__device__ inline short f2bf(float f) {
    __hip_bfloat16 h = __float2bfloat16(f);
    return *reinterpret_cast<short*>(&h);
}
__device__ inline unsigned short h_bits(_Float16 h) {
    union { _Float16 h; unsigned short u; } c; c.h = h; return c.u;
}

// ---------------- GroupNorm: fp64 stats, fp32 out --------------------------
__global__ __launch_bounds__(256) void groupnorm_kernel(
    const float* __restrict__ x, const float* __restrict__ gw,
    const float* __restrict__ gb, float* __restrict__ out, int b0)
{
    int t = threadIdx.x;
    int lb = blockIdx.x >> 5;
    int g  = blockIdx.x & 31;
    size_t src = ((size_t)(b0 + lb) * 32 + g) * 131072;
    size_t dst = (size_t)blockIdx.x * 131072;
    const float* xp = x + src;
    double s = 0.0, ss = 0.0;
    for (int i = t; i < 131072; i += 256) { double v = xp[i]; s += v; ss += v*v; }
    __shared__ double rs[256], rss[256];
    rs[t] = s; rss[t] = ss;
    __syncthreads();
    for (int k = 128; k > 0; k >>= 1) {
        if (t < k) { rs[t] += rs[t+k]; rss[t] += rss[t+k]; }
        __syncthreads();
    }
    __shared__ float smean, sinv;
    if (t == 0) {
        double mean = rs[0] * (1.0/131072.0);
        double var  = rss[0] * (1.0/131072.0) - mean*mean;
        smean = (float)mean;
        sinv  = (float)(1.0 / sqrt(var + 1e-5));
    }
    __syncthreads();
    float mean = smean, inv = sinv;
    for (int i = t; i < 131072; i += 256) {
        int c = (g << 3) + (i >> 14);
        out[dst + i] = (xp[i] - mean) * inv * gw[c] + gb[c];
    }
}

// ---------------- Depthwise 3x3 fp32 ---------------------------------------
__global__ __launch_bounds__(256) void dwconv_kernel(
    const float* __restrict__ in, const float* __restrict__ w, float* __restrict__ out)
{
    int t = threadIdx.x;
    int bc = blockIdx.x >> 6;
    int y  = ((blockIdx.x & 63) << 1) + (t >> 7);
    int x  = t & 127;
    int c  = bc & 255;
    const float* wp = w + c*9;
    const float* ip = in + ((size_t)bc << 14);
    float acc = 0.f;
    #pragma unroll
    for (int dy = 0; dy < 3; dy++) {
        int yy = y + dy - 1;
        if (yy < 0 || yy > 127) continue;
        const float* row = ip + (yy << 7);
        #pragma unroll
        for (int dx = 0; dx < 3; dx++) {
            int xx = x + dx - 1;
            if (xx >= 0 && xx <= 127) acc += wp[dy*3+dx] * row[xx];
        }
    }
    out[((size_t)bc << 14) + (y << 7) + x] = acc;
}

// ---------------- pw weight split: fp32 [768][256] -> fp16 hi/lo -----------
__global__ __launch_bounds__(256) void wcvtpw_kernel(
    const float* __restrict__ w, _Float16* __restrict__ whi,
    _Float16* __restrict__ wlo, int total)
{
    int i = blockIdx.x * 256 + threadIdx.x;
    if (i >= total) return;
    float v = w[i];
    _Float16 h = (_Float16)v;
    _Float16 l = (_Float16)(v - (float)h);
    whi[i] = h; wlo[i] = l;
}

// ---------------- row-DFT twiddle table: [160 bins][128 w] fp16 hi/lo ------
// bin<65: cos(2pi w bin/128)/128 ; bin in [65,130): -sin(2pi w (bin-65)/128)/128
__global__ __launch_bounds__(256) void twcvt_kernel(
    _Float16* __restrict__ twh, _Float16* __restrict__ twl)
{
    int i = blockIdx.x * 256 + threadIdx.x;
    if (i >= 20480) return;
    int bin = i >> 7, w = i & 127;
    double v = 0.0;
    if (bin < 65) v = cos(TWO_PI_D * ((bin * w) & 127) / 128.0) * 0.0078125;
    else if (bin < 130) v = -sin(TWO_PI_D * (((bin - 65) * w) & 127) / 128.0) * 0.0078125;
    _Float16 h = (_Float16)v;
    twh[i] = h;
    twl[i] = (_Float16)((float)v - (float)h);
}

// ---------------- pw conv: fp16x2 split MFMA (Cin=256 -> Cout=768) ---------
__global__ __launch_bounds__(256) void convpw_kernel(
    const float* __restrict__ in, const _Float16* __restrict__ whi,
    const _Float16* __restrict__ wlo, const float* __restrict__ bias,
    float* __restrict__ out)
{
    int y      = blockIdx.x;
    int coBase = blockIdx.y << 7;
    int lb     = blockIdx.z;
    int t = threadIdx.x;
    int lane = t & 63;
    int wave = t >> 6;
    int wm = (wave >> 1) << 6;
    int wn = (wave & 1) << 6;
    int lr = lane & 15;
    int kg = (lane >> 4) << 3;

    __shared__ _Float16 Ah[128][40], Al[128][40];
    __shared__ _Float16 Bh[128][40], Bl[128][40];

    f32x4 acc[4][4];
    #pragma unroll
    for (int i = 0; i < 4; i++)
        #pragma unroll
        for (int j = 0; j < 4; j++) acc[i][j] = (f32x4){0.f, 0.f, 0.f, 0.f};

    const float* inrow = in + (((size_t)lb * 256) << 14) + (y << 7);
    for (int ci0 = 0; ci0 < 256; ci0 += 32) {
        __syncthreads();
        #pragma unroll
        for (int u = 0; u < 2; u++) {
            int ii = t + (u << 8);
            int co = ii >> 2, cg = ii & 3;
            *(half8v*)&Ah[co][cg << 3] =
                *(const half8v*)&whi[(size_t)(coBase + co) * 256 + ci0 + (cg << 3)];
            *(half8v*)&Al[co][cg << 3] =
                *(const half8v*)&wlo[(size_t)(coBase + co) * 256 + ci0 + (cg << 3)];
        }
        for (int i = t; i < 2048; i += 256) {
            int px = i & 127, chp = i >> 7;
            int ci = ci0 + (chp << 1);
            float v0 = inrow[((size_t)ci << 14) + px];
            float v1 = inrow[((size_t)(ci + 1) << 14) + px];
            _Float16 h0 = (_Float16)v0, h1 = (_Float16)v1;
            _Float16 l0 = (_Float16)(v0 - (float)h0);
            _Float16 l1 = (_Float16)(v1 - (float)h1);
            unsigned uh = (unsigned)h_bits(h0) | ((unsigned)h_bits(h1) << 16);
            unsigned ul = (unsigned)h_bits(l0) | ((unsigned)h_bits(l1) << 16);
            *(unsigned*)&Bh[px][chp << 1] = uh;
            *(unsigned*)&Bl[px][chp << 1] = ul;
        }
        __syncthreads();
        half8v ah[4], al[4], bh4[4], bl4[4];
        #pragma unroll
        for (int i = 0; i < 4; i++) {
            ah[i] = *(const half8v*)&Ah[wm + i*16 + lr][kg];
            al[i] = *(const half8v*)&Al[wm + i*16 + lr][kg];
        }
        #pragma unroll
        for (int j = 0; j < 4; j++) {
            bh4[j] = *(const half8v*)&Bh[wn + j*16 + lr][kg];
            bl4[j] = *(const half8v*)&Bl[wn + j*16 + lr][kg];
        }
        #pragma unroll
        for (int i = 0; i < 4; i++)
            #pragma unroll
            for (int j = 0; j < 4; j++) {
                acc[i][j] = __builtin_amdgcn_mfma_f32_16x16x32_f16(
                    ah[i], bh4[j], acc[i][j], 0, 0, 0);
                acc[i][j] = __builtin_amdgcn_mfma_f32_16x16x32_f16(
                    ah[i], bl4[j], acc[i][j], 0, 0, 0);
                acc[i][j] = __builtin_amdgcn_mfma_f32_16x16x32_f16(
                    al[i], bh4[j], acc[i][j], 0, 0, 0);
            }
    }

    int pBase = y << 7;
    int mr = (lane >> 4) << 2;
    #pragma unroll
    for (int i = 0; i < 4; i++) {
        int co0 = coBase + wm + i*16 + mr;
        #pragma unroll
        for (int j = 0; j < 4; j++) {
            int px = pBase + wn + j*16 + lr;
            #pragma unroll
            for (int r = 0; r < 4; r++) {
                out[(((size_t)(lb*768 + co0 + r)) << 14) + px] =
                    acc[i][j][r] + bias[co0 + r];
            }
        }
    }
}

// ---------------- inverse L2 norms per pixel (no write-back) ---------------
__global__ __launch_bounds__(256) void l2inv_kernel(
    const float* __restrict__ qkv, float* __restrict__ invn)
{
    int p  = ((blockIdx.x & 63) << 8) + threadIdx.x;
    int bT = blockIdx.x >> 6;          // lb*3 + T
    int lb = bT / 3, T = bT - 3*lb;
    const float* base = qkv + (((size_t)(lb*768 + T*256)) << 14) + p;
    double ss = 0.0;
    for (int c = 0; c < 256; c++) { double v = base[(size_t)c << 14]; ss += v*v; }
    invn[((size_t)bT << 14) + p] = 1.f / fmaxf((float)sqrt(ss), 1e-12f);
}

// ---------------- FFT stage 1: row DFT as fp16x2 MFMA GEMM -----------------
// Per plane: [128 rows x 128 w] x Tw[160 bins][128 w]^T -> rre/rim.
// K staged in two 64-wide halves (LDS 34.8 KB); invn applied at staging.
__global__ __launch_bounds__(256) void fftrow_mfma_kernel(
    const float* __restrict__ qkv, const float* __restrict__ invn,
    const _Float16* __restrict__ twh, const _Float16* __restrict__ twl,
    float* __restrict__ rre, float* __restrict__ rim, int chunkBase)
{
    int loc = blockIdx.x;
    int gp  = chunkBase + loc;
    int t = threadIdx.x;
    int lane = t & 63;
    int wave = t >> 6;
    int wm  = (wave >> 1) << 6;    // row offset: 0 / 64
    int wnn = (wave & 1) * 80;     // bin offset: 0 / 80
    int lr = lane & 15;
    int kq = (lane >> 4) << 3;     // 0,8,16,24

    __shared__ _Float16 Xh[128][68], Xl[128][68];

    int lb = gp / 768, chn = gp - lb*768, T = chn >> 8;
    const float4* src = (const float4*)(qkv + ((size_t)gp << 14));
    const float4* ivp = (const float4*)(invn + (((size_t)(lb*3 + T)) << 14));

    f32x4 acc[4][5];
    #pragma unroll
    for (int i = 0; i < 4; i++)
        #pragma unroll
        for (int j = 0; j < 5; j++) acc[i][j] = (f32x4){0.f, 0.f, 0.f, 0.f};

    for (int half = 0; half < 2; half++) {
        __syncthreads();
        for (int i = t; i < 2048; i += 256) {
            int r = i >> 4, q4 = i & 15;
            int gi = (r << 5) + (half << 4) + q4;
            float4 v = src[gi], w = ivp[gi];
            v.x *= w.x; v.y *= w.y; v.z *= w.z; v.w *= w.w;
            int cl = q4 << 2;
            _Float16 h0 = (_Float16)v.x, h1 = (_Float16)v.y;
            _Float16 h2 = (_Float16)v.z, h3 = (_Float16)v.w;
            Xh[r][cl+0] = h0; Xh[r][cl+1] = h1; Xh[r][cl+2] = h2; Xh[r][cl+3] = h3;
            Xl[r][cl+0] = (_Float16)(v.x - (float)h0);
            Xl[r][cl+1] = (_Float16)(v.y - (float)h1);
            Xl[r][cl+2] = (_Float16)(v.z - (float)h2);
            Xl[r][cl+3] = (_Float16)(v.w - (float)h3);
        }
        __syncthreads();
        #pragma unroll
        for (int ks = 0; ks < 2; ks++) {
            int k0 = (ks << 5) + kq;            // local k in [0,64)
            int kg = (half << 6) + k0;          // global w
            half8v ah[4], al[4], bh[5], bl[5];
            #pragma unroll
            for (int i = 0; i < 4; i++) {
                ah[i] = *(const half8v*)&Xh[wm + i*16 + lr][k0];
                al[i] = *(const half8v*)&Xl[wm + i*16 + lr][k0];
            }
            #pragma unroll
            for (int j = 0; j < 5; j++) {
                int bin = wnn + j*16 + lr;
                bh[j] = *(const half8v*)&twh[(size_t)bin * 128 + kg];
                bl[j] = *(const half8v*)&twl[(size_t)bin * 128 + kg];
            }
            #pragma unroll
            for (int i = 0; i < 4; i++)
                #pragma unroll
                for (int j = 0; j < 5; j++) {
                    acc[i][j] = __builtin_amdgcn_mfma_f32_16x16x32_f16(
                        ah[i], bh[j], acc[i][j], 0, 0, 0);
                    acc[i][j] = __builtin_amdgcn_mfma_f32_16x16x32_f16(
                        al[i], bh[j], acc[i][j], 0, 0, 0);
                    acc[i][j] = __builtin_amdgcn_mfma_f32_16x16x32_f16(
                        ah[i], bl[j], acc[i][j], 0, 0, 0);
                }
        }
    }

    int mr = (lane >> 4) << 2;
    #pragma unroll
    for (int i = 0; i < 4; i++) {
        #pragma unroll
        for (int j = 0; j < 5; j++) {
            int bin = wnn + j*16 + lr;
            if (bin < 130) {
                float* dst = (bin < 65) ? rre : rim;
                int bb = (bin < 65) ? bin : bin - 65;
                #pragma unroll
                for (int r = 0; r < 4; r++) {
                    int row = wm + i*16 + mr + r;
                    dst[((size_t)loc*128 + row)*65 + bb] = acc[i][j][r];
                }
            }
        }
    }
}

// ---------------- FFT stage 2: radix-16x8 col DFT -> amp/phase -------------
__global__ __launch_bounds__(256) void fft_col_kernel(
    const float* __restrict__ rre, const float* __restrict__ rim,
    float* __restrict__ spec, int chunkBase, size_t slotStride)
{
    int kb  = blockIdx.x * 13;
    int loc = blockIdx.y;
    int gp  = chunkBase + loc;
    int t   = threadIdx.x;
    __shared__ float zr[128][14], zi[128][14];
    __shared__ float gr[8][16][14], gi[8][16][14];
    __shared__ float ct[128], st[128];
    if (t < 128) { double s, c; sincos(TWO_PI_D * t / 128.0, &s, &c);
                   st[t] = (float)s; ct[t] = (float)c; }
    for (int i = t; i < 1664; i += 256) {
        int r = i / 13, k = i - r*13;
        size_t si = ((size_t)loc*128 + r)*65 + kb + k;
        zr[r][k] = rre[si];
        zi[r][k] = rim[si];
    }
    __syncthreads();
    for (int i = t; i < 1664; i += 256) {
        int kx = i % 13, rm = i / 13;
        int r0 = rm >> 4, m = rm & 15;
        int step = (m << 3) & 127;
        float gre = 0.f, gim = 0.f;
        int idx = 0;
        for (int r1 = 0; r1 < 16; r1++) {
            float cc = ct[idx], sn = st[idx];
            float a = zr[(r1 << 3) + r0][kx], b = zi[(r1 << 3) + r0][kx];
            gre += a*cc + b*sn;
            gim += b*cc - a*sn;
            idx = (idx + step) & 127;
        }
        gr[r0][m][kx] = gre;
        gi[r0][m][kx] = gim;
    }
    __syncthreads();
    int lb = gp / 768; int chn = gp - lb*768;
    int T = chn >> 8;  int c = chn & 255;
    float* aD = spec + (size_t)(2*T)   * slotStride + ((size_t)(lb*256 + c))*8320;
    float* pD = spec + (size_t)(2*T+1) * slotStride + ((size_t)(lb*256 + c))*8320;
    for (int i = t; i < 1664; i += 256) {
        int kx = i % 13, k1 = i / 13;
        int m = k1 & 15;
        float re = 0.f, im = 0.f;
        int idx = 0;
        for (int r0 = 0; r0 < 8; r0++) {
            float cc = ct[idx], sn = st[idx];
            float a = gr[r0][m][kx], b = gi[r0][m][kx];
            re += a*cc + b*sn;
            im += b*cc - a*sn;
            idx = (idx + k1) & 127;
        }
        int kxv = kb + kx;
        // Self-conjugate rfft2 bins: im structurally zero; pocketfft gives
        // exact +0.0 -> angle in {0,+pi}. Force +0.0 so atan2 never flips
        // to -pi (decorrelates the winner-take-all phase attention).
        if ((k1 == 0 || k1 == 64) && (kxv == 0 || kxv == 64)) im = 0.f;
        int oi = k1*65 + kxv;
        aD[oi] = sqrtf(re*re + im*im);
        pD[oi] = atan2f(im, re);
    }
}

// ---------------- Attention: split-K partial sims (fp32, float4 LDS) -------
__global__ __launch_bounds__(256) void attn_sim_kernel(
    const float* __restrict__ qA, const float* __restrict__ kA,
    float* __restrict__ simpart)
{
    int sp = blockIdx.x;           // 0..15
    int bh = blockIdx.y;           // lb*8 + h
    int lb = bh >> 3, h = bh & 7;
    int t = threadIdx.x;
    __shared__ float qs[32][132], ks[32][132];
    const float* qb = qA + ((size_t)(lb*256 + h*32)) * 8320;
    const float* kb = kA + ((size_t)(lb*256 + h*32)) * 8320;
    float acc[4] = {0.f, 0.f, 0.f, 0.f};
    int j0 = t >> 5;
    int kq = t & 31;
    for (int sub = 0; sub < 4; sub++) {
        int n0 = sp*520 + sub*130;
        __syncthreads();
        for (int i = t; i < 4160; i += 256) {
            int j = i / 130, nn = i - j*130;
            qs[j][nn] = qb[(size_t)j*8320 + n0 + nn];
            ks[j][nn] = kb[(size_t)j*8320 + n0 + nn];
        }
        __syncthreads();
        for (int nn = 0; nn < 128; nn += 4) {
            float4 kv = *(const float4*)&ks[kq][nn];
            #pragma unroll
            for (int e = 0; e < 4; e++) {
                float4 qv = *(const float4*)&qs[j0 + e*8][nn];
                acc[e] += qv.x*kv.x + qv.y*kv.y + qv.z*kv.z + qv.w*kv.w;
            }
        }
        {
            float2 kv = *(const float2*)&ks[kq][128];
            #pragma unroll
            for (int e = 0; e < 4; e++) {
                float2 qv = *(const float2*)&qs[j0 + e*8][128];
                acc[e] += qv.x*kv.x + qv.y*kv.y;
            }
        }
    }
    float* dst = simpart + ((size_t)bh*16 + sp) * 1024;
    dst[t]       = acc[0];
    dst[t + 256] = acc[1];
    dst[t + 512] = acc[2];
    dst[t + 768] = acc[3];
}

// ---------------- Attention: reduce + softmax + PV (fp32) ------------------
__global__ __launch_bounds__(256) void attn_out_kernel(
    const float* __restrict__ simpart, const float* __restrict__ vA,
    float* __restrict__ outA)
{
    int nb = blockIdx.x << 8;
    int bh = blockIdx.y;
    int lb = bh >> 3, h = bh & 7;
    int t = threadIdx.x;
    __shared__ float sim[32][32];
    for (int e = t; e < 1024; e += 256) {
        float s = 0.f;
        const float* pp = simpart + (size_t)bh*16384 + e;
        #pragma unroll
        for (int sp = 0; sp < 16; sp++) s += pp[sp*1024];
        sim[e >> 5][e & 31] = s * ATTN_SCALE;
    }
    __syncthreads();
    if (t < 32) {
        float m = -1e30f;
        for (int k = 0; k < 32; k++) m = fmaxf(m, sim[t][k]);
        float s = 0.f;
        for (int k = 0; k < 32; k++) s += expf(sim[t][k] - m);
        float inv = 1.f / s;
        for (int k = 0; k < 32; k++) sim[t][k] = expf(sim[t][k] - m) * inv;
    }
    __syncthreads();
    int n = nb + t;
    if (n >= 8320) return;
    const float* vb = vA + ((size_t)(lb*256 + h*32)) * 8320 + n;
    float vv[32];
    #pragma unroll
    for (int k = 0; k < 32; k++) vv[k] = vb[(size_t)k * 8320];
    float* ob = outA + ((size_t)(lb*256 + h*32)) * 8320 + n;
    for (int j = 0; j < 32; j++) {
        float o = 0.f;
        #pragma unroll
        for (int k = 0; k < 32; k++) o += sim[j][k] * vv[k];
        ob[(size_t)j * 8320] = o;
    }
}

// ---------------- iFFT stage 1: radix-16x8 col inverse (e^{+i}) ------------
__global__ __launch_bounds__(256) void ifft_col_kernel(
    const float* __restrict__ ampo, const float* __restrict__ pho,
    float* __restrict__ tre, float* __restrict__ tim)
{
    int kb    = blockIdx.x * 13;
    int plane = blockIdx.y;
    int t     = threadIdx.x;
    __shared__ float zr[128][14], zi[128][14];
    __shared__ float gr[8][16][14], gi[8][16][14];
    __shared__ float ct[128], st[128];
    if (t < 128) { double s, c; sincos(TWO_PI_D * t / 128.0, &s, &c);
                   st[t] = (float)s; ct[t] = (float)c; }
    const float* ab = ampo + (size_t)plane * 8320;
    const float* pb = pho  + (size_t)plane * 8320;
    for (int i = t; i < 1664; i += 256) {
        int k1 = i / 13, k = i - k1*13;
        float a = ab[k1*65 + kb + k];
        float p = pb[k1*65 + kb + k];
        float sp, cp; sincosf(p, &sp, &cp);
        zr[k1][k] = a * cp;
        zi[k1][k] = a * sp;
    }
    __syncthreads();
    for (int i = t; i < 1664; i += 256) {
        int kx = i % 13, rm = i / 13;
        int r0 = rm >> 4, m = rm & 15;
        int step = (m << 3) & 127;
        float gre = 0.f, gim = 0.f;
        int idx = 0;
        for (int r1 = 0; r1 < 16; r1++) {
            float cc = ct[idx], sn = st[idx];
            float a = zr[(r1 << 3) + r0][kx], b = zi[(r1 << 3) + r0][kx];
            gre += a*cc - b*sn;
            gim += a*sn + b*cc;
            idx = (idx + step) & 127;
        }
        gr[r0][m][kx] = gre;
        gi[r0][m][kx] = gim;
    }
    __syncthreads();
    for (int i = t; i < 1664; i += 256) {
        int kx = i % 13, y = i / 13;
        int m = y & 15;
        float re = 0.f, im = 0.f;
        int idx = 0;
        for (int r0 = 0; r0 < 8; r0++) {
            float cc = ct[idx], sn = st[idx];
            float a = gr[r0][m][kx], b = gi[r0][m][kx];
            re += a*cc - b*sn;
            im += a*sn + b*cc;
            idx = (idx + y) & 127;
        }
        size_t oi = ((size_t)plane*128 + y)*65 + kb + kx;
        tre[oi] = re;
        tim[oi] = im;
    }
}

// ---------------- iFFT stage 2: Hermitian rows, output-folded, 4-row -------
__global__ __launch_bounds__(256) void ifft_row_kernel(
    const float* __restrict__ tre, const float* __restrict__ tim,
    float* __restrict__ spat)
{
    int rc    = blockIdx.x;        // 0..7
    int plane = blockIdx.y;
    int t     = threadIdx.x;
    __shared__ float tr[16][66], ti[16][66];
    __shared__ float ct[128], st[128];
    if (t < 128) { double s, c; sincos(TWO_PI_D * t / 128.0, &s, &c);
                   st[t] = (float)s; ct[t] = (float)c; }
    for (int i = t; i < 1040; i += 256) {
        int r = i / 65, k = i - r*65;
        size_t si = ((size_t)plane*128 + rc*16 + r)*65 + k;
        float sc = (k >= 1 && k < 64) ? 2.f : 1.f;
        tr[r][k] = tre[si] * sc;
        ti[r][k] = tim[si] * sc;
    }
    __syncthreads();
    for (int oo = t; oo < 260; oo += 256) {
        int x = oo % 65, rq = oo / 65;
        int r0i = rq << 2;
        float C0 = tr[r0i+0][0], C1 = tr[r0i+1][0], C2 = tr[r0i+2][0], C3 = tr[r0i+3][0];
        float S0 = 0.f, S1 = 0.f, S2 = 0.f, S3 = 0.f;
        int m = x;
        for (int k = 1; k <= 64; k++) {
            float cc = ct[m], sn = st[m];
            C0 += tr[r0i+0][k]*cc; S0 += ti[r0i+0][k]*sn;
            C1 += tr[r0i+1][k]*cc; S1 += ti[r0i+1][k]*sn;
            C2 += tr[r0i+2][k]*cc; S2 += ti[r0i+2][k]*sn;
            C3 += tr[r0i+3][k]*cc; S3 += ti[r0i+3][k]*sn;
            m = (m + x) & 127;
        }
        size_t ob = ((size_t)plane << 14) + ((rc*16 + r0i) << 7);
        spat[ob + x]       = (C0 - S0)*0.0078125f;
        spat[ob + 128 + x] = (C1 - S1)*0.0078125f;
        spat[ob + 256 + x] = (C2 - S2)*0.0078125f;
        spat[ob + 384 + x] = (C3 - S3)*0.0078125f;
        if (x >= 1 && x <= 63) {
            int xm = 128 - x;
            spat[ob + xm]       = (C0 + S0)*0.0078125f;
            spat[ob + 128 + xm] = (C1 + S1)*0.0078125f;
            spat[ob + 256 + xm] = (C2 + S2)*0.0078125f;
            spat[ob + 384 + xm] = (C3 + S3)*0.0078125f;
        }
    }
}

// ---------------- weight pre-transform: fp32 [Co][Ci][R][R] -> bf16 [RR][Co][Ci]
__global__ __launch_bounds__(256) void wcvt_kernel(
    const float* __restrict__ w, short* __restrict__ wbf,
    int Cout, int Cin, int RR)
{
    int i = blockIdx.x * 256 + threadIdx.x;
    int total = Cout * Cin * RR;
    if (i >= total) return;
    int rr = i % RR;
    int ci = (i / RR) % Cin;
    int co = i / (RR * Cin);
    wbf[((size_t)rr * Cout + co) * Cin + ci] = f2bf(w[i]);
}

// ---------------- bf16 MFMA conv v2 (ao: fp32 in, LDS staged) --------------
__global__ __launch_bounds__(256) void convmf2_kernel(
    const float* __restrict__ in, const short* __restrict__ wbf,
    const float* __restrict__ bias, const float* __restrict__ res,
    float* __restrict__ out, short* __restrict__ out_t,
    int Cin, int Cout, int act, int in_b0, int res_b0, int out_b0)
{
    int y      = blockIdx.x;
    int coBase = blockIdx.y << 7;
    int lb = blockIdx.z;
    int t = threadIdx.x;
    int lane = t & 63;
    int wave = t >> 6;
    int wm = (wave >> 1) << 6;
    int wn = (wave & 1) << 6;

    __shared__ short As[128][40];
    __shared__ short Bs[128][40];

    f32x4 acc[4][4];
    #pragma unroll
    for (int i = 0; i < 4; i++)
        #pragma unroll
        for (int j = 0; j < 4; j++) acc[i][j] = (f32x4){0.f, 0.f, 0.f, 0.f};

    const size_t inb = ((size_t)(in_b0 + lb) * Cin) << 14;
    int lr = lane & 15;
    int kg = (lane >> 4) << 3;

    const float* inrow = in + inb + (y << 7);
    const short* wslice = wbf + (size_t)coBase * Cin;
    for (int ci0 = 0; ci0 < Cin; ci0 += 32) {
        __syncthreads();
        #pragma unroll
        for (int u = 0; u < 2; u++) {
            int ii = t + (u << 8);
            int co = ii >> 2, cg = ii & 3;
            *(short8*)&As[co][cg << 3] =
                *(const short8*)&wslice[(size_t)co * Cin + ci0 + (cg << 3)];
        }
        for (int i = t; i < 2048; i += 256) {
            int px = i & 127, chp = i >> 7;
            int ci = ci0 + (chp << 1);
            float v0 = inrow[((size_t)ci << 14) + px];
            float v1 = inrow[((size_t)(ci + 1) << 14) + px];
            unsigned u2 = (unsigned)(unsigned short)f2bf(v0)
                        | ((unsigned)(unsigned short)f2bf(v1) << 16);
            *(unsigned*)&Bs[px][chp << 1] = u2;
        }
        __syncthreads();
        short8 af[4], bf[4];
        #pragma unroll
        for (int i = 0; i < 4; i++)
            af[i] = *(const short8*)&As[wm + i*16 + lr][kg];
        #pragma unroll
        for (int j = 0; j < 4; j++)
            bf[j] = *(const short8*)&Bs[wn + j*16 + lr][kg];
        #pragma unroll
        for (int i = 0; i < 4; i++)
            #pragma unroll
            for (int j = 0; j < 4; j++)
                acc[i][j] = __builtin_amdgcn_mfma_f32_16x16x32_bf16(
                    af[i], bf[j], acc[i][j], 0, 0, 0);
    }

    int pBase = y << 7;
    int mr = (lane >> 4) << 2;
    #pragma unroll
    for (int i = 0; i < 4; i++) {
        int co0 = coBase + wm + i*16 + mr;
        #pragma unroll
        for (int j = 0; j < 4; j++) {
            int px = pBase + wn + j*16 + lr;
            float v[4];
            #pragma unroll
            for (int r = 0; r < 4; r++) {
                float vv = acc[i][j][r] + (bias ? bias[co0 + r] : 0.f);
                if (act == 1) vv = vv / (1.f + expf(-vv));
                if (res) vv += res[(((size_t)(res_b0 + lb) * Cout + co0 + r) << 14) + px];
                v[r] = vv;
            }
            if (out) {
                #pragma unroll
                for (int r = 0; r < 4; r++)
                    out[(((size_t)(out_b0 + lb) * Cout + co0 + r) << 14) + px] = v[r];
            }
            if (out_t) {
                short4v s4 = { f2bf(v[0]), f2bf(v[1]), f2bf(v[2]), f2bf(v[3]) };
                *(short4v*)&out_t[((size_t)(lb*16384 + px)) * Cout + co0] = s4;
            }
        }
    }
}

// ---------------- bf16 MFMA conv v3: direct-load, bf16T activations --------
template<int R>
__global__ __launch_bounds__(256) void convmf3_kernel(
    const short* __restrict__ in_t, const short* __restrict__ wbf,
    const float* __restrict__ bias, const float* __restrict__ res,
    float* __restrict__ out, short* __restrict__ out_t,
    int Cin, int Cout, int act, int res_b0, int out_b0)
{
    int y      = blockIdx.x;
    int coBase = blockIdx.y << 7;
    int lb = blockIdx.z;
    int t = threadIdx.x;
    int lane = t & 63;
    int wave = t >> 6;
    int wm = (wave >> 1) << 6;
    int wn = (wave & 1) << 6;
    int lr = lane & 15;
    int kg = (lane >> 4) << 3;

    f32x4 acc[4][4];
    #pragma unroll
    for (int i = 0; i < 4; i++)
        #pragma unroll
        for (int j = 0; j < 4; j++) acc[i][j] = (f32x4){0.f, 0.f, 0.f, 0.f};

    const short* inb = in_t + (((size_t)lb << 14)) * Cin;
    const short8 zero8 = {0,0,0,0,0,0,0,0};

    for (int rr = 0; rr < R*R; rr++) {
        int dy = (R == 3) ? (rr / 3) : 0;
        int dx = (R == 3) ? (rr - dy*3) : 0;
        int yy = (R == 3) ? (y + dy - 1) : y;
        if (R == 3 && (yy < 0 || yy > 127)) continue;
        const short* wsl  = wbf + ((size_t)rr * Cout + coBase) * Cin;
        const short* brow = inb + ((size_t)(yy << 7)) * Cin;
        for (int ci0 = 0; ci0 < Cin; ci0 += 32) {
            short8 af[4], bf[4];
            #pragma unroll
            for (int i = 0; i < 4; i++)
                af[i] = *(const short8*)&wsl[(size_t)(wm + i*16 + lr) * Cin + ci0 + kg];
            #pragma unroll
            for (int j = 0; j < 4; j++) {
                int pxl = wn + j*16 + lr;
                int xx = (R == 3) ? (pxl + dx - 1) : pxl;
                if (R == 3 && (xx < 0 || xx > 127)) bf[j] = zero8;
                else bf[j] = *(const short8*)&brow[(size_t)xx * Cin + ci0 + kg];
            }
            #pragma unroll
            for (int i = 0; i < 4; i++)
                #pragma unroll
                for (int j = 0; j < 4; j++)
                    acc[i][j] = __builtin_amdgcn_mfma_f32_16x16x32_bf16(
                        af[i], bf[j], acc[i][j], 0, 0, 0);
        }
    }

    int pBase = y << 7;
    int mr = (lane >> 4) << 2;
    #pragma unroll
    for (int i = 0; i < 4; i++) {
        int co0 = coBase + wm + i*16 + mr;
        #pragma unroll
        for (int j = 0; j < 4; j++) {
            int px = pBase + wn + j*16 + lr;
            float v[4];
            #pragma unroll
            for (int r = 0; r < 4; r++) {
                float vv = acc[i][j][r] + (bias ? bias[co0 + r] : 0.f);
                if (act == 1) vv = vv / (1.f + expf(-vv));
                if (res) vv += res[(((size_t)(res_b0 + lb) * Cout + co0 + r) << 14) + px];
                v[r] = vv;
            }
            if (out) {
                #pragma unroll
                for (int r = 0; r < 4; r++)
                    out[(((size_t)(out_b0 + lb) * Cout + co0 + r) << 14) + px] = v[r];
            }
            if (out_t) {
                short4v s4 = { f2bf(v[0]), f2bf(v[1]), f2bf(v[2]), f2bf(v[3]) };
                *(short4v*)&out_t[((size_t)(lb*16384 + px)) * Cout + co0] = s4;
            }
        }
    }
}

// ---------------------------------------------------------------------------
extern "C" void kernel_launch(void* const* d_in, const int* in_sizes, int n_in,
                              void* d_out, int out_size, void* d_ws, size_t ws_size,
                              hipStream_t stream) {
    (void)in_sizes; (void)n_in; (void)out_size;
    const float* x    = (const float*)d_in[0];
    const float* gn_w = (const float*)d_in[1];
    const float* gn_b = (const float*)d_in[2];
    const float* dw_w = (const float*)d_in[3];
    const float* pw_w = (const float*)d_in[4];
    const float* pw_b = (const float*)d_in[5];
    const float* ao_w = (const float*)d_in[6];
    const float* ao_b = (const float*)d_in[7];
    const float* f1_w = (const float*)d_in[8];
    const float* f2_w = (const float*)d_in[9];
    const float* f3_w = (const float*)d_in[10];
    const float* f3_b = (const float*)d_in[11];
    float* outp = (float*)d_out;

    // per-batch region sizes in floats
    const size_t F_QKV  = 12582912;   // qkv; later abuf/h1t/h2t (bf16T)
    const size_t F_SLOT = 2129920;
    const size_t F_SPEC = 6 * F_SLOT;
    const size_t F_XN   = 4194304;
    const size_t F_E    = 4259840;    // max(dw; rre+rim)
    const size_t F_SIMP = 262144;     // invn / fp32 simpart
    const size_t F_TOT  = F_QKV + F_SPEC + F_XN + F_E + F_SIMP; // 34,078,720
    const size_t F_WB   = 1462272;    // bf16 weights + pw fp16 hi/lo + twiddle

    int NB = 0;
    for (int cand : {8, 4, 2, 1}) {
        if (((size_t)cand * F_TOT + F_WB) * 4 <= ws_size) { NB = cand; break; }
    }
    if (NB == 0) return;

    float* wsf  = (float*)d_ws;
    float* qkv  = wsf;
    short* abuf = (short*)wsf;                           // [NB][16384][256]
    short* h1t  = (short*)(wsf + (size_t)NB * 2097152);  // [NB][16384][512]
    short* h2t  = (short*)(wsf + (size_t)NB * 6291456);  // [NB][16384][256]
    float* spec = wsf + (size_t)NB * F_QKV;
    size_t ss   = (size_t)NB * F_SLOT;
    float* tre  = spec + 2*ss;
    float* tim  = spec + 3*ss;
    float* spat = spec + 4*ss;
    float* xn   = spec + 6*ss;
    float* ebuf = xn + (size_t)NB * F_XN;
    float* dw   = ebuf;
    float* rre  = ebuf;
    float* rim  = ebuf + (size_t)NB * 2129920;
    float* simpf = ebuf + (size_t)NB * F_E;
    float* invn  = simpf;
    float* simp  = simpf;
    short* wb    = (short*)(wsf + (size_t)NB * F_TOT);
    short* wb_ao = wb;
    short* wb_f1 = wb + 65536;
    short* wb_f2 = wb + 1245184;
    short* wb_f3 = wb + 2424832;
    _Float16* wb_pw_hi = (_Float16*)(wb + 2490368);
    _Float16* wb_pw_lo = (_Float16*)(wb + 2686976);
    _Float16* wb_tw_hi = (_Float16*)(wb + 2883584);
    _Float16* wb_tw_lo = (_Float16*)(wb + 2904064);

    wcvt_kernel<<<256,  256, 0, stream>>>(ao_w, wb_ao, 256, 256, 1);
    wcvt_kernel<<<4608, 256, 0, stream>>>(f1_w, wb_f1, 512, 256, 9);
    wcvt_kernel<<<4608, 256, 0, stream>>>(f2_w, wb_f2, 256, 512, 9);
    wcvt_kernel<<<256,  256, 0, stream>>>(f3_w, wb_f3, 256, 256, 1);
    wcvtpw_kernel<<<768, 256, 0, stream>>>(pw_w, wb_pw_hi, wb_pw_lo, 196608);
    twcvt_kernel<<<80, 256, 0, stream>>>(wb_tw_hi, wb_tw_lo);

    const int passes = 8 / NB;
    for (int p = 0; p < passes; p++) {
        int b0 = p * NB;
        // 1. GroupNorm -> xn
        groupnorm_kernel<<<NB*32, 256, 0, stream>>>(x, gn_w, gn_b, xn, b0);
        // 2. depthwise 3x3: xn -> dw
        dwconv_kernel<<<NB*256*64, 256, 0, stream>>>(xn, dw_w, dw);
        // 3. pointwise 256->768 (+bias): fp16x2 split MFMA -> qkv
        convpw_kernel<<<dim3(128, 6, NB), 256, 0, stream>>>(
            dw, wb_pw_hi, wb_pw_lo, pw_b, qkv);
        // 4. inverse L2 norms (applied inside fftrow_mfma)
        l2inv_kernel<<<NB*3*64, 256, 0, stream>>>(qkv, invn);
        // 5. rfft2 -> amp/phase spec slots, 3 chunks of NB*256 planes
        for (int chunk = 0; chunk < 3; chunk++) {
            fftrow_mfma_kernel<<<NB*256, 256, 0, stream>>>(
                qkv, invn, wb_tw_hi, wb_tw_lo, rre, rim, chunk*NB*256);
            fft_col_kernel<<<dim3(5, NB*256), 256, 0, stream>>>(
                rre, rim, spec, chunk*NB*256, ss);
        }
        // 6. channel attention (split-K, fp32)
        attn_sim_kernel<<<dim3(16, NB*8), 256, 0, stream>>>(spec + 0*ss, spec + 2*ss, simp);
        attn_out_kernel<<<dim3(33, NB*8), 256, 0, stream>>>(simp, spec + 4*ss, spec + 0*ss);
        attn_sim_kernel<<<dim3(16, NB*8), 256, 0, stream>>>(spec + 1*ss, spec + 3*ss, simp);
        attn_out_kernel<<<dim3(33, NB*8), 256, 0, stream>>>(simp, spec + 5*ss, spec + 1*ss);
        // 7. irfft2: slots 0,1 -> tre/tim (slots 2,3) -> spat (slots 4-5)
        ifft_col_kernel<<<dim3(5, NB*256), 256, 0, stream>>>(spec + 0*ss, spec + 1*ss,
                                                             tre, tim);
        ifft_row_kernel<<<dim3(8, NB*256), 256, 0, stream>>>(tre, tim, spat);
        // 8. ao 1x1 (+bias) + xn residual -> d_out fp32 + abuf bf16T
        convmf2_kernel<<<dim3(128, 2, NB), 256, 0, stream>>>(
            spat, wb_ao, ao_b, xn, outp, abuf, 256, 256, 0, 0, 0, b0);
        // 9. f1 3x3 256->512 + SiLU: abuf -> h1t (bf16T only)   [direct-load]
        convmf3_kernel<3><<<dim3(128, 4, NB), 256, 0, stream>>>(
            abuf, wb_f1, nullptr, nullptr, nullptr, h1t, 256, 512, 1, 0, 0);
        // 10. f2 3x3 512->256: h1t -> h2t                        [direct-load]
        convmf3_kernel<3><<<dim3(128, 2, NB), 256, 0, stream>>>(
            h1t, wb_f2, nullptr, nullptr, nullptr, h2t, 512, 256, 0, 0, 0);
        // 11. f3 1x1 (+bias) + attn residual -> d_out fp32       [direct-load]
        convmf3_kernel<1><<<dim3(128, 2, NB), 256, 0, stream>>>(
            h2t, wb_f3, f3_b, outp, outp, nullptr, 256, 256, 0, b0, b0);
    }
}

// Round 18
// 6333.092 us; speedup vs baseline: 5.2289x; 1.0201x over previous
//
#include <hip/hip_runtime.h>
#include <hip/hip_bf16.h>
#include <math.h>

// ---------------------------------------------------------------------------
// FreqCA: B=8, C=256, H=W=128, NHEADS=8, GROUPS=32.
// Round 18: ifft_col -> fp16x2 split MFMA against constant 256x256 M-table
// (zin rows interleaved [zr0,zi0,zr1,zi1,...]); dwconv via LDS halo.
// Forward FFT / attention untouched (error-margin preservation).
// Self-conjugate rfft2 bins forced im=+0.0 (pocketfft +pi convention).
// ---------------------------------------------------------------------------

#define TWO_PI_D 6.283185307179586476925286766559
#define ATTN_SCALE 0.17677669529663687f  // 1/sqrt(32)

typedef __attribute__((ext_vector_type(8))) short short8;
typedef __attribute__((ext_vector_type(4))) short short4v;
typedef __attribute__((ext_vector_type(4))) float f32x4;
typedef _Float16 half8v __attribute__((ext_vector_type(8)));

__device__ inline short f2bf(float f) {
    __hip_bfloat16 h = __float2bfloat16(f);
    return *reinterpret_cast<short*>(&h);
}
__device__ inline unsigned short h_bits(_Float16 h) {
    union { _Float16 h; unsigned short u; } c; c.h = h; return c.u;
}

// ---------------- GroupNorm: fp64 stats, fp32 out --------------------------
__global__ __launch_bounds__(256) void groupnorm_kernel(
    const float* __restrict__ x, const float* __restrict__ gw,
    const float* __restrict__ gb, float* __restrict__ out, int b0)
{
    int t = threadIdx.x;
    int lb = blockIdx.x >> 5;
    int g  = blockIdx.x & 31;
    size_t src = ((size_t)(b0 + lb) * 32 + g) * 131072;
    size_t dst = (size_t)blockIdx.x * 131072;
    const float* xp = x + src;
    double s = 0.0, ss = 0.0;
    for (int i = t; i < 131072; i += 256) { double v = xp[i]; s += v; ss += v*v; }
    __shared__ double rs[256], rss[256];
    rs[t] = s; rss[t] = ss;
    __syncthreads();
    for (int k = 128; k > 0; k >>= 1) {
        if (t < k) { rs[t] += rs[t+k]; rss[t] += rss[t+k]; }
        __syncthreads();
    }
    __shared__ float smean, sinv;
    if (t == 0) {
        double mean = rs[0] * (1.0/131072.0);
        double var  = rss[0] * (1.0/131072.0) - mean*mean;
        smean = (float)mean;
        sinv  = (float)(1.0 / sqrt(var + 1e-5));
    }
    __syncthreads();
    float mean = smean, inv = sinv;
    for (int i = t; i < 131072; i += 256) {
        int c = (g << 3) + (i >> 14);
        out[dst + i] = (xp[i] - mean) * inv * gw[c] + gb[c];
    }
}

// ---------------- Depthwise 3x3 fp32, LDS halo -----------------------------
__global__ __launch_bounds__(256) void dwconv_kernel(
    const float* __restrict__ in, const float* __restrict__ w, float* __restrict__ out)
{
    int t = threadIdx.x;
    int bc = blockIdx.x >> 6;
    int ystrip = (blockIdx.x & 63) << 1;
    int c  = bc & 255;
    const float* wp = w + c*9;
    const float* ip = in + ((size_t)bc << 14);
    __shared__ float xs[4][128];
    for (int i = t; i < 512; i += 256) {
        int rr = i >> 7, xx = i & 127;
        int yy = ystrip - 1 + rr;
        xs[rr][xx] = (yy >= 0 && yy < 128) ? ip[(yy << 7) + xx] : 0.f;
    }
    __syncthreads();
    int r0 = t >> 7;
    int x  = t & 127;
    float acc = 0.f;
    #pragma unroll
    for (int dy = 0; dy < 3; dy++) {
        const float* row = xs[r0 + dy];
        #pragma unroll
        for (int dx = 0; dx < 3; dx++) {
            int xx = x + dx - 1;
            if (xx >= 0 && xx <= 127) acc += wp[dy*3+dx] * row[xx];
        }
    }
    out[((size_t)bc << 14) + ((ystrip + r0) << 7) + x] = acc;
}

// ---------------- pw weight split: fp32 [768][256] -> fp16 hi/lo -----------
__global__ __launch_bounds__(256) void wcvtpw_kernel(
    const float* __restrict__ w, _Float16* __restrict__ whi,
    _Float16* __restrict__ wlo, int total)
{
    int i = blockIdx.x * 256 + threadIdx.x;
    if (i >= total) return;
    float v = w[i];
    _Float16 h = (_Float16)v;
    _Float16 l = (_Float16)(v - (float)h);
    whi[i] = h; wlo[i] = l;
}

// ---------------- row-DFT twiddle table: [160 bins][128 w] fp16 hi/lo ------
__global__ __launch_bounds__(256) void twcvt_kernel(
    _Float16* __restrict__ twh, _Float16* __restrict__ twl)
{
    int i = blockIdx.x * 256 + threadIdx.x;
    if (i >= 20480) return;
    int bin = i >> 7, w = i & 127;
    double v = 0.0;
    if (bin < 65) v = cos(TWO_PI_D * ((bin * w) & 127) / 128.0) * 0.0078125;
    else if (bin < 130) v = -sin(TWO_PI_D * (((bin - 65) * w) & 127) / 128.0) * 0.0078125;
    _Float16 h = (_Float16)v;
    twh[i] = h;
    twl[i] = (_Float16)((float)v - (float)h);
}

// ---------------- ifft-col M table: [256 rows][256 zin] fp16 hi/lo ---------
// zin interleaved: col=2k1 -> zr[k1], col=2k1+1 -> zi[k1].
// row y<128 (tre): M=c / -s ; row 128+y (tim): M=s / c. (e^{+i} transform)
__global__ __launch_bounds__(256) void micvt_kernel(
    _Float16* __restrict__ mih, _Float16* __restrict__ mil)
{
    int i = blockIdx.x * 256 + threadIdx.x;
    if (i >= 65536) return;
    int row = i >> 8, col = i & 255;
    int k1 = col >> 1, u = col & 1;
    int yy = row & 127;
    double ang = TWO_PI_D * ((k1 * yy) & 127) / 128.0;
    double cc = cos(ang), sn = sin(ang);
    double v;
    if (row < 128) v = (u == 0) ? cc : -sn;
    else           v = (u == 0) ? sn :  cc;
    _Float16 h = (_Float16)v;
    mih[i] = h;
    mil[i] = (_Float16)((float)v - (float)h);
}

// ---------------- pw conv: fp16x2 split MFMA (Cin=256 -> Cout=768) ---------
__global__ __launch_bounds__(256) void convpw_kernel(
    const float* __restrict__ in, const _Float16* __restrict__ whi,
    const _Float16* __restrict__ wlo, const float* __restrict__ bias,
    float* __restrict__ out)
{
    int y      = blockIdx.x;
    int coBase = blockIdx.y << 7;
    int lb     = blockIdx.z;
    int t = threadIdx.x;
    int lane = t & 63;
    int wave = t >> 6;
    int wm = (wave >> 1) << 6;
    int wn = (wave & 1) << 6;
    int lr = lane & 15;
    int kg = (lane >> 4) << 3;

    __shared__ _Float16 Ah[128][40], Al[128][40];
    __shared__ _Float16 Bh[128][40], Bl[128][40];

    f32x4 acc[4][4];
    #pragma unroll
    for (int i = 0; i < 4; i++)
        #pragma unroll
        for (int j = 0; j < 4; j++) acc[i][j] = (f32x4){0.f, 0.f, 0.f, 0.f};

    const float* inrow = in + (((size_t)lb * 256) << 14) + (y << 7);
    for (int ci0 = 0; ci0 < 256; ci0 += 32) {
        __syncthreads();
        #pragma unroll
        for (int u = 0; u < 2; u++) {
            int ii = t + (u << 8);
            int co = ii >> 2, cg = ii & 3;
            *(half8v*)&Ah[co][cg << 3] =
                *(const half8v*)&whi[(size_t)(coBase + co) * 256 + ci0 + (cg << 3)];
            *(half8v*)&Al[co][cg << 3] =
                *(const half8v*)&wlo[(size_t)(coBase + co) * 256 + ci0 + (cg << 3)];
        }
        for (int i = t; i < 2048; i += 256) {
            int px = i & 127, chp = i >> 7;
            int ci = ci0 + (chp << 1);
            float v0 = inrow[((size_t)ci << 14) + px];
            float v1 = inrow[((size_t)(ci + 1) << 14) + px];
            _Float16 h0 = (_Float16)v0, h1 = (_Float16)v1;
            _Float16 l0 = (_Float16)(v0 - (float)h0);
            _Float16 l1 = (_Float16)(v1 - (float)h1);
            unsigned uh = (unsigned)h_bits(h0) | ((unsigned)h_bits(h1) << 16);
            unsigned ul = (unsigned)h_bits(l0) | ((unsigned)h_bits(l1) << 16);
            *(unsigned*)&Bh[px][chp << 1] = uh;
            *(unsigned*)&Bl[px][chp << 1] = ul;
        }
        __syncthreads();
        half8v ah[4], al[4], bh4[4], bl4[4];
        #pragma unroll
        for (int i = 0; i < 4; i++) {
            ah[i] = *(const half8v*)&Ah[wm + i*16 + lr][kg];
            al[i] = *(const half8v*)&Al[wm + i*16 + lr][kg];
        }
        #pragma unroll
        for (int j = 0; j < 4; j++) {
            bh4[j] = *(const half8v*)&Bh[wn + j*16 + lr][kg];
            bl4[j] = *(const half8v*)&Bl[wn + j*16 + lr][kg];
        }
        #pragma unroll
        for (int i = 0; i < 4; i++)
            #pragma unroll
            for (int j = 0; j < 4; j++) {
                acc[i][j] = __builtin_amdgcn_mfma_f32_16x16x32_f16(
                    ah[i], bh4[j], acc[i][j], 0, 0, 0);
                acc[i][j] = __builtin_amdgcn_mfma_f32_16x16x32_f16(
                    ah[i], bl4[j], acc[i][j], 0, 0, 0);
                acc[i][j] = __builtin_amdgcn_mfma_f32_16x16x32_f16(
                    al[i], bh4[j], acc[i][j], 0, 0, 0);
            }
    }

    int pBase = y << 7;
    int mr = (lane >> 4) << 2;
    #pragma unroll
    for (int i = 0; i < 4; i++) {
        int co0 = coBase + wm + i*16 + mr;
        #pragma unroll
        for (int j = 0; j < 4; j++) {
            int px = pBase + wn + j*16 + lr;
            #pragma unroll
            for (int r = 0; r < 4; r++) {
                out[(((size_t)(lb*768 + co0 + r)) << 14) + px] =
                    acc[i][j][r] + bias[co0 + r];
            }
        }
    }
}

// ---------------- inverse L2 norms per pixel (no write-back) ---------------
__global__ __launch_bounds__(256) void l2inv_kernel(
    const float* __restrict__ qkv, float* __restrict__ invn)
{
    int p  = ((blockIdx.x & 63) << 8) + threadIdx.x;
    int bT = blockIdx.x >> 6;          // lb*3 + T
    int lb = bT / 3, T = bT - 3*lb;
    const float* base = qkv + (((size_t)(lb*768 + T*256)) << 14) + p;
    double ss = 0.0;
    for (int c = 0; c < 256; c++) { double v = base[(size_t)c << 14]; ss += v*v; }
    invn[((size_t)bT << 14) + p] = 1.f / fmaxf((float)sqrt(ss), 1e-12f);
}

// ---------------- FFT stage 1: row DFT as fp16x2 MFMA GEMM -----------------
__global__ __launch_bounds__(256) void fftrow_mfma_kernel(
    const float* __restrict__ qkv, const float* __restrict__ invn,
    const _Float16* __restrict__ twh, const _Float16* __restrict__ twl,
    float* __restrict__ rre, float* __restrict__ rim, int chunkBase)
{
    int loc = blockIdx.x;
    int gp  = chunkBase + loc;
    int t = threadIdx.x;
    int lane = t & 63;
    int wave = t >> 6;
    int wm  = (wave >> 1) << 6;
    int wnn = (wave & 1) * 80;
    int lr = lane & 15;
    int kq = (lane >> 4) << 3;

    __shared__ _Float16 Xh[128][68], Xl[128][68];

    int lb = gp / 768, chn = gp - lb*768, T = chn >> 8;
    const float4* src = (const float4*)(qkv + ((size_t)gp << 14));
    const float4* ivp = (const float4*)(invn + (((size_t)(lb*3 + T)) << 14));

    f32x4 acc[4][5];
    #pragma unroll
    for (int i = 0; i < 4; i++)
        #pragma unroll
        for (int j = 0; j < 5; j++) acc[i][j] = (f32x4){0.f, 0.f, 0.f, 0.f};

    for (int half = 0; half < 2; half++) {
        __syncthreads();
        for (int i = t; i < 2048; i += 256) {
            int r = i >> 4, q4 = i & 15;
            int gi = (r << 5) + (half << 4) + q4;
            float4 v = src[gi], w = ivp[gi];
            v.x *= w.x; v.y *= w.y; v.z *= w.z; v.w *= w.w;
            int cl = q4 << 2;
            _Float16 h0 = (_Float16)v.x, h1 = (_Float16)v.y;
            _Float16 h2 = (_Float16)v.z, h3 = (_Float16)v.w;
            Xh[r][cl+0] = h0; Xh[r][cl+1] = h1; Xh[r][cl+2] = h2; Xh[r][cl+3] = h3;
            Xl[r][cl+0] = (_Float16)(v.x - (float)h0);
            Xl[r][cl+1] = (_Float16)(v.y - (float)h1);
            Xl[r][cl+2] = (_Float16)(v.z - (float)h2);
            Xl[r][cl+3] = (_Float16)(v.w - (float)h3);
        }
        __syncthreads();
        #pragma unroll
        for (int ks = 0; ks < 2; ks++) {
            int k0 = (ks << 5) + kq;
            int kg = (half << 6) + k0;
            half8v ah[4], al[4], bh[5], bl[5];
            #pragma unroll
            for (int i = 0; i < 4; i++) {
                ah[i] = *(const half8v*)&Xh[wm + i*16 + lr][k0];
                al[i] = *(const half8v*)&Xl[wm + i*16 + lr][k0];
            }
            #pragma unroll
            for (int j = 0; j < 5; j++) {
                int bin = wnn + j*16 + lr;
                bh[j] = *(const half8v*)&twh[(size_t)bin * 128 + kg];
                bl[j] = *(const half8v*)&twl[(size_t)bin * 128 + kg];
            }
            #pragma unroll
            for (int i = 0; i < 4; i++)
                #pragma unroll
                for (int j = 0; j < 5; j++) {
                    acc[i][j] = __builtin_amdgcn_mfma_f32_16x16x32_f16(
                        ah[i], bh[j], acc[i][j], 0, 0, 0);
                    acc[i][j] = __builtin_amdgcn_mfma_f32_16x16x32_f16(
                        al[i], bh[j], acc[i][j], 0, 0, 0);
                    acc[i][j] = __builtin_amdgcn_mfma_f32_16x16x32_f16(
                        ah[i], bl[j], acc[i][j], 0, 0, 0);
                }
        }
    }

    int mr = (lane >> 4) << 2;
    #pragma unroll
    for (int i = 0; i < 4; i++) {
        #pragma unroll
        for (int j = 0; j < 5; j++) {
            int bin = wnn + j*16 + lr;
            if (bin < 130) {
                float* dst = (bin < 65) ? rre : rim;
                int bb = (bin < 65) ? bin : bin - 65;
                #pragma unroll
                for (int r = 0; r < 4; r++) {
                    int row = wm + i*16 + mr + r;
                    dst[((size_t)loc*128 + row)*65 + bb] = acc[i][j][r];
                }
            }
        }
    }
}

// ---------------- FFT stage 2: radix-16x8 col DFT -> amp/phase -------------
__global__ __launch_bounds__(256) void fft_col_kernel(
    const float* __restrict__ rre, const float* __restrict__ rim,
    float* __restrict__ spec, int chunkBase, size_t slotStride)
{
    int kb  = blockIdx.x * 13;
    int loc = blockIdx.y;
    int gp  = chunkBase + loc;
    int t   = threadIdx.x;
    __shared__ float zr[128][14], zi[128][14];
    __shared__ float gr[8][16][14], gi[8][16][14];
    __shared__ float ct[128], st[128];
    if (t < 128) { double s, c; sincos(TWO_PI_D * t / 128.0, &s, &c);
                   st[t] = (float)s; ct[t] = (float)c; }
    for (int i = t; i < 1664; i += 256) {
        int r = i / 13, k = i - r*13;
        size_t si = ((size_t)loc*128 + r)*65 + kb + k;
        zr[r][k] = rre[si];
        zi[r][k] = rim[si];
    }
    __syncthreads();
    for (int i = t; i < 1664; i += 256) {
        int kx = i % 13, rm = i / 13;
        int r0 = rm >> 4, m = rm & 15;
        int step = (m << 3) & 127;
        float gre = 0.f, gim = 0.f;
        int idx = 0;
        for (int r1 = 0; r1 < 16; r1++) {
            float cc = ct[idx], sn = st[idx];
            float a = zr[(r1 << 3) + r0][kx], b = zi[(r1 << 3) + r0][kx];
            gre += a*cc + b*sn;
            gim += b*cc - a*sn;
            idx = (idx + step) & 127;
        }
        gr[r0][m][kx] = gre;
        gi[r0][m][kx] = gim;
    }
    __syncthreads();
    int lb = gp / 768; int chn = gp - lb*768;
    int T = chn >> 8;  int c = chn & 255;
    float* aD = spec + (size_t)(2*T)   * slotStride + ((size_t)(lb*256 + c))*8320;
    float* pD = spec + (size_t)(2*T+1) * slotStride + ((size_t)(lb*256 + c))*8320;
    for (int i = t; i < 1664; i += 256) {
        int kx = i % 13, k1 = i / 13;
        int m = k1 & 15;
        float re = 0.f, im = 0.f;
        int idx = 0;
        for (int r0 = 0; r0 < 8; r0++) {
            float cc = ct[idx], sn = st[idx];
            float a = gr[r0][m][kx], b = gi[r0][m][kx];
            re += a*cc + b*sn;
            im += b*cc - a*sn;
            idx = (idx + k1) & 127;
        }
        int kxv = kb + kx;
        // Self-conjugate rfft2 bins: im structurally zero; pocketfft gives
        // exact +0.0 -> angle in {0,+pi}. Force +0.0 so atan2 never flips
        // to -pi (decorrelates the winner-take-all phase attention).
        if ((k1 == 0 || k1 == 64) && (kxv == 0 || kxv == 64)) im = 0.f;
        int oi = k1*65 + kxv;
        aD[oi] = sqrtf(re*re + im*im);
        pD[oi] = atan2f(im, re);
    }
}

// ---------------- Attention: split-K partial sims (fp32, float4 LDS) -------
__global__ __launch_bounds__(256) void attn_sim_kernel(
    const float* __restrict__ qA, const float* __restrict__ kA,
    float* __restrict__ simpart)
{
    int sp = blockIdx.x;           // 0..15
    int bh = blockIdx.y;           // lb*8 + h
    int lb = bh >> 3, h = bh & 7;
    int t = threadIdx.x;
    __shared__ float qs[32][132], ks[32][132];
    const float* qb = qA + ((size_t)(lb*256 + h*32)) * 8320;
    const float* kb = kA + ((size_t)(lb*256 + h*32)) * 8320;
    float acc[4] = {0.f, 0.f, 0.f, 0.f};
    int j0 = t >> 5;
    int kq = t & 31;
    for (int sub = 0; sub < 4; sub++) {
        int n0 = sp*520 + sub*130;
        __syncthreads();
        for (int i = t; i < 4160; i += 256) {
            int j = i / 130, nn = i - j*130;
            qs[j][nn] = qb[(size_t)j*8320 + n0 + nn];
            ks[j][nn] = kb[(size_t)j*8320 + n0 + nn];
        }
        __syncthreads();
        for (int nn = 0; nn < 128; nn += 4) {
            float4 kv = *(const float4*)&ks[kq][nn];
            #pragma unroll
            for (int e = 0; e < 4; e++) {
                float4 qv = *(const float4*)&qs[j0 + e*8][nn];
                acc[e] += qv.x*kv.x + qv.y*kv.y + qv.z*kv.z + qv.w*kv.w;
            }
        }
        {
            float2 kv = *(const float2*)&ks[kq][128];
            #pragma unroll
            for (int e = 0; e < 4; e++) {
                float2 qv = *(const float2*)&qs[j0 + e*8][128];
                acc[e] += qv.x*kv.x + qv.y*kv.y;
            }
        }
    }
    float* dst = simpart + ((size_t)bh*16 + sp) * 1024;
    dst[t]       = acc[0];
    dst[t + 256] = acc[1];
    dst[t + 512] = acc[2];
    dst[t + 768] = acc[3];
}

// ---------------- Attention: reduce + softmax + PV (fp32) ------------------
__global__ __launch_bounds__(256) void attn_out_kernel(
    const float* __restrict__ simpart, const float* __restrict__ vA,
    float* __restrict__ outA)
{
    int nb = blockIdx.x << 8;
    int bh = blockIdx.y;
    int lb = bh >> 3, h = bh & 7;
    int t = threadIdx.x;
    __shared__ float sim[32][32];
    for (int e = t; e < 1024; e += 256) {
        float s = 0.f;
        const float* pp = simpart + (size_t)bh*16384 + e;
        #pragma unroll
        for (int sp = 0; sp < 16; sp++) s += pp[sp*1024];
        sim[e >> 5][e & 31] = s * ATTN_SCALE;
    }
    __syncthreads();
    if (t < 32) {
        float m = -1e30f;
        for (int k = 0; k < 32; k++) m = fmaxf(m, sim[t][k]);
        float s = 0.f;
        for (int k = 0; k < 32; k++) s += expf(sim[t][k] - m);
        float inv = 1.f / s;
        for (int k = 0; k < 32; k++) sim[t][k] = expf(sim[t][k] - m) * inv;
    }
    __syncthreads();
    int n = nb + t;
    if (n >= 8320) return;
    const float* vb = vA + ((size_t)(lb*256 + h*32)) * 8320 + n;
    float vv[32];
    #pragma unroll
    for (int k = 0; k < 32; k++) vv[k] = vb[(size_t)k * 8320];
    float* ob = outA + ((size_t)(lb*256 + h*32)) * 8320 + n;
    for (int j = 0; j < 32; j++) {
        float o = 0.f;
        #pragma unroll
        for (int k = 0; k < 32; k++) o += sim[j][k] * vv[k];
        ob[(size_t)j * 8320] = o;
    }
}

// ---------------- iFFT stage 1: fp16x2 MFMA vs constant M table ------------
// Per plane: T[256 rows (tre|tim)] = M[256x256] x zin[256][65], zin rows
// interleaved (2k1 -> zr, 2k1+1 -> zi) from amp*e^{i phase}. K chunks of 64.
__global__ __launch_bounds__(256) void ifftcol_mfma_kernel(
    const float* __restrict__ ampo, const float* __restrict__ pho,
    const _Float16* __restrict__ mih, const _Float16* __restrict__ mil,
    float* __restrict__ tre, float* __restrict__ tim)
{
    int plane = blockIdx.x;
    int t = threadIdx.x;
    int lane = t & 63;
    int wave = t >> 6;
    int wm = wave << 6;            // output-row offset: 0/64/128/192
    int lr = lane & 15;
    int kg = (lane >> 4) << 3;     // 0,8,16,24

    __shared__ _Float16 Bh[80][72], Bl[80][72];

    const float* ab = ampo + (size_t)plane * 8320;
    const float* pb = pho  + (size_t)plane * 8320;

    f32x4 acc[4][5];
    #pragma unroll
    for (int i = 0; i < 4; i++)
        #pragma unroll
        for (int j = 0; j < 5; j++) acc[i][j] = (f32x4){0.f, 0.f, 0.f, 0.f};

    for (int kc = 0; kc < 4; kc++) {       // zin rows kc*64 .. kc*64+63
        __syncthreads();
        for (int i = t; i < 2080; i += 256) {
            int k1l = i / 65, kx = i - k1l*65;      // k1l 0..31
            int k1 = (kc << 5) + k1l;
            float a = ab[k1*65 + kx];
            float p = pb[k1*65 + kx];
            float sp, cp; sincosf(p, &sp, &cp);
            float zr = a * cp, zi = a * sp;
            _Float16 hr = (_Float16)zr, hi = (_Float16)zi;
            unsigned uh = (unsigned)h_bits(hr) | ((unsigned)h_bits(hi) << 16);
            unsigned ul = (unsigned)h_bits((_Float16)(zr - (float)hr))
                        | ((unsigned)h_bits((_Float16)(zi - (float)hi)) << 16);
            *(unsigned*)&Bh[kx][k1l << 1] = uh;
            *(unsigned*)&Bl[kx][k1l << 1] = ul;
        }
        __syncthreads();
        #pragma unroll
        for (int ks = 0; ks < 2; ks++) {
            int kq = (ks << 5) + kg;               // local K in [0,64)
            int kgl = (kc << 6) + kq;              // global K
            half8v ah[4], al[4], bh[5], bl[5];
            #pragma unroll
            for (int i = 0; i < 4; i++) {
                int row = wm + i*16 + lr;
                ah[i] = *(const half8v*)&mih[(size_t)row * 256 + kgl];
                al[i] = *(const half8v*)&mil[(size_t)row * 256 + kgl];
            }
            #pragma unroll
            for (int j = 0; j < 5; j++) {
                int col = j*16 + lr;
                bh[j] = *(const half8v*)&Bh[col][kq];
                bl[j] = *(const half8v*)&Bl[col][kq];
            }
            #pragma unroll
            for (int i = 0; i < 4; i++)
                #pragma unroll
                for (int j = 0; j < 5; j++) {
                    acc[i][j] = __builtin_amdgcn_mfma_f32_16x16x32_f16(
                        ah[i], bh[j], acc[i][j], 0, 0, 0);
                    acc[i][j] = __builtin_amdgcn_mfma_f32_16x16x32_f16(
                        al[i], bh[j], acc[i][j], 0, 0, 0);
                    acc[i][j] = __builtin_amdgcn_mfma_f32_16x16x32_f16(
                        ah[i], bl[j], acc[i][j], 0, 0, 0);
                }
        }
    }

    int mr = (lane >> 4) << 2;
    #pragma unroll
    for (int i = 0; i < 4; i++) {
        #pragma unroll
        for (int j = 0; j < 5; j++) {
            int col = j*16 + lr;
            if (col < 65) {
                #pragma unroll
                for (int r = 0; r < 4; r++) {
                    int row = wm + i*16 + mr + r;
                    if (row < 128)
                        tre[((size_t)plane*128 + row)*65 + col] = acc[i][j][r];
                    else
                        tim[((size_t)plane*128 + (row - 128))*65 + col] = acc[i][j][r];
                }
            }
        }
    }
}

// ---------------- iFFT stage 2: Hermitian rows, output-folded, 4-row -------
__global__ __launch_bounds__(256) void ifft_row_kernel(
    const float* __restrict__ tre, const float* __restrict__ tim,
    float* __restrict__ spat)
{
    int rc    = blockIdx.x;        // 0..7
    int plane = blockIdx.y;
    int t     = threadIdx.x;
    __shared__ float tr[16][66], ti[16][66];
    __shared__ float ct[128], st[128];
    if (t < 128) { double s, c; sincos(TWO_PI_D * t / 128.0, &s, &c);
                   st[t] = (float)s; ct[t] = (float)c; }
    for (int i = t; i < 1040; i += 256) {
        int r = i / 65, k = i - r*65;
        size_t si = ((size_t)plane*128 + rc*16 + r)*65 + k;
        float sc = (k >= 1 && k < 64) ? 2.f : 1.f;
        tr[r][k] = tre[si] * sc;
        ti[r][k] = tim[si] * sc;
    }
    __syncthreads();
    for (int oo = t; oo < 260; oo += 256) {
        int x = oo % 65, rq = oo / 65;
        int r0i = rq << 2;
        float C0 = tr[r0i+0][0], C1 = tr[r0i+1][0], C2 = tr[r0i+2][0], C3 = tr[r0i+3][0];
        float S0 = 0.f, S1 = 0.f, S2 = 0.f, S3 = 0.f;
        int m = x;
        for (int k = 1; k <= 64; k++) {
            float cc = ct[m], sn = st[m];
            C0 += tr[r0i+0][k]*cc; S0 += ti[r0i+0][k]*sn;
            C1 += tr[r0i+1][k]*cc; S1 += ti[r0i+1][k]*sn;
            C2 += tr[r0i+2][k]*cc; S2 += ti[r0i+2][k]*sn;
            C3 += tr[r0i+3][k]*cc; S3 += ti[r0i+3][k]*sn;
            m = (m + x) & 127;
        }
        size_t ob = ((size_t)plane << 14) + ((rc*16 + r0i) << 7);
        spat[ob + x]       = (C0 - S0)*0.0078125f;
        spat[ob + 128 + x] = (C1 - S1)*0.0078125f;
        spat[ob + 256 + x] = (C2 - S2)*0.0078125f;
        spat[ob + 384 + x] = (C3 - S3)*0.0078125f;
        if (x >= 1 && x <= 63) {
            int xm = 128 - x;
            spat[ob + xm]       = (C0 + S0)*0.0078125f;
            spat[ob + 128 + xm] = (C1 + S1)*0.0078125f;
            spat[ob + 256 + xm] = (C2 + S2)*0.0078125f;
            spat[ob + 384 + xm] = (C3 + S3)*0.0078125f;
        }
    }
}

// ---------------- weight pre-transform: fp32 [Co][Ci][R][R] -> bf16 [RR][Co][Ci]
__global__ __launch_bounds__(256) void wcvt_kernel(
    const float* __restrict__ w, short* __restrict__ wbf,
    int Cout, int Cin, int RR)
{
    int i = blockIdx.x * 256 + threadIdx.x;
    int total = Cout * Cin * RR;
    if (i >= total) return;
    int rr = i % RR;
    int ci = (i / RR) % Cin;
    int co = i / (RR * Cin);
    wbf[((size_t)rr * Cout + co) * Cin + ci] = f2bf(w[i]);
}

// ---------------- bf16 MFMA conv v2 (ao: fp32 in, LDS staged) --------------
__global__ __launch_bounds__(256) void convmf2_kernel(
    const float* __restrict__ in, const short* __restrict__ wbf,
    const float* __restrict__ bias, const float* __restrict__ res,
    float* __restrict__ out, short* __restrict__ out_t,
    int Cin, int Cout, int act, int in_b0, int res_b0, int out_b0)
{
    int y      = blockIdx.x;
    int coBase = blockIdx.y << 7;
    int lb = blockIdx.z;
    int t = threadIdx.x;
    int lane = t & 63;
    int wave = t >> 6;
    int wm = (wave >> 1) << 6;
    int wn = (wave & 1) << 6;

    __shared__ short As[128][40];
    __shared__ short Bs[128][40];

    f32x4 acc[4][4];
    #pragma unroll
    for (int i = 0; i < 4; i++)
        #pragma unroll
        for (int j = 0; j < 4; j++) acc[i][j] = (f32x4){0.f, 0.f, 0.f, 0.f};

    const size_t inb = ((size_t)(in_b0 + lb) * Cin) << 14;
    int lr = lane & 15;
    int kg = (lane >> 4) << 3;

    const float* inrow = in + inb + (y << 7);
    const short* wslice = wbf + (size_t)coBase * Cin;
    for (int ci0 = 0; ci0 < Cin; ci0 += 32) {
        __syncthreads();
        #pragma unroll
        for (int u = 0; u < 2; u++) {
            int ii = t + (u << 8);
            int co = ii >> 2, cg = ii & 3;
            *(short8*)&As[co][cg << 3] =
                *(const short8*)&wslice[(size_t)co * Cin + ci0 + (cg << 3)];
        }
        for (int i = t; i < 2048; i += 256) {
            int px = i & 127, chp = i >> 7;
            int ci = ci0 + (chp << 1);
            float v0 = inrow[((size_t)ci << 14) + px];
            float v1 = inrow[((size_t)(ci + 1) << 14) + px];
            unsigned u2 = (unsigned)(unsigned short)f2bf(v0)
                        | ((unsigned)(unsigned short)f2bf(v1) << 16);
            *(unsigned*)&Bs[px][chp << 1] = u2;
        }
        __syncthreads();
        short8 af[4], bf[4];
        #pragma unroll
        for (int i = 0; i < 4; i++)
            af[i] = *(const short8*)&As[wm + i*16 + lr][kg];
        #pragma unroll
        for (int j = 0; j < 4; j++)
            bf[j] = *(const short8*)&Bs[wn + j*16 + lr][kg];
        #pragma unroll
        for (int i = 0; i < 4; i++)
            #pragma unroll
            for (int j = 0; j < 4; j++)
                acc[i][j] = __builtin_amdgcn_mfma_f32_16x16x32_bf16(
                    af[i], bf[j], acc[i][j], 0, 0, 0);
    }

    int pBase = y << 7;
    int mr = (lane >> 4) << 2;
    #pragma unroll
    for (int i = 0; i < 4; i++) {
        int co0 = coBase + wm + i*16 + mr;
        #pragma unroll
        for (int j = 0; j < 4; j++) {
            int px = pBase + wn + j*16 + lr;
            float v[4];
            #pragma unroll
            for (int r = 0; r < 4; r++) {
                float vv = acc[i][j][r] + (bias ? bias[co0 + r] : 0.f);
                if (act == 1) vv = vv / (1.f + expf(-vv));
                if (res) vv += res[(((size_t)(res_b0 + lb) * Cout + co0 + r) << 14) + px];
                v[r] = vv;
            }
            if (out) {
                #pragma unroll
                for (int r = 0; r < 4; r++)
                    out[(((size_t)(out_b0 + lb) * Cout + co0 + r) << 14) + px] = v[r];
            }
            if (out_t) {
                short4v s4 = { f2bf(v[0]), f2bf(v[1]), f2bf(v[2]), f2bf(v[3]) };
                *(short4v*)&out_t[((size_t)(lb*16384 + px)) * Cout + co0] = s4;
            }
        }
    }
}

// ---------------- bf16 MFMA conv v3: direct-load, bf16T activations --------
template<int R>
__global__ __launch_bounds__(256) void convmf3_kernel(
    const short* __restrict__ in_t, const short* __restrict__ wbf,
    const float* __restrict__ bias, const float* __restrict__ res,
    float* __restrict__ out, short* __restrict__ out_t,
    int Cin, int Cout, int act, int res_b0, int out_b0)
{
    int y      = blockIdx.x;
    int coBase = blockIdx.y << 7;
    int lb = blockIdx.z;
    int t = threadIdx.x;
    int lane = t & 63;
    int wave = t >> 6;
    int wm = (wave >> 1) << 6;
    int wn = (wave & 1) << 6;
    int lr = lane & 15;
    int kg = (lane >> 4) << 3;

    f32x4 acc[4][4];
    #pragma unroll
    for (int i = 0; i < 4; i++)
        #pragma unroll
        for (int j = 0; j < 4; j++) acc[i][j] = (f32x4){0.f, 0.f, 0.f, 0.f};

    const short* inb = in_t + (((size_t)lb << 14)) * Cin;
    const short8 zero8 = {0,0,0,0,0,0,0,0};

    for (int rr = 0; rr < R*R; rr++) {
        int dy = (R == 3) ? (rr / 3) : 0;
        int dx = (R == 3) ? (rr - dy*3) : 0;
        int yy = (R == 3) ? (y + dy - 1) : y;
        if (R == 3 && (yy < 0 || yy > 127)) continue;
        const short* wsl  = wbf + ((size_t)rr * Cout + coBase) * Cin;
        const short* brow = inb + ((size_t)(yy << 7)) * Cin;
        for (int ci0 = 0; ci0 < Cin; ci0 += 32) {
            short8 af[4], bf[4];
            #pragma unroll
            for (int i = 0; i < 4; i++)
                af[i] = *(const short8*)&wsl[(size_t)(wm + i*16 + lr) * Cin + ci0 + kg];
            #pragma unroll
            for (int j = 0; j < 4; j++) {
                int pxl = wn + j*16 + lr;
                int xx = (R == 3) ? (pxl + dx - 1) : pxl;
                if (R == 3 && (xx < 0 || xx > 127)) bf[j] = zero8;
                else bf[j] = *(const short8*)&brow[(size_t)xx * Cin + ci0 + kg];
            }
            #pragma unroll
            for (int i = 0; i < 4; i++)
                #pragma unroll
                for (int j = 0; j < 4; j++)
                    acc[i][j] = __builtin_amdgcn_mfma_f32_16x16x32_bf16(
                        af[i], bf[j], acc[i][j], 0, 0, 0);
        }
    }

    int pBase = y << 7;
    int mr = (lane >> 4) << 2;
    #pragma unroll
    for (int i = 0; i < 4; i++) {
        int co0 = coBase + wm + i*16 + mr;
        #pragma unroll
        for (int j = 0; j < 4; j++) {
            int px = pBase + wn + j*16 + lr;
            float v[4];
            #pragma unroll
            for (int r = 0; r < 4; r++) {
                float vv = acc[i][j][r] + (bias ? bias[co0 + r] : 0.f);
                if (act == 1) vv = vv / (1.f + expf(-vv));
                if (res) vv += res[(((size_t)(res_b0 + lb) * Cout + co0 + r) << 14) + px];
                v[r] = vv;
            }
            if (out) {
                #pragma unroll
                for (int r = 0; r < 4; r++)
                    out[(((size_t)(out_b0 + lb) * Cout + co0 + r) << 14) + px] = v[r];
            }
            if (out_t) {
                short4v s4 = { f2bf(v[0]), f2bf(v[1]), f2bf(v[2]), f2bf(v[3]) };
                *(short4v*)&out_t[((size_t)(lb*16384 + px)) * Cout + co0] = s4;
            }
        }
    }
}

// ---------------------------------------------------------------------------
extern "C" void kernel_launch(void* const* d_in, const int* in_sizes, int n_in,
                              void* d_out, int out_size, void* d_ws, size_t ws_size,
                              hipStream_t stream) {
    (void)in_sizes; (void)n_in; (void)out_size;
    const float* x    = (const float*)d_in[0];
    const float* gn_w = (const float*)d_in[1];
    const float* gn_b = (const float*)d_in[2];
    const float* dw_w = (const float*)d_in[3];
    const float* pw_w = (const float*)d_in[4];
    const float* pw_b = (const float*)d_in[5];
    const float* ao_w = (const float*)d_in[6];
    const float* ao_b = (const float*)d_in[7];
    const float* f1_w = (const float*)d_in[8];
    const float* f2_w = (const float*)d_in[9];
    const float* f3_w = (const float*)d_in[10];
    const float* f3_b = (const float*)d_in[11];
    float* outp = (float*)d_out;

    // per-batch region sizes in floats
    const size_t F_QKV  = 12582912;   // qkv; later abuf/h1t/h2t (bf16T)
    const size_t F_SLOT = 2129920;
    const size_t F_SPEC = 6 * F_SLOT;
    const size_t F_XN   = 4194304;
    const size_t F_E    = 4259840;    // max(dw; rre+rim)
    const size_t F_SIMP = 262144;     // invn / fp32 simpart
    const size_t F_TOT  = F_QKV + F_SPEC + F_XN + F_E + F_SIMP; // 34,078,720
    const size_t F_WB   = 1527808;    // bf16 weights + pw/twiddle/M fp16 hi/lo

    int NB = 0;
    for (int cand : {8, 4, 2, 1}) {
        if (((size_t)cand * F_TOT + F_WB) * 4 <= ws_size) { NB = cand; break; }
    }
    if (NB == 0) return;

    float* wsf  = (float*)d_ws;
    float* qkv  = wsf;
    short* abuf = (short*)wsf;                           // [NB][16384][256]
    short* h1t  = (short*)(wsf + (size_t)NB * 2097152);  // [NB][16384][512]
    short* h2t  = (short*)(wsf + (size_t)NB * 6291456);  // [NB][16384][256]
    float* spec = wsf + (size_t)NB * F_QKV;
    size_t ss   = (size_t)NB * F_SLOT;
    float* tre  = spec + 2*ss;
    float* tim  = spec + 3*ss;
    float* spat = spec + 4*ss;
    float* xn   = spec + 6*ss;
    float* ebuf = xn + (size_t)NB * F_XN;
    float* dw   = ebuf;
    float* rre  = ebuf;
    float* rim  = ebuf + (size_t)NB * 2129920;
    float* simpf = ebuf + (size_t)NB * F_E;
    float* invn  = simpf;
    float* simp  = simpf;
    short* wb    = (short*)(wsf + (size_t)NB * F_TOT);
    short* wb_ao = wb;
    short* wb_f1 = wb + 65536;
    short* wb_f2 = wb + 1245184;
    short* wb_f3 = wb + 2424832;
    _Float16* wb_pw_hi = (_Float16*)(wb + 2490368);
    _Float16* wb_pw_lo = (_Float16*)(wb + 2686976);
    _Float16* wb_tw_hi = (_Float16*)(wb + 2883584);
    _Float16* wb_tw_lo = (_Float16*)(wb + 2904064);
    _Float16* wb_mi_hi = (_Float16*)(wb + 2924544);
    _Float16* wb_mi_lo = (_Float16*)(wb + 2990080);

    wcvt_kernel<<<256,  256, 0, stream>>>(ao_w, wb_ao, 256, 256, 1);
    wcvt_kernel<<<4608, 256, 0, stream>>>(f1_w, wb_f1, 512, 256, 9);
    wcvt_kernel<<<4608, 256, 0, stream>>>(f2_w, wb_f2, 256, 512, 9);
    wcvt_kernel<<<256,  256, 0, stream>>>(f3_w, wb_f3, 256, 256, 1);
    wcvtpw_kernel<<<768, 256, 0, stream>>>(pw_w, wb_pw_hi, wb_pw_lo, 196608);
    twcvt_kernel<<<80, 256, 0, stream>>>(wb_tw_hi, wb_tw_lo);
    micvt_kernel<<<256, 256, 0, stream>>>(wb_mi_hi, wb_mi_lo);

    const int passes = 8 / NB;
    for (int p = 0; p < passes; p++) {
        int b0 = p * NB;
        // 1. GroupNorm -> xn
        groupnorm_kernel<<<NB*32, 256, 0, stream>>>(x, gn_w, gn_b, xn, b0);
        // 2. depthwise 3x3 (LDS halo): xn -> dw
        dwconv_kernel<<<NB*256*64, 256, 0, stream>>>(xn, dw_w, dw);
        // 3. pointwise 256->768 (+bias): fp16x2 split MFMA -> qkv
        convpw_kernel<<<dim3(128, 6, NB), 256, 0, stream>>>(
            dw, wb_pw_hi, wb_pw_lo, pw_b, qkv);
        // 4. inverse L2 norms (applied inside fftrow_mfma)
        l2inv_kernel<<<NB*3*64, 256, 0, stream>>>(qkv, invn);
        // 5. rfft2 -> amp/phase spec slots, 3 chunks of NB*256 planes
        for (int chunk = 0; chunk < 3; chunk++) {
            fftrow_mfma_kernel<<<NB*256, 256, 0, stream>>>(
                qkv, invn, wb_tw_hi, wb_tw_lo, rre, rim, chunk*NB*256);
            fft_col_kernel<<<dim3(5, NB*256), 256, 0, stream>>>(
                rre, rim, spec, chunk*NB*256, ss);
        }
        // 6. channel attention (split-K, fp32)
        attn_sim_kernel<<<dim3(16, NB*8), 256, 0, stream>>>(spec + 0*ss, spec + 2*ss, simp);
        attn_out_kernel<<<dim3(33, NB*8), 256, 0, stream>>>(simp, spec + 4*ss, spec + 0*ss);
        attn_sim_kernel<<<dim3(16, NB*8), 256, 0, stream>>>(spec + 1*ss, spec + 3*ss, simp);
        attn_out_kernel<<<dim3(33, NB*8), 256, 0, stream>>>(simp, spec + 5*ss, spec + 1*ss);
        // 7. irfft2: slots 0,1 -> tre/tim (fp16x2 MFMA) -> spat (VALU rows)
        ifftcol_mfma_kernel<<<NB*256, 256, 0, stream>>>(
            spec + 0*ss, spec + 1*ss, wb_mi_hi, wb_mi_lo, tre, tim);
        ifft_row_kernel<<<dim3(8, NB*256), 256, 0, stream>>>(tre, tim, spat);
        // 8. ao 1x1 (+bias) + xn residual -> d_out fp32 + abuf bf16T
        convmf2_kernel<<<dim3(128, 2, NB), 256, 0, stream>>>(
            spat, wb_ao, ao_b, xn, outp, abuf, 256, 256, 0, 0, 0, b0);
        // 9. f1 3x3 256->512 + SiLU: abuf -> h1t (bf16T only)   [direct-load]
        convmf3_kernel<3><<<dim3(128, 4, NB), 256, 0, stream>>>(
            abuf, wb_f1, nullptr, nullptr, nullptr, h1t, 256, 512, 1, 0, 0);
        // 10. f2 3x3 512->256: h1t -> h2t                        [direct-load]
        convmf3_kernel<3><<<dim3(128, 2, NB), 256, 0, stream>>>(
            h1t, wb_f2, nullptr, nullptr, nullptr, h2t, 512, 256, 0, 0, 0);
        // 11. f3 1x1 (+bias) + attn residual -> d_out fp32       [direct-load]
        convmf3_kernel<1><<<dim3(128, 2, NB), 256, 0, stream>>>(
            h2t, wb_f3, f3_b, outp, outp, nullptr, 256, 256, 0, b0, b0);
    }
}

// Round 19
// 6175.592 us; speedup vs baseline: 5.3623x; 1.0255x over previous
//
#include <hip/hip_runtime.h>
#include <hip/hip_bf16.h>
#include <math.h>

// ---------------------------------------------------------------------------
// FreqCA: B=8, C=256, H=W=128, NHEADS=8, GROUPS=32.
// Round 19: convmf3 ci0 loop fully unrolled (immediate-offset folding +
// load/MFMA software pipelining; offsets span <=448B, fits 13-bit imm).
// Everything else identical to round 18: fp16x2 MFMA fftrow/ifftcol/pw,
// radix-16x8 fft_col, folded ifft_row, fp32 attention, bf16 MFMA tail.
// Self-conjugate rfft2 bins forced im=+0.0 (pocketfft +pi convention).
// ---------------------------------------------------------------------------

#define TWO_PI_D 6.283185307179586476925286766559
#define ATTN_SCALE 0.17677669529663687f  // 1/sqrt(32)

typedef __attribute__((ext_vector_type(8))) short short8;
typedef __attribute__((ext_vector_type(4))) short short4v;
typedef __attribute__((ext_vector_type(4))) float f32x4;
typedef _Float16 half8v __attribute__((ext_vector_type(8)));

__device__ inline short f2bf(float f) {
    __hip_bfloat16 h = __float2bfloat16(f);
    return *reinterpret_cast<short*>(&h);
}
__device__ inline unsigned short h_bits(_Float16 h) {
    union { _Float16 h; unsigned short u; } c; c.h = h; return c.u;
}

// ---------------- GroupNorm: fp64 stats, fp32 out --------------------------
__global__ __launch_bounds__(256) void groupnorm_kernel(
    const float* __restrict__ x, const float* __restrict__ gw,
    const float* __restrict__ gb, float* __restrict__ out, int b0)
{
    int t = threadIdx.x;
    int lb = blockIdx.x >> 5;
    int g  = blockIdx.x & 31;
    size_t src = ((size_t)(b0 + lb) * 32 + g) * 131072;
    size_t dst = (size_t)blockIdx.x * 131072;
    const float* xp = x + src;
    double s = 0.0, ss = 0.0;
    for (int i = t; i < 131072; i += 256) { double v = xp[i]; s += v; ss += v*v; }
    __shared__ double rs[256], rss[256];
    rs[t] = s; rss[t] = ss;
    __syncthreads();
    for (int k = 128; k > 0; k >>= 1) {
        if (t < k) { rs[t] += rs[t+k]; rss[t] += rss[t+k]; }
        __syncthreads();
    }
    __shared__ float smean, sinv;
    if (t == 0) {
        double mean = rs[0] * (1.0/131072.0);
        double var  = rss[0] * (1.0/131072.0) - mean*mean;
        smean = (float)mean;
        sinv  = (float)(1.0 / sqrt(var + 1e-5));
    }
    __syncthreads();
    float mean = smean, inv = sinv;
    for (int i = t; i < 131072; i += 256) {
        int c = (g << 3) + (i >> 14);
        out[dst + i] = (xp[i] - mean) * inv * gw[c] + gb[c];
    }
}

// ---------------- Depthwise 3x3 fp32, LDS halo -----------------------------
__global__ __launch_bounds__(256) void dwconv_kernel(
    const float* __restrict__ in, const float* __restrict__ w, float* __restrict__ out)
{
    int t = threadIdx.x;
    int bc = blockIdx.x >> 6;
    int ystrip = (blockIdx.x & 63) << 1;
    int c  = bc & 255;
    const float* wp = w + c*9;
    const float* ip = in + ((size_t)bc << 14);
    __shared__ float xs[4][128];
    for (int i = t; i < 512; i += 256) {
        int rr = i >> 7, xx = i & 127;
        int yy = ystrip - 1 + rr;
        xs[rr][xx] = (yy >= 0 && yy < 128) ? ip[(yy << 7) + xx] : 0.f;
    }
    __syncthreads();
    int r0 = t >> 7;
    int x  = t & 127;
    float acc = 0.f;
    #pragma unroll
    for (int dy = 0; dy < 3; dy++) {
        const float* row = xs[r0 + dy];
        #pragma unroll
        for (int dx = 0; dx < 3; dx++) {
            int xx = x + dx - 1;
            if (xx >= 0 && xx <= 127) acc += wp[dy*3+dx] * row[xx];
        }
    }
    out[((size_t)bc << 14) + ((ystrip + r0) << 7) + x] = acc;
}

// ---------------- pw weight split: fp32 [768][256] -> fp16 hi/lo -----------
__global__ __launch_bounds__(256) void wcvtpw_kernel(
    const float* __restrict__ w, _Float16* __restrict__ whi,
    _Float16* __restrict__ wlo, int total)
{
    int i = blockIdx.x * 256 + threadIdx.x;
    if (i >= total) return;
    float v = w[i];
    _Float16 h = (_Float16)v;
    _Float16 l = (_Float16)(v - (float)h);
    whi[i] = h; wlo[i] = l;
}

// ---------------- row-DFT twiddle table: [160 bins][128 w] fp16 hi/lo ------
__global__ __launch_bounds__(256) void twcvt_kernel(
    _Float16* __restrict__ twh, _Float16* __restrict__ twl)
{
    int i = blockIdx.x * 256 + threadIdx.x;
    if (i >= 20480) return;
    int bin = i >> 7, w = i & 127;
    double v = 0.0;
    if (bin < 65) v = cos(TWO_PI_D * ((bin * w) & 127) / 128.0) * 0.0078125;
    else if (bin < 130) v = -sin(TWO_PI_D * (((bin - 65) * w) & 127) / 128.0) * 0.0078125;
    _Float16 h = (_Float16)v;
    twh[i] = h;
    twl[i] = (_Float16)((float)v - (float)h);
}

// ---------------- ifft-col M table: [256 rows][256 zin] fp16 hi/lo ---------
__global__ __launch_bounds__(256) void micvt_kernel(
    _Float16* __restrict__ mih, _Float16* __restrict__ mil)
{
    int i = blockIdx.x * 256 + threadIdx.x;
    if (i >= 65536) return;
    int row = i >> 8, col = i & 255;
    int k1 = col >> 1, u = col & 1;
    int yy = row & 127;
    double ang = TWO_PI_D * ((k1 * yy) & 127) / 128.0;
    double cc = cos(ang), sn = sin(ang);
    double v;
    if (row < 128) v = (u == 0) ? cc : -sn;
    else           v = (u == 0) ? sn :  cc;
    _Float16 h = (_Float16)v;
    mih[i] = h;
    mil[i] = (_Float16)((float)v - (float)h);
}

// ---------------- pw conv: fp16x2 split MFMA (Cin=256 -> Cout=768) ---------
__global__ __launch_bounds__(256) void convpw_kernel(
    const float* __restrict__ in, const _Float16* __restrict__ whi,
    const _Float16* __restrict__ wlo, const float* __restrict__ bias,
    float* __restrict__ out)
{
    int y      = blockIdx.x;
    int coBase = blockIdx.y << 7;
    int lb     = blockIdx.z;
    int t = threadIdx.x;
    int lane = t & 63;
    int wave = t >> 6;
    int wm = (wave >> 1) << 6;
    int wn = (wave & 1) << 6;
    int lr = lane & 15;
    int kg = (lane >> 4) << 3;

    __shared__ _Float16 Ah[128][40], Al[128][40];
    __shared__ _Float16 Bh[128][40], Bl[128][40];

    f32x4 acc[4][4];
    #pragma unroll
    for (int i = 0; i < 4; i++)
        #pragma unroll
        for (int j = 0; j < 4; j++) acc[i][j] = (f32x4){0.f, 0.f, 0.f, 0.f};

    const float* inrow = in + (((size_t)lb * 256) << 14) + (y << 7);
    for (int ci0 = 0; ci0 < 256; ci0 += 32) {
        __syncthreads();
        #pragma unroll
        for (int u = 0; u < 2; u++) {
            int ii = t + (u << 8);
            int co = ii >> 2, cg = ii & 3;
            *(half8v*)&Ah[co][cg << 3] =
                *(const half8v*)&whi[(size_t)(coBase + co) * 256 + ci0 + (cg << 3)];
            *(half8v*)&Al[co][cg << 3] =
                *(const half8v*)&wlo[(size_t)(coBase + co) * 256 + ci0 + (cg << 3)];
        }
        for (int i = t; i < 2048; i += 256) {
            int px = i & 127, chp = i >> 7;
            int ci = ci0 + (chp << 1);
            float v0 = inrow[((size_t)ci << 14) + px];
            float v1 = inrow[((size_t)(ci + 1) << 14) + px];
            _Float16 h0 = (_Float16)v0, h1 = (_Float16)v1;
            _Float16 l0 = (_Float16)(v0 - (float)h0);
            _Float16 l1 = (_Float16)(v1 - (float)h1);
            unsigned uh = (unsigned)h_bits(h0) | ((unsigned)h_bits(h1) << 16);
            unsigned ul = (unsigned)h_bits(l0) | ((unsigned)h_bits(l1) << 16);
            *(unsigned*)&Bh[px][chp << 1] = uh;
            *(unsigned*)&Bl[px][chp << 1] = ul;
        }
        __syncthreads();
        half8v ah[4], al[4], bh4[4], bl4[4];
        #pragma unroll
        for (int i = 0; i < 4; i++) {
            ah[i] = *(const half8v*)&Ah[wm + i*16 + lr][kg];
            al[i] = *(const half8v*)&Al[wm + i*16 + lr][kg];
        }
        #pragma unroll
        for (int j = 0; j < 4; j++) {
            bh4[j] = *(const half8v*)&Bh[wn + j*16 + lr][kg];
            bl4[j] = *(const half8v*)&Bl[wn + j*16 + lr][kg];
        }
        #pragma unroll
        for (int i = 0; i < 4; i++)
            #pragma unroll
            for (int j = 0; j < 4; j++) {
                acc[i][j] = __builtin_amdgcn_mfma_f32_16x16x32_f16(
                    ah[i], bh4[j], acc[i][j], 0, 0, 0);
                acc[i][j] = __builtin_amdgcn_mfma_f32_16x16x32_f16(
                    ah[i], bl4[j], acc[i][j], 0, 0, 0);
                acc[i][j] = __builtin_amdgcn_mfma_f32_16x16x32_f16(
                    al[i], bh4[j], acc[i][j], 0, 0, 0);
            }
    }

    int pBase = y << 7;
    int mr = (lane >> 4) << 2;
    #pragma unroll
    for (int i = 0; i < 4; i++) {
        int co0 = coBase + wm + i*16 + mr;
        #pragma unroll
        for (int j = 0; j < 4; j++) {
            int px = pBase + wn + j*16 + lr;
            #pragma unroll
            for (int r = 0; r < 4; r++) {
                out[(((size_t)(lb*768 + co0 + r)) << 14) + px] =
                    acc[i][j][r] + bias[co0 + r];
            }
        }
    }
}

// ---------------- inverse L2 norms per pixel (no write-back) ---------------
__global__ __launch_bounds__(256) void l2inv_kernel(
    const float* __restrict__ qkv, float* __restrict__ invn)
{
    int p  = ((blockIdx.x & 63) << 8) + threadIdx.x;
    int bT = blockIdx.x >> 6;          // lb*3 + T
    int lb = bT / 3, T = bT - 3*lb;
    const float* base = qkv + (((size_t)(lb*768 + T*256)) << 14) + p;
    double ss = 0.0;
    for (int c = 0; c < 256; c++) { double v = base[(size_t)c << 14]; ss += v*v; }
    invn[((size_t)bT << 14) + p] = 1.f / fmaxf((float)sqrt(ss), 1e-12f);
}

// ---------------- FFT stage 1: row DFT as fp16x2 MFMA GEMM -----------------
__global__ __launch_bounds__(256) void fftrow_mfma_kernel(
    const float* __restrict__ qkv, const float* __restrict__ invn,
    const _Float16* __restrict__ twh, const _Float16* __restrict__ twl,
    float* __restrict__ rre, float* __restrict__ rim, int chunkBase)
{
    int loc = blockIdx.x;
    int gp  = chunkBase + loc;
    int t = threadIdx.x;
    int lane = t & 63;
    int wave = t >> 6;
    int wm  = (wave >> 1) << 6;
    int wnn = (wave & 1) * 80;
    int lr = lane & 15;
    int kq = (lane >> 4) << 3;

    __shared__ _Float16 Xh[128][68], Xl[128][68];

    int lb = gp / 768, chn = gp - lb*768, T = chn >> 8;
    const float4* src = (const float4*)(qkv + ((size_t)gp << 14));
    const float4* ivp = (const float4*)(invn + (((size_t)(lb*3 + T)) << 14));

    f32x4 acc[4][5];
    #pragma unroll
    for (int i = 0; i < 4; i++)
        #pragma unroll
        for (int j = 0; j < 5; j++) acc[i][j] = (f32x4){0.f, 0.f, 0.f, 0.f};

    for (int half = 0; half < 2; half++) {
        __syncthreads();
        for (int i = t; i < 2048; i += 256) {
            int r = i >> 4, q4 = i & 15;
            int gi = (r << 5) + (half << 4) + q4;
            float4 v = src[gi], w = ivp[gi];
            v.x *= w.x; v.y *= w.y; v.z *= w.z; v.w *= w.w;
            int cl = q4 << 2;
            _Float16 h0 = (_Float16)v.x, h1 = (_Float16)v.y;
            _Float16 h2 = (_Float16)v.z, h3 = (_Float16)v.w;
            Xh[r][cl+0] = h0; Xh[r][cl+1] = h1; Xh[r][cl+2] = h2; Xh[r][cl+3] = h3;
            Xl[r][cl+0] = (_Float16)(v.x - (float)h0);
            Xl[r][cl+1] = (_Float16)(v.y - (float)h1);
            Xl[r][cl+2] = (_Float16)(v.z - (float)h2);
            Xl[r][cl+3] = (_Float16)(v.w - (float)h3);
        }
        __syncthreads();
        #pragma unroll
        for (int ks = 0; ks < 2; ks++) {
            int k0 = (ks << 5) + kq;
            int kg = (half << 6) + k0;
            half8v ah[4], al[4], bh[5], bl[5];
            #pragma unroll
            for (int i = 0; i < 4; i++) {
                ah[i] = *(const half8v*)&Xh[wm + i*16 + lr][k0];
                al[i] = *(const half8v*)&Xl[wm + i*16 + lr][k0];
            }
            #pragma unroll
            for (int j = 0; j < 5; j++) {
                int bin = wnn + j*16 + lr;
                bh[j] = *(const half8v*)&twh[(size_t)bin * 128 + kg];
                bl[j] = *(const half8v*)&twl[(size_t)bin * 128 + kg];
            }
            #pragma unroll
            for (int i = 0; i < 4; i++)
                #pragma unroll
                for (int j = 0; j < 5; j++) {
                    acc[i][j] = __builtin_amdgcn_mfma_f32_16x16x32_f16(
                        ah[i], bh[j], acc[i][j], 0, 0, 0);
                    acc[i][j] = __builtin_amdgcn_mfma_f32_16x16x32_f16(
                        al[i], bh[j], acc[i][j], 0, 0, 0);
                    acc[i][j] = __builtin_amdgcn_mfma_f32_16x16x32_f16(
                        ah[i], bl[j], acc[i][j], 0, 0, 0);
                }
        }
    }

    int mr = (lane >> 4) << 2;
    #pragma unroll
    for (int i = 0; i < 4; i++) {
        #pragma unroll
        for (int j = 0; j < 5; j++) {
            int bin = wnn + j*16 + lr;
            if (bin < 130) {
                float* dst = (bin < 65) ? rre : rim;
                int bb = (bin < 65) ? bin : bin - 65;
                #pragma unroll
                for (int r = 0; r < 4; r++) {
                    int row = wm + i*16 + mr + r;
                    dst[((size_t)loc*128 + row)*65 + bb] = acc[i][j][r];
                }
            }
        }
    }
}

// ---------------- FFT stage 2: radix-16x8 col DFT -> amp/phase -------------
__global__ __launch_bounds__(256) void fft_col_kernel(
    const float* __restrict__ rre, const float* __restrict__ rim,
    float* __restrict__ spec, int chunkBase, size_t slotStride)
{
    int kb  = blockIdx.x * 13;
    int loc = blockIdx.y;
    int gp  = chunkBase + loc;
    int t   = threadIdx.x;
    __shared__ float zr[128][14], zi[128][14];
    __shared__ float gr[8][16][14], gi[8][16][14];
    __shared__ float ct[128], st[128];
    if (t < 128) { double s, c; sincos(TWO_PI_D * t / 128.0, &s, &c);
                   st[t] = (float)s; ct[t] = (float)c; }
    for (int i = t; i < 1664; i += 256) {
        int r = i / 13, k = i - r*13;
        size_t si = ((size_t)loc*128 + r)*65 + kb + k;
        zr[r][k] = rre[si];
        zi[r][k] = rim[si];
    }
    __syncthreads();
    for (int i = t; i < 1664; i += 256) {
        int kx = i % 13, rm = i / 13;
        int r0 = rm >> 4, m = rm & 15;
        int step = (m << 3) & 127;
        float gre = 0.f, gim = 0.f;
        int idx = 0;
        for (int r1 = 0; r1 < 16; r1++) {
            float cc = ct[idx], sn = st[idx];
            float a = zr[(r1 << 3) + r0][kx], b = zi[(r1 << 3) + r0][kx];
            gre += a*cc + b*sn;
            gim += b*cc - a*sn;
            idx = (idx + step) & 127;
        }
        gr[r0][m][kx] = gre;
        gi[r0][m][kx] = gim;
    }
    __syncthreads();
    int lb = gp / 768; int chn = gp - lb*768;
    int T = chn >> 8;  int c = chn & 255;
    float* aD = spec + (size_t)(2*T)   * slotStride + ((size_t)(lb*256 + c))*8320;
    float* pD = spec + (size_t)(2*T+1) * slotStride + ((size_t)(lb*256 + c))*8320;
    for (int i = t; i < 1664; i += 256) {
        int kx = i % 13, k1 = i / 13;
        int m = k1 & 15;
        float re = 0.f, im = 0.f;
        int idx = 0;
        for (int r0 = 0; r0 < 8; r0++) {
            float cc = ct[idx], sn = st[idx];
            float a = gr[r0][m][kx], b = gi[r0][m][kx];
            re += a*cc + b*sn;
            im += b*cc - a*sn;
            idx = (idx + k1) & 127;
        }
        int kxv = kb + kx;
        // Self-conjugate rfft2 bins: im structurally zero; pocketfft gives
        // exact +0.0 -> angle in {0,+pi}. Force +0.0 so atan2 never flips
        // to -pi (decorrelates the winner-take-all phase attention).
        if ((k1 == 0 || k1 == 64) && (kxv == 0 || kxv == 64)) im = 0.f;
        int oi = k1*65 + kxv;
        aD[oi] = sqrtf(re*re + im*im);
        pD[oi] = atan2f(im, re);
    }
}

// ---------------- Attention: split-K partial sims (fp32, float4 LDS) -------
__global__ __launch_bounds__(256) void attn_sim_kernel(
    const float* __restrict__ qA, const float* __restrict__ kA,
    float* __restrict__ simpart)
{
    int sp = blockIdx.x;           // 0..15
    int bh = blockIdx.y;           // lb*8 + h
    int lb = bh >> 3, h = bh & 7;
    int t = threadIdx.x;
    __shared__ float qs[32][132], ks[32][132];
    const float* qb = qA + ((size_t)(lb*256 + h*32)) * 8320;
    const float* kb = kA + ((size_t)(lb*256 + h*32)) * 8320;
    float acc[4] = {0.f, 0.f, 0.f, 0.f};
    int j0 = t >> 5;
    int kq = t & 31;
    for (int sub = 0; sub < 4; sub++) {
        int n0 = sp*520 + sub*130;
        __syncthreads();
        for (int i = t; i < 4160; i += 256) {
            int j = i / 130, nn = i - j*130;
            qs[j][nn] = qb[(size_t)j*8320 + n0 + nn];
            ks[j][nn] = kb[(size_t)j*8320 + n0 + nn];
        }
        __syncthreads();
        for (int nn = 0; nn < 128; nn += 4) {
            float4 kv = *(const float4*)&ks[kq][nn];
            #pragma unroll
            for (int e = 0; e < 4; e++) {
                float4 qv = *(const float4*)&qs[j0 + e*8][nn];
                acc[e] += qv.x*kv.x + qv.y*kv.y + qv.z*kv.z + qv.w*kv.w;
            }
        }
        {
            float2 kv = *(const float2*)&ks[kq][128];
            #pragma unroll
            for (int e = 0; e < 4; e++) {
                float2 qv = *(const float2*)&qs[j0 + e*8][128];
                acc[e] += qv.x*kv.x + qv.y*kv.y;
            }
        }
    }
    float* dst = simpart + ((size_t)bh*16 + sp) * 1024;
    dst[t]       = acc[0];
    dst[t + 256] = acc[1];
    dst[t + 512] = acc[2];
    dst[t + 768] = acc[3];
}

// ---------------- Attention: reduce + softmax + PV (fp32) ------------------
__global__ __launch_bounds__(256) void attn_out_kernel(
    const float* __restrict__ simpart, const float* __restrict__ vA,
    float* __restrict__ outA)
{
    int nb = blockIdx.x << 8;
    int bh = blockIdx.y;
    int lb = bh >> 3, h = bh & 7;
    int t = threadIdx.x;
    __shared__ float sim[32][32];
    for (int e = t; e < 1024; e += 256) {
        float s = 0.f;
        const float* pp = simpart + (size_t)bh*16384 + e;
        #pragma unroll
        for (int sp = 0; sp < 16; sp++) s += pp[sp*1024];
        sim[e >> 5][e & 31] = s * ATTN_SCALE;
    }
    __syncthreads();
    if (t < 32) {
        float m = -1e30f;
        for (int k = 0; k < 32; k++) m = fmaxf(m, sim[t][k]);
        float s = 0.f;
        for (int k = 0; k < 32; k++) s += expf(sim[t][k] - m);
        float inv = 1.f / s;
        for (int k = 0; k < 32; k++) sim[t][k] = expf(sim[t][k] - m) * inv;
    }
    __syncthreads();
    int n = nb + t;
    if (n >= 8320) return;
    const float* vb = vA + ((size_t)(lb*256 + h*32)) * 8320 + n;
    float vv[32];
    #pragma unroll
    for (int k = 0; k < 32; k++) vv[k] = vb[(size_t)k * 8320];
    float* ob = outA + ((size_t)(lb*256 + h*32)) * 8320 + n;
    for (int j = 0; j < 32; j++) {
        float o = 0.f;
        #pragma unroll
        for (int k = 0; k < 32; k++) o += sim[j][k] * vv[k];
        ob[(size_t)j * 8320] = o;
    }
}

// ---------------- iFFT stage 1: fp16x2 MFMA vs constant M table ------------
__global__ __launch_bounds__(256) void ifftcol_mfma_kernel(
    const float* __restrict__ ampo, const float* __restrict__ pho,
    const _Float16* __restrict__ mih, const _Float16* __restrict__ mil,
    float* __restrict__ tre, float* __restrict__ tim)
{
    int plane = blockIdx.x;
    int t = threadIdx.x;
    int lane = t & 63;
    int wave = t >> 6;
    int wm = wave << 6;
    int lr = lane & 15;
    int kg = (lane >> 4) << 3;

    __shared__ _Float16 Bh[80][72], Bl[80][72];

    const float* ab = ampo + (size_t)plane * 8320;
    const float* pb = pho  + (size_t)plane * 8320;

    f32x4 acc[4][5];
    #pragma unroll
    for (int i = 0; i < 4; i++)
        #pragma unroll
        for (int j = 0; j < 5; j++) acc[i][j] = (f32x4){0.f, 0.f, 0.f, 0.f};

    for (int kc = 0; kc < 4; kc++) {
        __syncthreads();
        for (int i = t; i < 2080; i += 256) {
            int k1l = i / 65, kx = i - k1l*65;
            int k1 = (kc << 5) + k1l;
            float a = ab[k1*65 + kx];
            float p = pb[k1*65 + kx];
            float sp, cp; sincosf(p, &sp, &cp);
            float zr = a * cp, zi = a * sp;
            _Float16 hr = (_Float16)zr, hi = (_Float16)zi;
            unsigned uh = (unsigned)h_bits(hr) | ((unsigned)h_bits(hi) << 16);
            unsigned ul = (unsigned)h_bits((_Float16)(zr - (float)hr))
                        | ((unsigned)h_bits((_Float16)(zi - (float)hi)) << 16);
            *(unsigned*)&Bh[kx][k1l << 1] = uh;
            *(unsigned*)&Bl[kx][k1l << 1] = ul;
        }
        __syncthreads();
        #pragma unroll
        for (int ks = 0; ks < 2; ks++) {
            int kq = (ks << 5) + kg;
            int kgl = (kc << 6) + kq;
            half8v ah[4], al[4], bh[5], bl[5];
            #pragma unroll
            for (int i = 0; i < 4; i++) {
                int row = wm + i*16 + lr;
                ah[i] = *(const half8v*)&mih[(size_t)row * 256 + kgl];
                al[i] = *(const half8v*)&mil[(size_t)row * 256 + kgl];
            }
            #pragma unroll
            for (int j = 0; j < 5; j++) {
                int col = j*16 + lr;
                bh[j] = *(const half8v*)&Bh[col][kq];
                bl[j] = *(const half8v*)&Bl[col][kq];
            }
            #pragma unroll
            for (int i = 0; i < 4; i++)
                #pragma unroll
                for (int j = 0; j < 5; j++) {
                    acc[i][j] = __builtin_amdgcn_mfma_f32_16x16x32_f16(
                        ah[i], bh[j], acc[i][j], 0, 0, 0);
                    acc[i][j] = __builtin_amdgcn_mfma_f32_16x16x32_f16(
                        al[i], bh[j], acc[i][j], 0, 0, 0);
                    acc[i][j] = __builtin_amdgcn_mfma_f32_16x16x32_f16(
                        ah[i], bl[j], acc[i][j], 0, 0, 0);
                }
        }
    }

    int mr = (lane >> 4) << 2;
    #pragma unroll
    for (int i = 0; i < 4; i++) {
        #pragma unroll
        for (int j = 0; j < 5; j++) {
            int col = j*16 + lr;
            if (col < 65) {
                #pragma unroll
                for (int r = 0; r < 4; r++) {
                    int row = wm + i*16 + mr + r;
                    if (row < 128)
                        tre[((size_t)plane*128 + row)*65 + col] = acc[i][j][r];
                    else
                        tim[((size_t)plane*128 + (row - 128))*65 + col] = acc[i][j][r];
                }
            }
        }
    }
}

// ---------------- iFFT stage 2: Hermitian rows, output-folded, 4-row -------
__global__ __launch_bounds__(256) void ifft_row_kernel(
    const float* __restrict__ tre, const float* __restrict__ tim,
    float* __restrict__ spat)
{
    int rc    = blockIdx.x;        // 0..7
    int plane = blockIdx.y;
    int t     = threadIdx.x;
    __shared__ float tr[16][66], ti[16][66];
    __shared__ float ct[128], st[128];
    if (t < 128) { double s, c; sincos(TWO_PI_D * t / 128.0, &s, &c);
                   st[t] = (float)s; ct[t] = (float)c; }
    for (int i = t; i < 1040; i += 256) {
        int r = i / 65, k = i - r*65;
        size_t si = ((size_t)plane*128 + rc*16 + r)*65 + k;
        float sc = (k >= 1 && k < 64) ? 2.f : 1.f;
        tr[r][k] = tre[si] * sc;
        ti[r][k] = tim[si] * sc;
    }
    __syncthreads();
    for (int oo = t; oo < 260; oo += 256) {
        int x = oo % 65, rq = oo / 65;
        int r0i = rq << 2;
        float C0 = tr[r0i+0][0], C1 = tr[r0i+1][0], C2 = tr[r0i+2][0], C3 = tr[r0i+3][0];
        float S0 = 0.f, S1 = 0.f, S2 = 0.f, S3 = 0.f;
        int m = x;
        for (int k = 1; k <= 64; k++) {
            float cc = ct[m], sn = st[m];
            C0 += tr[r0i+0][k]*cc; S0 += ti[r0i+0][k]*sn;
            C1 += tr[r0i+1][k]*cc; S1 += ti[r0i+1][k]*sn;
            C2 += tr[r0i+2][k]*cc; S2 += ti[r0i+2][k]*sn;
            C3 += tr[r0i+3][k]*cc; S3 += ti[r0i+3][k]*sn;
            m = (m + x) & 127;
        }
        size_t ob = ((size_t)plane << 14) + ((rc*16 + r0i) << 7);
        spat[ob + x]       = (C0 - S0)*0.0078125f;
        spat[ob + 128 + x] = (C1 - S1)*0.0078125f;
        spat[ob + 256 + x] = (C2 - S2)*0.0078125f;
        spat[ob + 384 + x] = (C3 - S3)*0.0078125f;
        if (x >= 1 && x <= 63) {
            int xm = 128 - x;
            spat[ob + xm]       = (C0 + S0)*0.0078125f;
            spat[ob + 128 + xm] = (C1 + S1)*0.0078125f;
            spat[ob + 256 + xm] = (C2 + S2)*0.0078125f;
            spat[ob + 384 + xm] = (C3 + S3)*0.0078125f;
        }
    }
}

// ---------------- weight pre-transform: fp32 [Co][Ci][R][R] -> bf16 [RR][Co][Ci]
__global__ __launch_bounds__(256) void wcvt_kernel(
    const float* __restrict__ w, short* __restrict__ wbf,
    int Cout, int Cin, int RR)
{
    int i = blockIdx.x * 256 + threadIdx.x;
    int total = Cout * Cin * RR;
    if (i >= total) return;
    int rr = i % RR;
    int ci = (i / RR) % Cin;
    int co = i / (RR * Cin);
    wbf[((size_t)rr * Cout + co) * Cin + ci] = f2bf(w[i]);
}

// ---------------- bf16 MFMA conv v2 (ao: fp32 in, LDS staged) --------------
__global__ __launch_bounds__(256) void convmf2_kernel(
    const float* __restrict__ in, const short* __restrict__ wbf,
    const float* __restrict__ bias, const float* __restrict__ res,
    float* __restrict__ out, short* __restrict__ out_t,
    int Cin, int Cout, int act, int in_b0, int res_b0, int out_b0)
{
    int y      = blockIdx.x;
    int coBase = blockIdx.y << 7;
    int lb = blockIdx.z;
    int t = threadIdx.x;
    int lane = t & 63;
    int wave = t >> 6;
    int wm = (wave >> 1) << 6;
    int wn = (wave & 1) << 6;

    __shared__ short As[128][40];
    __shared__ short Bs[128][40];

    f32x4 acc[4][4];
    #pragma unroll
    for (int i = 0; i < 4; i++)
        #pragma unroll
        for (int j = 0; j < 4; j++) acc[i][j] = (f32x4){0.f, 0.f, 0.f, 0.f};

    const size_t inb = ((size_t)(in_b0 + lb) * Cin) << 14;
    int lr = lane & 15;
    int kg = (lane >> 4) << 3;

    const float* inrow = in + inb + (y << 7);
    const short* wslice = wbf + (size_t)coBase * Cin;
    for (int ci0 = 0; ci0 < Cin; ci0 += 32) {
        __syncthreads();
        #pragma unroll
        for (int u = 0; u < 2; u++) {
            int ii = t + (u << 8);
            int co = ii >> 2, cg = ii & 3;
            *(short8*)&As[co][cg << 3] =
                *(const short8*)&wslice[(size_t)co * Cin + ci0 + (cg << 3)];
        }
        for (int i = t; i < 2048; i += 256) {
            int px = i & 127, chp = i >> 7;
            int ci = ci0 + (chp << 1);
            float v0 = inrow[((size_t)ci << 14) + px];
            float v1 = inrow[((size_t)(ci + 1) << 14) + px];
            unsigned u2 = (unsigned)(unsigned short)f2bf(v0)
                        | ((unsigned)(unsigned short)f2bf(v1) << 16);
            *(unsigned*)&Bs[px][chp << 1] = u2;
        }
        __syncthreads();
        short8 af[4], bf[4];
        #pragma unroll
        for (int i = 0; i < 4; i++)
            af[i] = *(const short8*)&As[wm + i*16 + lr][kg];
        #pragma unroll
        for (int j = 0; j < 4; j++)
            bf[j] = *(const short8*)&Bs[wn + j*16 + lr][kg];
        #pragma unroll
        for (int i = 0; i < 4; i++)
            #pragma unroll
            for (int j = 0; j < 4; j++)
                acc[i][j] = __builtin_amdgcn_mfma_f32_16x16x32_bf16(
                    af[i], bf[j], acc[i][j], 0, 0, 0);
    }

    int pBase = y << 7;
    int mr = (lane >> 4) << 2;
    #pragma unroll
    for (int i = 0; i < 4; i++) {
        int co0 = coBase + wm + i*16 + mr;
        #pragma unroll
        for (int j = 0; j < 4; j++) {
            int px = pBase + wn + j*16 + lr;
            float v[4];
            #pragma unroll
            for (int r = 0; r < 4; r++) {
                float vv = acc[i][j][r] + (bias ? bias[co0 + r] : 0.f);
                if (act == 1) vv = vv / (1.f + expf(-vv));
                if (res) vv += res[(((size_t)(res_b0 + lb) * Cout + co0 + r) << 14) + px];
                v[r] = vv;
            }
            if (out) {
                #pragma unroll
                for (int r = 0; r < 4; r++)
                    out[(((size_t)(out_b0 + lb) * Cout + co0 + r) << 14) + px] = v[r];
            }
            if (out_t) {
                short4v s4 = { f2bf(v[0]), f2bf(v[1]), f2bf(v[2]), f2bf(v[3]) };
                *(short4v*)&out_t[((size_t)(lb*16384 + px)) * Cout + co0] = s4;
            }
        }
    }
}

// ---------------- bf16 MFMA conv v3: direct-load, bf16T activations --------
// ci0 loop fully unrolled: per-iteration offsets (<=448B) fold into the
// 13-bit global_load immediate; loads pipeline across MFMA clusters.
template<int R>
__global__ __launch_bounds__(256) void convmf3_kernel(
    const short* __restrict__ in_t, const short* __restrict__ wbf,
    const float* __restrict__ bias, const float* __restrict__ res,
    float* __restrict__ out, short* __restrict__ out_t,
    int Cin, int Cout, int act, int res_b0, int out_b0)
{
    int y      = blockIdx.x;
    int coBase = blockIdx.y << 7;
    int lb = blockIdx.z;
    int t = threadIdx.x;
    int lane = t & 63;
    int wave = t >> 6;
    int wm = (wave >> 1) << 6;
    int wn = (wave & 1) << 6;
    int lr = lane & 15;
    int kg = (lane >> 4) << 3;

    f32x4 acc[4][4];
    #pragma unroll
    for (int i = 0; i < 4; i++)
        #pragma unroll
        for (int j = 0; j < 4; j++) acc[i][j] = (f32x4){0.f, 0.f, 0.f, 0.f};

    const short* inb = in_t + (((size_t)lb << 14)) * Cin;
    const short8 zero8 = {0,0,0,0,0,0,0,0};

    for (int rr = 0; rr < R*R; rr++) {
        int dy = (R == 3) ? (rr / 3) : 0;
        int dx = (R == 3) ? (rr - dy*3) : 0;
        int yy = (R == 3) ? (y + dy - 1) : y;
        if (R == 3 && (yy < 0 || yy > 127)) continue;
        // hoisted per-lane row bases (constant within the ci0 loop)
        const short* wrow[4];
        #pragma unroll
        for (int i = 0; i < 4; i++)
            wrow[i] = wbf + ((size_t)rr * Cout + coBase) * Cin
                    + (size_t)(wm + i*16 + lr) * Cin + kg;
        const short* brow_base = inb + ((size_t)(yy << 7)) * Cin;
        const short* brow[4];
        bool bvalid[4];
        #pragma unroll
        for (int j = 0; j < 4; j++) {
            int pxl = wn + j*16 + lr;
            int xx = (R == 3) ? (pxl + dx - 1) : pxl;
            bvalid[j] = !(R == 3 && (xx < 0 || xx > 127));
            brow[j] = brow_base + (size_t)(bvalid[j] ? xx : 0) * Cin + kg;
        }
        #pragma unroll
        for (int ci0 = 0; ci0 < 512; ci0 += 32) {
            if (ci0 >= Cin) break;
            short8 af[4], bf[4];
            #pragma unroll
            for (int i = 0; i < 4; i++)
                af[i] = *(const short8*)&wrow[i][ci0];
            #pragma unroll
            for (int j = 0; j < 4; j++)
                bf[j] = bvalid[j] ? *(const short8*)&brow[j][ci0] : zero8;
            #pragma unroll
            for (int i = 0; i < 4; i++)
                #pragma unroll
                for (int j = 0; j < 4; j++)
                    acc[i][j] = __builtin_amdgcn_mfma_f32_16x16x32_bf16(
                        af[i], bf[j], acc[i][j], 0, 0, 0);
        }
    }

    int pBase = y << 7;
    int mr = (lane >> 4) << 2;
    #pragma unroll
    for (int i = 0; i < 4; i++) {
        int co0 = coBase + wm + i*16 + mr;
        #pragma unroll
        for (int j = 0; j < 4; j++) {
            int px = pBase + wn + j*16 + lr;
            float v[4];
            #pragma unroll
            for (int r = 0; r < 4; r++) {
                float vv = acc[i][j][r] + (bias ? bias[co0 + r] : 0.f);
                if (act == 1) vv = vv / (1.f + expf(-vv));
                if (res) vv += res[(((size_t)(res_b0 + lb) * Cout + co0 + r) << 14) + px];
                v[r] = vv;
            }
            if (out) {
                #pragma unroll
                for (int r = 0; r < 4; r++)
                    out[(((size_t)(out_b0 + lb) * Cout + co0 + r) << 14) + px] = v[r];
            }
            if (out_t) {
                short4v s4 = { f2bf(v[0]), f2bf(v[1]), f2bf(v[2]), f2bf(v[3]) };
                *(short4v*)&out_t[((size_t)(lb*16384 + px)) * Cout + co0] = s4;
            }
        }
    }
}

// ---------------------------------------------------------------------------
extern "C" void kernel_launch(void* const* d_in, const int* in_sizes, int n_in,
                              void* d_out, int out_size, void* d_ws, size_t ws_size,
                              hipStream_t stream) {
    (void)in_sizes; (void)n_in; (void)out_size;
    const float* x    = (const float*)d_in[0];
    const float* gn_w = (const float*)d_in[1];
    const float* gn_b = (const float*)d_in[2];
    const float* dw_w = (const float*)d_in[3];
    const float* pw_w = (const float*)d_in[4];
    const float* pw_b = (const float*)d_in[5];
    const float* ao_w = (const float*)d_in[6];
    const float* ao_b = (const float*)d_in[7];
    const float* f1_w = (const float*)d_in[8];
    const float* f2_w = (const float*)d_in[9];
    const float* f3_w = (const float*)d_in[10];
    const float* f3_b = (const float*)d_in[11];
    float* outp = (float*)d_out;

    // per-batch region sizes in floats
    const size_t F_QKV  = 12582912;   // qkv; later abuf/h1t/h2t (bf16T)
    const size_t F_SLOT = 2129920;
    const size_t F_SPEC = 6 * F_SLOT;
    const size_t F_XN   = 4194304;
    const size_t F_E    = 4259840;    // max(dw; rre+rim)
    const size_t F_SIMP = 262144;     // invn / fp32 simpart
    const size_t F_TOT  = F_QKV + F_SPEC + F_XN + F_E + F_SIMP; // 34,078,720
    const size_t F_WB   = 1527808;    // bf16 weights + pw/twiddle/M fp16 hi/lo

    int NB = 0;
    for (int cand : {8, 4, 2, 1}) {
        if (((size_t)cand * F_TOT + F_WB) * 4 <= ws_size) { NB = cand; break; }
    }
    if (NB == 0) return;

    float* wsf  = (float*)d_ws;
    float* qkv  = wsf;
    short* abuf = (short*)wsf;                           // [NB][16384][256]
    short* h1t  = (short*)(wsf + (size_t)NB * 2097152);  // [NB][16384][512]
    short* h2t  = (short*)(wsf + (size_t)NB * 6291456);  // [NB][16384][256]
    float* spec = wsf + (size_t)NB * F_QKV;
    size_t ss   = (size_t)NB * F_SLOT;
    float* tre  = spec + 2*ss;
    float* tim  = spec + 3*ss;
    float* spat = spec + 4*ss;
    float* xn   = spec + 6*ss;
    float* ebuf = xn + (size_t)NB * F_XN;
    float* dw   = ebuf;
    float* rre  = ebuf;
    float* rim  = ebuf + (size_t)NB * 2129920;
    float* simpf = ebuf + (size_t)NB * F_E;
    float* invn  = simpf;
    float* simp  = simpf;
    short* wb    = (short*)(wsf + (size_t)NB * F_TOT);
    short* wb_ao = wb;
    short* wb_f1 = wb + 65536;
    short* wb_f2 = wb + 1245184;
    short* wb_f3 = wb + 2424832;
    _Float16* wb_pw_hi = (_Float16*)(wb + 2490368);
    _Float16* wb_pw_lo = (_Float16*)(wb + 2686976);
    _Float16* wb_tw_hi = (_Float16*)(wb + 2883584);
    _Float16* wb_tw_lo = (_Float16*)(wb + 2904064);
    _Float16* wb_mi_hi = (_Float16*)(wb + 2924544);
    _Float16* wb_mi_lo = (_Float16*)(wb + 2990080);

    wcvt_kernel<<<256,  256, 0, stream>>>(ao_w, wb_ao, 256, 256, 1);
    wcvt_kernel<<<4608, 256, 0, stream>>>(f1_w, wb_f1, 512, 256, 9);
    wcvt_kernel<<<4608, 256, 0, stream>>>(f2_w, wb_f2, 256, 512, 9);
    wcvt_kernel<<<256,  256, 0, stream>>>(f3_w, wb_f3, 256, 256, 1);
    wcvtpw_kernel<<<768, 256, 0, stream>>>(pw_w, wb_pw_hi, wb_pw_lo, 196608);
    twcvt_kernel<<<80, 256, 0, stream>>>(wb_tw_hi, wb_tw_lo);
    micvt_kernel<<<256, 256, 0, stream>>>(wb_mi_hi, wb_mi_lo);

    const int passes = 8 / NB;
    for (int p = 0; p < passes; p++) {
        int b0 = p * NB;
        // 1. GroupNorm -> xn
        groupnorm_kernel<<<NB*32, 256, 0, stream>>>(x, gn_w, gn_b, xn, b0);
        // 2. depthwise 3x3 (LDS halo): xn -> dw
        dwconv_kernel<<<NB*256*64, 256, 0, stream>>>(xn, dw_w, dw);
        // 3. pointwise 256->768 (+bias): fp16x2 split MFMA -> qkv
        convpw_kernel<<<dim3(128, 6, NB), 256, 0, stream>>>(
            dw, wb_pw_hi, wb_pw_lo, pw_b, qkv);
        // 4. inverse L2 norms (applied inside fftrow_mfma)
        l2inv_kernel<<<NB*3*64, 256, 0, stream>>>(qkv, invn);
        // 5. rfft2 -> amp/phase spec slots, 3 chunks of NB*256 planes
        for (int chunk = 0; chunk < 3; chunk++) {
            fftrow_mfma_kernel<<<NB*256, 256, 0, stream>>>(
                qkv, invn, wb_tw_hi, wb_tw_lo, rre, rim, chunk*NB*256);
            fft_col_kernel<<<dim3(5, NB*256), 256, 0, stream>>>(
                rre, rim, spec, chunk*NB*256, ss);
        }
        // 6. channel attention (split-K, fp32)
        attn_sim_kernel<<<dim3(16, NB*8), 256, 0, stream>>>(spec + 0*ss, spec + 2*ss, simp);
        attn_out_kernel<<<dim3(33, NB*8), 256, 0, stream>>>(simp, spec + 4*ss, spec + 0*ss);
        attn_sim_kernel<<<dim3(16, NB*8), 256, 0, stream>>>(spec + 1*ss, spec + 3*ss, simp);
        attn_out_kernel<<<dim3(33, NB*8), 256, 0, stream>>>(simp, spec + 5*ss, spec + 1*ss);
        // 7. irfft2: slots 0,1 -> tre/tim (fp16x2 MFMA) -> spat (VALU rows)
        ifftcol_mfma_kernel<<<NB*256, 256, 0, stream>>>(
            spec + 0*ss, spec + 1*ss, wb_mi_hi, wb_mi_lo, tre, tim);
        ifft_row_kernel<<<dim3(8, NB*256), 256, 0, stream>>>(tre, tim, spat);
        // 8. ao 1x1 (+bias) + xn residual -> d_out fp32 + abuf bf16T
        convmf2_kernel<<<dim3(128, 2, NB), 256, 0, stream>>>(
            spat, wb_ao, ao_b, xn, outp, abuf, 256, 256, 0, 0, 0, b0);
        // 9. f1 3x3 256->512 + SiLU: abuf -> h1t (bf16T only)   [direct-load]
        convmf3_kernel<3><<<dim3(128, 4, NB), 256, 0, stream>>>(
            abuf, wb_f1, nullptr, nullptr, nullptr, h1t, 256, 512, 1, 0, 0);
        // 10. f2 3x3 512->256: h1t -> h2t                        [direct-load]
        convmf3_kernel<3><<<dim3(128, 2, NB), 256, 0, stream>>>(
            h1t, wb_f2, nullptr, nullptr, nullptr, h2t, 512, 256, 0, 0, 0);
        // 11. f3 1x1 (+bias) + attn residual -> d_out fp32       [direct-load]
        convmf3_kernel<1><<<dim3(128, 2, NB), 256, 0, stream>>>(
            h2t, wb_f3, f3_b, outp, outp, nullptr, 256, 256, 0, b0, b0);
    }
}

// Round 20
// 6133.240 us; speedup vs baseline: 5.3993x; 1.0069x over previous
//
#include <hip/hip_runtime.h>
#include <hip/hip_bf16.h>
#include <math.h>

// ---------------------------------------------------------------------------
// FreqCA: B=8, C=256, H=W=128, NHEADS=8, GROUPS=32.
// Round 20: ifft_row -> fp16x2 split MFMA against constant [128 x][192 kk]
// N-table (tr/ti interleaved K, sc_k and 1/128 folded in). Downstream of
// softmax => precision-safe. Everything else identical to round 19.
// Self-conjugate rfft2 bins forced im=+0.0 (pocketfft +pi convention).
// ---------------------------------------------------------------------------

#define TWO_PI_D 6.283185307179586476925286766559
#define ATTN_SCALE 0.17677669529663687f  // 1/sqrt(32)

typedef __attribute__((ext_vector_type(8))) short short8;
typedef __attribute__((ext_vector_type(4))) short short4v;
typedef __attribute__((ext_vector_type(4))) float f32x4;
typedef _Float16 half8v __attribute__((ext_vector_type(8)));

__device__ inline short f2bf(float f) {
    __hip_bfloat16 h = __float2bfloat16(f);
    return *reinterpret_cast<short*>(&h);
}
__device__ inline unsigned short h_bits(_Float16 h) {
    union { _Float16 h; unsigned short u; } c; c.h = h; return c.u;
}

// ---------------- GroupNorm: fp64 stats, fp32 out --------------------------
__global__ __launch_bounds__(256) void groupnorm_kernel(
    const float* __restrict__ x, const float* __restrict__ gw,
    const float* __restrict__ gb, float* __restrict__ out, int b0)
{
    int t = threadIdx.x;
    int lb = blockIdx.x >> 5;
    int g  = blockIdx.x & 31;
    size_t src = ((size_t)(b0 + lb) * 32 + g) * 131072;
    size_t dst = (size_t)blockIdx.x * 131072;
    const float* xp = x + src;
    double s = 0.0, ss = 0.0;
    for (int i = t; i < 131072; i += 256) { double v = xp[i]; s += v; ss += v*v; }
    __shared__ double rs[256], rss[256];
    rs[t] = s; rss[t] = ss;
    __syncthreads();
    for (int k = 128; k > 0; k >>= 1) {
        if (t < k) { rs[t] += rs[t+k]; rss[t] += rss[t+k]; }
        __syncthreads();
    }
    __shared__ float smean, sinv;
    if (t == 0) {
        double mean = rs[0] * (1.0/131072.0);
        double var  = rss[0] * (1.0/131072.0) - mean*mean;
        smean = (float)mean;
        sinv  = (float)(1.0 / sqrt(var + 1e-5));
    }
    __syncthreads();
    float mean = smean, inv = sinv;
    for (int i = t; i < 131072; i += 256) {
        int c = (g << 3) + (i >> 14);
        out[dst + i] = (xp[i] - mean) * inv * gw[c] + gb[c];
    }
}

// ---------------- Depthwise 3x3 fp32, LDS halo -----------------------------
__global__ __launch_bounds__(256) void dwconv_kernel(
    const float* __restrict__ in, const float* __restrict__ w, float* __restrict__ out)
{
    int t = threadIdx.x;
    int bc = blockIdx.x >> 6;
    int ystrip = (blockIdx.x & 63) << 1;
    int c  = bc & 255;
    const float* wp = w + c*9;
    const float* ip = in + ((size_t)bc << 14);
    __shared__ float xs[4][128];
    for (int i = t; i < 512; i += 256) {
        int rr = i >> 7, xx = i & 127;
        int yy = ystrip - 1 + rr;
        xs[rr][xx] = (yy >= 0 && yy < 128) ? ip[(yy << 7) + xx] : 0.f;
    }
    __syncthreads();
    int r0 = t >> 7;
    int x  = t & 127;
    float acc = 0.f;
    #pragma unroll
    for (int dy = 0; dy < 3; dy++) {
        const float* row = xs[r0 + dy];
        #pragma unroll
        for (int dx = 0; dx < 3; dx++) {
            int xx = x + dx - 1;
            if (xx >= 0 && xx <= 127) acc += wp[dy*3+dx] * row[xx];
        }
    }
    out[((size_t)bc << 14) + ((ystrip + r0) << 7) + x] = acc;
}

// ---------------- pw weight split: fp32 [768][256] -> fp16 hi/lo -----------
__global__ __launch_bounds__(256) void wcvtpw_kernel(
    const float* __restrict__ w, _Float16* __restrict__ whi,
    _Float16* __restrict__ wlo, int total)
{
    int i = blockIdx.x * 256 + threadIdx.x;
    if (i >= total) return;
    float v = w[i];
    _Float16 h = (_Float16)v;
    _Float16 l = (_Float16)(v - (float)h);
    whi[i] = h; wlo[i] = l;
}

// ---------------- row-DFT twiddle table: [160 bins][128 w] fp16 hi/lo ------
__global__ __launch_bounds__(256) void twcvt_kernel(
    _Float16* __restrict__ twh, _Float16* __restrict__ twl)
{
    int i = blockIdx.x * 256 + threadIdx.x;
    if (i >= 20480) return;
    int bin = i >> 7, w = i & 127;
    double v = 0.0;
    if (bin < 65) v = cos(TWO_PI_D * ((bin * w) & 127) / 128.0) * 0.0078125;
    else if (bin < 130) v = -sin(TWO_PI_D * (((bin - 65) * w) & 127) / 128.0) * 0.0078125;
    _Float16 h = (_Float16)v;
    twh[i] = h;
    twl[i] = (_Float16)((float)v - (float)h);
}

// ---------------- ifft-col M table: [256 rows][256 zin] fp16 hi/lo ---------
__global__ __launch_bounds__(256) void micvt_kernel(
    _Float16* __restrict__ mih, _Float16* __restrict__ mil)
{
    int i = blockIdx.x * 256 + threadIdx.x;
    if (i >= 65536) return;
    int row = i >> 8, col = i & 255;
    int k1 = col >> 1, u = col & 1;
    int yy = row & 127;
    double ang = TWO_PI_D * ((k1 * yy) & 127) / 128.0;
    double cc = cos(ang), sn = sin(ang);
    double v;
    if (row < 128) v = (u == 0) ? cc : -sn;
    else           v = (u == 0) ? sn :  cc;
    _Float16 h = (_Float16)v;
    mih[i] = h;
    mil[i] = (_Float16)((float)v - (float)h);
}

// ---------------- ifft-row N table: [128 x][192 kk] fp16 hi/lo -------------
// kk = 2k+u, k in [0,64]: u==0 -> cos(2pi kx/128)*sc_k/128, u==1 ->
// -sin(2pi kx/128)*sc_k/128, sc_k = 2 for 1<=k<64 else 1. kk>=130 -> 0.
__global__ __launch_bounds__(256) void nrcvt_kernel(
    _Float16* __restrict__ nrh, _Float16* __restrict__ nrl)
{
    int i = blockIdx.x * 256 + threadIdx.x;
    if (i >= 24576) return;
    int x = i / 192, kk = i - x*192;
    double v = 0.0;
    if (kk < 130) {
        int k = kk >> 1, u = kk & 1;
        double sc = (k >= 1 && k < 64) ? 2.0 : 1.0;
        double ang = TWO_PI_D * ((k * x) & 127) / 128.0;
        v = ((u == 0) ? cos(ang) : -sin(ang)) * sc * 0.0078125;
    }
    _Float16 h = (_Float16)v;
    nrh[i] = h;
    nrl[i] = (_Float16)((float)v - (float)h);
}

// ---------------- pw conv: fp16x2 split MFMA (Cin=256 -> Cout=768) ---------
__global__ __launch_bounds__(256) void convpw_kernel(
    const float* __restrict__ in, const _Float16* __restrict__ whi,
    const _Float16* __restrict__ wlo, const float* __restrict__ bias,
    float* __restrict__ out)
{
    int y      = blockIdx.x;
    int coBase = blockIdx.y << 7;
    int lb     = blockIdx.z;
    int t = threadIdx.x;
    int lane = t & 63;
    int wave = t >> 6;
    int wm = (wave >> 1) << 6;
    int wn = (wave & 1) << 6;
    int lr = lane & 15;
    int kg = (lane >> 4) << 3;

    __shared__ _Float16 Ah[128][40], Al[128][40];
    __shared__ _Float16 Bh[128][40], Bl[128][40];

    f32x4 acc[4][4];
    #pragma unroll
    for (int i = 0; i < 4; i++)
        #pragma unroll
        for (int j = 0; j < 4; j++) acc[i][j] = (f32x4){0.f, 0.f, 0.f, 0.f};

    const float* inrow = in + (((size_t)lb * 256) << 14) + (y << 7);
    for (int ci0 = 0; ci0 < 256; ci0 += 32) {
        __syncthreads();
        #pragma unroll
        for (int u = 0; u < 2; u++) {
            int ii = t + (u << 8);
            int co = ii >> 2, cg = ii & 3;
            *(half8v*)&Ah[co][cg << 3] =
                *(const half8v*)&whi[(size_t)(coBase + co) * 256 + ci0 + (cg << 3)];
            *(half8v*)&Al[co][cg << 3] =
                *(const half8v*)&wlo[(size_t)(coBase + co) * 256 + ci0 + (cg << 3)];
        }
        for (int i = t; i < 2048; i += 256) {
            int px = i & 127, chp = i >> 7;
            int ci = ci0 + (chp << 1);
            float v0 = inrow[((size_t)ci << 14) + px];
            float v1 = inrow[((size_t)(ci + 1) << 14) + px];
            _Float16 h0 = (_Float16)v0, h1 = (_Float16)v1;
            _Float16 l0 = (_Float16)(v0 - (float)h0);
            _Float16 l1 = (_Float16)(v1 - (float)h1);
            unsigned uh = (unsigned)h_bits(h0) | ((unsigned)h_bits(h1) << 16);
            unsigned ul = (unsigned)h_bits(l0) | ((unsigned)h_bits(l1) << 16);
            *(unsigned*)&Bh[px][chp << 1] = uh;
            *(unsigned*)&Bl[px][chp << 1] = ul;
        }
        __syncthreads();
        half8v ah[4], al[4], bh4[4], bl4[4];
        #pragma unroll
        for (int i = 0; i < 4; i++) {
            ah[i] = *(const half8v*)&Ah[wm + i*16 + lr][kg];
            al[i] = *(const half8v*)&Al[wm + i*16 + lr][kg];
        }
        #pragma unroll
        for (int j = 0; j < 4; j++) {
            bh4[j] = *(const half8v*)&Bh[wn + j*16 + lr][kg];
            bl4[j] = *(const half8v*)&Bl[wn + j*16 + lr][kg];
        }
        #pragma unroll
        for (int i = 0; i < 4; i++)
            #pragma unroll
            for (int j = 0; j < 4; j++) {
                acc[i][j] = __builtin_amdgcn_mfma_f32_16x16x32_f16(
                    ah[i], bh4[j], acc[i][j], 0, 0, 0);
                acc[i][j] = __builtin_amdgcn_mfma_f32_16x16x32_f16(
                    ah[i], bl4[j], acc[i][j], 0, 0, 0);
                acc[i][j] = __builtin_amdgcn_mfma_f32_16x16x32_f16(
                    al[i], bh4[j], acc[i][j], 0, 0, 0);
            }
    }

    int pBase = y << 7;
    int mr = (lane >> 4) << 2;
    #pragma unroll
    for (int i = 0; i < 4; i++) {
        int co0 = coBase + wm + i*16 + mr;
        #pragma unroll
        for (int j = 0; j < 4; j++) {
            int px = pBase + wn + j*16 + lr;
            #pragma unroll
            for (int r = 0; r < 4; r++) {
                out[(((size_t)(lb*768 + co0 + r)) << 14) + px] =
                    acc[i][j][r] + bias[co0 + r];
            }
        }
    }
}

// ---------------- inverse L2 norms per pixel (no write-back) ---------------
__global__ __launch_bounds__(256) void l2inv_kernel(
    const float* __restrict__ qkv, float* __restrict__ invn)
{
    int p  = ((blockIdx.x & 63) << 8) + threadIdx.x;
    int bT = blockIdx.x >> 6;          // lb*3 + T
    int lb = bT / 3, T = bT - 3*lb;
    const float* base = qkv + (((size_t)(lb*768 + T*256)) << 14) + p;
    double ss = 0.0;
    for (int c = 0; c < 256; c++) { double v = base[(size_t)c << 14]; ss += v*v; }
    invn[((size_t)bT << 14) + p] = 1.f / fmaxf((float)sqrt(ss), 1e-12f);
}

// ---------------- FFT stage 1: row DFT as fp16x2 MFMA GEMM -----------------
__global__ __launch_bounds__(256) void fftrow_mfma_kernel(
    const float* __restrict__ qkv, const float* __restrict__ invn,
    const _Float16* __restrict__ twh, const _Float16* __restrict__ twl,
    float* __restrict__ rre, float* __restrict__ rim, int chunkBase)
{
    int loc = blockIdx.x;
    int gp  = chunkBase + loc;
    int t = threadIdx.x;
    int lane = t & 63;
    int wave = t >> 6;
    int wm  = (wave >> 1) << 6;
    int wnn = (wave & 1) * 80;
    int lr = lane & 15;
    int kq = (lane >> 4) << 3;

    __shared__ _Float16 Xh[128][68], Xl[128][68];

    int lb = gp / 768, chn = gp - lb*768, T = chn >> 8;
    const float4* src = (const float4*)(qkv + ((size_t)gp << 14));
    const float4* ivp = (const float4*)(invn + (((size_t)(lb*3 + T)) << 14));

    f32x4 acc[4][5];
    #pragma unroll
    for (int i = 0; i < 4; i++)
        #pragma unroll
        for (int j = 0; j < 5; j++) acc[i][j] = (f32x4){0.f, 0.f, 0.f, 0.f};

    for (int half = 0; half < 2; half++) {
        __syncthreads();
        for (int i = t; i < 2048; i += 256) {
            int r = i >> 4, q4 = i & 15;
            int gi = (r << 5) + (half << 4) + q4;
            float4 v = src[gi], w = ivp[gi];
            v.x *= w.x; v.y *= w.y; v.z *= w.z; v.w *= w.w;
            int cl = q4 << 2;
            _Float16 h0 = (_Float16)v.x, h1 = (_Float16)v.y;
            _Float16 h2 = (_Float16)v.z, h3 = (_Float16)v.w;
            Xh[r][cl+0] = h0; Xh[r][cl+1] = h1; Xh[r][cl+2] = h2; Xh[r][cl+3] = h3;
            Xl[r][cl+0] = (_Float16)(v.x - (float)h0);
            Xl[r][cl+1] = (_Float16)(v.y - (float)h1);
            Xl[r][cl+2] = (_Float16)(v.z - (float)h2);
            Xl[r][cl+3] = (_Float16)(v.w - (float)h3);
        }
        __syncthreads();
        #pragma unroll
        for (int ks = 0; ks < 2; ks++) {
            int k0 = (ks << 5) + kq;
            int kg = (half << 6) + k0;
            half8v ah[4], al[4], bh[5], bl[5];
            #pragma unroll
            for (int i = 0; i < 4; i++) {
                ah[i] = *(const half8v*)&Xh[wm + i*16 + lr][k0];
                al[i] = *(const half8v*)&Xl[wm + i*16 + lr][k0];
            }
            #pragma unroll
            for (int j = 0; j < 5; j++) {
                int bin = wnn + j*16 + lr;
                bh[j] = *(const half8v*)&twh[(size_t)bin * 128 + kg];
                bl[j] = *(const half8v*)&twl[(size_t)bin * 128 + kg];
            }
            #pragma unroll
            for (int i = 0; i < 4; i++)
                #pragma unroll
                for (int j = 0; j < 5; j++) {
                    acc[i][j] = __builtin_amdgcn_mfma_f32_16x16x32_f16(
                        ah[i], bh[j], acc[i][j], 0, 0, 0);
                    acc[i][j] = __builtin_amdgcn_mfma_f32_16x16x32_f16(
                        al[i], bh[j], acc[i][j], 0, 0, 0);
                    acc[i][j] = __builtin_amdgcn_mfma_f32_16x16x32_f16(
                        ah[i], bl[j], acc[i][j], 0, 0, 0);
                }
        }
    }

    int mr = (lane >> 4) << 2;
    #pragma unroll
    for (int i = 0; i < 4; i++) {
        #pragma unroll
        for (int j = 0; j < 5; j++) {
            int bin = wnn + j*16 + lr;
            if (bin < 130) {
                float* dst = (bin < 65) ? rre : rim;
                int bb = (bin < 65) ? bin : bin - 65;
                #pragma unroll
                for (int r = 0; r < 4; r++) {
                    int row = wm + i*16 + mr + r;
                    dst[((size_t)loc*128 + row)*65 + bb] = acc[i][j][r];
                }
            }
        }
    }
}

// ---------------- FFT stage 2: radix-16x8 col DFT -> amp/phase -------------
__global__ __launch_bounds__(256) void fft_col_kernel(
    const float* __restrict__ rre, const float* __restrict__ rim,
    float* __restrict__ spec, int chunkBase, size_t slotStride)
{
    int kb  = blockIdx.x * 13;
    int loc = blockIdx.y;
    int gp  = chunkBase + loc;
    int t   = threadIdx.x;
    __shared__ float zr[128][14], zi[128][14];
    __shared__ float gr[8][16][14], gi[8][16][14];
    __shared__ float ct[128], st[128];
    if (t < 128) { double s, c; sincos(TWO_PI_D * t / 128.0, &s, &c);
                   st[t] = (float)s; ct[t] = (float)c; }
    for (int i = t; i < 1664; i += 256) {
        int r = i / 13, k = i - r*13;
        size_t si = ((size_t)loc*128 + r)*65 + kb + k;
        zr[r][k] = rre[si];
        zi[r][k] = rim[si];
    }
    __syncthreads();
    for (int i = t; i < 1664; i += 256) {
        int kx = i % 13, rm = i / 13;
        int r0 = rm >> 4, m = rm & 15;
        int step = (m << 3) & 127;
        float gre = 0.f, gim = 0.f;
        int idx = 0;
        for (int r1 = 0; r1 < 16; r1++) {
            float cc = ct[idx], sn = st[idx];
            float a = zr[(r1 << 3) + r0][kx], b = zi[(r1 << 3) + r0][kx];
            gre += a*cc + b*sn;
            gim += b*cc - a*sn;
            idx = (idx + step) & 127;
        }
        gr[r0][m][kx] = gre;
        gi[r0][m][kx] = gim;
    }
    __syncthreads();
    int lb = gp / 768; int chn = gp - lb*768;
    int T = chn >> 8;  int c = chn & 255;
    float* aD = spec + (size_t)(2*T)   * slotStride + ((size_t)(lb*256 + c))*8320;
    float* pD = spec + (size_t)(2*T+1) * slotStride + ((size_t)(lb*256 + c))*8320;
    for (int i = t; i < 1664; i += 256) {
        int kx = i % 13, k1 = i / 13;
        int m = k1 & 15;
        float re = 0.f, im = 0.f;
        int idx = 0;
        for (int r0 = 0; r0 < 8; r0++) {
            float cc = ct[idx], sn = st[idx];
            float a = gr[r0][m][kx], b = gi[r0][m][kx];
            re += a*cc + b*sn;
            im += b*cc - a*sn;
            idx = (idx + k1) & 127;
        }
        int kxv = kb + kx;
        // Self-conjugate rfft2 bins: im structurally zero; pocketfft gives
        // exact +0.0 -> angle in {0,+pi}. Force +0.0 so atan2 never flips
        // to -pi (decorrelates the winner-take-all phase attention).
        if ((k1 == 0 || k1 == 64) && (kxv == 0 || kxv == 64)) im = 0.f;
        int oi = k1*65 + kxv;
        aD[oi] = sqrtf(re*re + im*im);
        pD[oi] = atan2f(im, re);
    }
}

// ---------------- Attention: split-K partial sims (fp32, float4 LDS) -------
__global__ __launch_bounds__(256) void attn_sim_kernel(
    const float* __restrict__ qA, const float* __restrict__ kA,
    float* __restrict__ simpart)
{
    int sp = blockIdx.x;           // 0..15
    int bh = blockIdx.y;           // lb*8 + h
    int lb = bh >> 3, h = bh & 7;
    int t = threadIdx.x;
    __shared__ float qs[32][132], ks[32][132];
    const float* qb = qA + ((size_t)(lb*256 + h*32)) * 8320;
    const float* kb = kA + ((size_t)(lb*256 + h*32)) * 8320;
    float acc[4] = {0.f, 0.f, 0.f, 0.f};
    int j0 = t >> 5;
    int kq = t & 31;
    for (int sub = 0; sub < 4; sub++) {
        int n0 = sp*520 + sub*130;
        __syncthreads();
        for (int i = t; i < 4160; i += 256) {
            int j = i / 130, nn = i - j*130;
            qs[j][nn] = qb[(size_t)j*8320 + n0 + nn];
            ks[j][nn] = kb[(size_t)j*8320 + n0 + nn];
        }
        __syncthreads();
        for (int nn = 0; nn < 128; nn += 4) {
            float4 kv = *(const float4*)&ks[kq][nn];
            #pragma unroll
            for (int e = 0; e < 4; e++) {
                float4 qv = *(const float4*)&qs[j0 + e*8][nn];
                acc[e] += qv.x*kv.x + qv.y*kv.y + qv.z*kv.z + qv.w*kv.w;
            }
        }
        {
            float2 kv = *(const float2*)&ks[kq][128];
            #pragma unroll
            for (int e = 0; e < 4; e++) {
                float2 qv = *(const float2*)&qs[j0 + e*8][128];
                acc[e] += qv.x*kv.x + qv.y*kv.y;
            }
        }
    }
    float* dst = simpart + ((size_t)bh*16 + sp) * 1024;
    dst[t]       = acc[0];
    dst[t + 256] = acc[1];
    dst[t + 512] = acc[2];
    dst[t + 768] = acc[3];
}

// ---------------- Attention: reduce + softmax + PV (fp32) ------------------
__global__ __launch_bounds__(256) void attn_out_kernel(
    const float* __restrict__ simpart, const float* __restrict__ vA,
    float* __restrict__ outA)
{
    int nb = blockIdx.x << 8;
    int bh = blockIdx.y;
    int lb = bh >> 3, h = bh & 7;
    int t = threadIdx.x;
    __shared__ float sim[32][32];
    for (int e = t; e < 1024; e += 256) {
        float s = 0.f;
        const float* pp = simpart + (size_t)bh*16384 + e;
        #pragma unroll
        for (int sp = 0; sp < 16; sp++) s += pp[sp*1024];
        sim[e >> 5][e & 31] = s * ATTN_SCALE;
    }
    __syncthreads();
    if (t < 32) {
        float m = -1e30f;
        for (int k = 0; k < 32; k++) m = fmaxf(m, sim[t][k]);
        float s = 0.f;
        for (int k = 0; k < 32; k++) s += expf(sim[t][k] - m);
        float inv = 1.f / s;
        for (int k = 0; k < 32; k++) sim[t][k] = expf(sim[t][k] - m) * inv;
    }
    __syncthreads();
    int n = nb + t;
    if (n >= 8320) return;
    const float* vb = vA + ((size_t)(lb*256 + h*32)) * 8320 + n;
    float vv[32];
    #pragma unroll
    for (int k = 0; k < 32; k++) vv[k] = vb[(size_t)k * 8320];
    float* ob = outA + ((size_t)(lb*256 + h*32)) * 8320 + n;
    for (int j = 0; j < 32; j++) {
        float o = 0.f;
        #pragma unroll
        for (int k = 0; k < 32; k++) o += sim[j][k] * vv[k];
        ob[(size_t)j * 8320] = o;
    }
}

// ---------------- iFFT stage 1: fp16x2 MFMA vs constant M table ------------
__global__ __launch_bounds__(256) void ifftcol_mfma_kernel(
    const float* __restrict__ ampo, const float* __restrict__ pho,
    const _Float16* __restrict__ mih, const _Float16* __restrict__ mil,
    float* __restrict__ tre, float* __restrict__ tim)
{
    int plane = blockIdx.x;
    int t = threadIdx.x;
    int lane = t & 63;
    int wave = t >> 6;
    int wm = wave << 6;
    int lr = lane & 15;
    int kg = (lane >> 4) << 3;

    __shared__ _Float16 Bh[80][72], Bl[80][72];

    const float* ab = ampo + (size_t)plane * 8320;
    const float* pb = pho  + (size_t)plane * 8320;

    f32x4 acc[4][5];
    #pragma unroll
    for (int i = 0; i < 4; i++)
        #pragma unroll
        for (int j = 0; j < 5; j++) acc[i][j] = (f32x4){0.f, 0.f, 0.f, 0.f};

    for (int kc = 0; kc < 4; kc++) {
        __syncthreads();
        for (int i = t; i < 2080; i += 256) {
            int k1l = i / 65, kx = i - k1l*65;
            int k1 = (kc << 5) + k1l;
            float a = ab[k1*65 + kx];
            float p = pb[k1*65 + kx];
            float sp, cp; sincosf(p, &sp, &cp);
            float zr = a * cp, zi = a * sp;
            _Float16 hr = (_Float16)zr, hi = (_Float16)zi;
            unsigned uh = (unsigned)h_bits(hr) | ((unsigned)h_bits(hi) << 16);
            unsigned ul = (unsigned)h_bits((_Float16)(zr - (float)hr))
                        | ((unsigned)h_bits((_Float16)(zi - (float)hi)) << 16);
            *(unsigned*)&Bh[kx][k1l << 1] = uh;
            *(unsigned*)&Bl[kx][k1l << 1] = ul;
        }
        __syncthreads();
        #pragma unroll
        for (int ks = 0; ks < 2; ks++) {
            int kq = (ks << 5) + kg;
            int kgl = (kc << 6) + kq;
            half8v ah[4], al[4], bh[5], bl[5];
            #pragma unroll
            for (int i = 0; i < 4; i++) {
                int row = wm + i*16 + lr;
                ah[i] = *(const half8v*)&mih[(size_t)row * 256 + kgl];
                al[i] = *(const half8v*)&mil[(size_t)row * 256 + kgl];
            }
            #pragma unroll
            for (int j = 0; j < 5; j++) {
                int col = j*16 + lr;
                bh[j] = *(const half8v*)&Bh[col][kq];
                bl[j] = *(const half8v*)&Bl[col][kq];
            }
            #pragma unroll
            for (int i = 0; i < 4; i++)
                #pragma unroll
                for (int j = 0; j < 5; j++) {
                    acc[i][j] = __builtin_amdgcn_mfma_f32_16x16x32_f16(
                        ah[i], bh[j], acc[i][j], 0, 0, 0);
                    acc[i][j] = __builtin_amdgcn_mfma_f32_16x16x32_f16(
                        al[i], bh[j], acc[i][j], 0, 0, 0);
                    acc[i][j] = __builtin_amdgcn_mfma_f32_16x16x32_f16(
                        ah[i], bl[j], acc[i][j], 0, 0, 0);
                }
        }
    }

    int mr = (lane >> 4) << 2;
    #pragma unroll
    for (int i = 0; i < 4; i++) {
        #pragma unroll
        for (int j = 0; j < 5; j++) {
            int col = j*16 + lr;
            if (col < 65) {
                #pragma unroll
                for (int r = 0; r < 4; r++) {
                    int row = wm + i*16 + mr + r;
                    if (row < 128)
                        tre[((size_t)plane*128 + row)*65 + col] = acc[i][j][r];
                    else
                        tim[((size_t)plane*128 + (row - 128))*65 + col] = acc[i][j][r];
                }
            }
        }
    }
}

// ---------------- iFFT stage 2: fp16x2 MFMA vs constant N table ------------
// Per plane: spat[r][x] = sum_kk A[r][kk] * N[x][kk], A = interleaved
// [tr(k),ti(k)] (130 kk, padded to 192), N has sc_k and 1/128 folded in.
__global__ __launch_bounds__(256) void ifftrow_mfma_kernel(
    const float* __restrict__ tre, const float* __restrict__ tim,
    const _Float16* __restrict__ nrh, const _Float16* __restrict__ nrl,
    float* __restrict__ spat)
{
    int plane = blockIdx.x;
    int t = threadIdx.x;
    int lane = t & 63;
    int wave = t >> 6;
    int wm = (wave >> 1) << 6;     // r offset: 0 / 64
    int wn = (wave & 1) << 6;      // x offset: 0 / 64
    int lr = lane & 15;
    int kg = (lane >> 4) << 3;

    __shared__ _Float16 Ah[128][72], Al[128][72];

    const float* trb = tre + (size_t)plane * 128 * 65;
    const float* tib = tim + (size_t)plane * 128 * 65;

    f32x4 acc[4][4];
    #pragma unroll
    for (int i = 0; i < 4; i++)
        #pragma unroll
        for (int j = 0; j < 4; j++) acc[i][j] = (f32x4){0.f, 0.f, 0.f, 0.f};

    for (int kc = 0; kc < 3; kc++) {       // kk chunks of 64 (130 used, 192 padded)
        __syncthreads();
        for (int i = t; i < 8192; i += 256) {
            int r = i >> 6, kkl = i & 63;
            int kkg = (kc << 6) + kkl;
            float v = 0.f;
            if (kkg < 130) {
                int k = kkg >> 1;
                v = (kkg & 1) ? tib[r*65 + k] : trb[r*65 + k];
            }
            _Float16 h = (_Float16)v;
            Ah[r][kkl] = h;
            Al[r][kkl] = (_Float16)(v - (float)h);
        }
        __syncthreads();
        #pragma unroll
        for (int ks = 0; ks < 2; ks++) {
            int kq = (ks << 5) + kg;           // local kk in [0,64)
            int kgl = (kc << 6) + kq;          // global kk
            half8v ah[4], al[4], bh[4], bl[4];
            #pragma unroll
            for (int i = 0; i < 4; i++) {
                ah[i] = *(const half8v*)&Ah[wm + i*16 + lr][kq];
                al[i] = *(const half8v*)&Al[wm + i*16 + lr][kq];
            }
            #pragma unroll
            for (int j = 0; j < 4; j++) {
                int x = wn + j*16 + lr;
                bh[j] = *(const half8v*)&nrh[(size_t)x * 192 + kgl];
                bl[j] = *(const half8v*)&nrl[(size_t)x * 192 + kgl];
            }
            #pragma unroll
            for (int i = 0; i < 4; i++)
                #pragma unroll
                for (int j = 0; j < 4; j++) {
                    acc[i][j] = __builtin_amdgcn_mfma_f32_16x16x32_f16(
                        ah[i], bh[j], acc[i][j], 0, 0, 0);
                    acc[i][j] = __builtin_amdgcn_mfma_f32_16x16x32_f16(
                        al[i], bh[j], acc[i][j], 0, 0, 0);
                    acc[i][j] = __builtin_amdgcn_mfma_f32_16x16x32_f16(
                        ah[i], bl[j], acc[i][j], 0, 0, 0);
                }
        }
    }

    int mr = (lane >> 4) << 2;
    size_t pbase = (size_t)plane << 14;
    #pragma unroll
    for (int i = 0; i < 4; i++) {
        #pragma unroll
        for (int j = 0; j < 4; j++) {
            int x = wn + j*16 + lr;
            #pragma unroll
            for (int r = 0; r < 4; r++) {
                int row = wm + i*16 + mr + r;
                spat[pbase + (row << 7) + x] = acc[i][j][r];
            }
        }
    }
}

// ---------------- weight pre-transform: fp32 [Co][Ci][R][R] -> bf16 [RR][Co][Ci]
__global__ __launch_bounds__(256) void wcvt_kernel(
    const float* __restrict__ w, short* __restrict__ wbf,
    int Cout, int Cin, int RR)
{
    int i = blockIdx.x * 256 + threadIdx.x;
    int total = Cout * Cin * RR;
    if (i >= total) return;
    int rr = i % RR;
    int ci = (i / RR) % Cin;
    int co = i / (RR * Cin);
    wbf[((size_t)rr * Cout + co) * Cin + ci] = f2bf(w[i]);
}

// ---------------- bf16 MFMA conv v2 (ao: fp32 in, LDS staged) --------------
__global__ __launch_bounds__(256) void convmf2_kernel(
    const float* __restrict__ in, const short* __restrict__ wbf,
    const float* __restrict__ bias, const float* __restrict__ res,
    float* __restrict__ out, short* __restrict__ out_t,
    int Cin, int Cout, int act, int in_b0, int res_b0, int out_b0)
{
    int y      = blockIdx.x;
    int coBase = blockIdx.y << 7;
    int lb = blockIdx.z;
    int t = threadIdx.x;
    int lane = t & 63;
    int wave = t >> 6;
    int wm = (wave >> 1) << 6;
    int wn = (wave & 1) << 6;

    __shared__ short As[128][40];
    __shared__ short Bs[128][40];

    f32x4 acc[4][4];
    #pragma unroll
    for (int i = 0; i < 4; i++)
        #pragma unroll
        for (int j = 0; j < 4; j++) acc[i][j] = (f32x4){0.f, 0.f, 0.f, 0.f};

    const size_t inb = ((size_t)(in_b0 + lb) * Cin) << 14;
    int lr = lane & 15;
    int kg = (lane >> 4) << 3;

    const float* inrow = in + inb + (y << 7);
    const short* wslice = wbf + (size_t)coBase * Cin;
    for (int ci0 = 0; ci0 < Cin; ci0 += 32) {
        __syncthreads();
        #pragma unroll
        for (int u = 0; u < 2; u++) {
            int ii = t + (u << 8);
            int co = ii >> 2, cg = ii & 3;
            *(short8*)&As[co][cg << 3] =
                *(const short8*)&wslice[(size_t)co * Cin + ci0 + (cg << 3)];
        }
        for (int i = t; i < 2048; i += 256) {
            int px = i & 127, chp = i >> 7;
            int ci = ci0 + (chp << 1);
            float v0 = inrow[((size_t)ci << 14) + px];
            float v1 = inrow[((size_t)(ci + 1) << 14) + px];
            unsigned u2 = (unsigned)(unsigned short)f2bf(v0)
                        | ((unsigned)(unsigned short)f2bf(v1) << 16);
            *(unsigned*)&Bs[px][chp << 1] = u2;
        }
        __syncthreads();
        short8 af[4], bf[4];
        #pragma unroll
        for (int i = 0; i < 4; i++)
            af[i] = *(const short8*)&As[wm + i*16 + lr][kg];
        #pragma unroll
        for (int j = 0; j < 4; j++)
            bf[j] = *(const short8*)&Bs[wn + j*16 + lr][kg];
        #pragma unroll
        for (int i = 0; i < 4; i++)
            #pragma unroll
            for (int j = 0; j < 4; j++)
                acc[i][j] = __builtin_amdgcn_mfma_f32_16x16x32_bf16(
                    af[i], bf[j], acc[i][j], 0, 0, 0);
    }

    int pBase = y << 7;
    int mr = (lane >> 4) << 2;
    #pragma unroll
    for (int i = 0; i < 4; i++) {
        int co0 = coBase + wm + i*16 + mr;
        #pragma unroll
        for (int j = 0; j < 4; j++) {
            int px = pBase + wn + j*16 + lr;
            float v[4];
            #pragma unroll
            for (int r = 0; r < 4; r++) {
                float vv = acc[i][j][r] + (bias ? bias[co0 + r] : 0.f);
                if (act == 1) vv = vv / (1.f + expf(-vv));
                if (res) vv += res[(((size_t)(res_b0 + lb) * Cout + co0 + r) << 14) + px];
                v[r] = vv;
            }
            if (out) {
                #pragma unroll
                for (int r = 0; r < 4; r++)
                    out[(((size_t)(out_b0 + lb) * Cout + co0 + r) << 14) + px] = v[r];
            }
            if (out_t) {
                short4v s4 = { f2bf(v[0]), f2bf(v[1]), f2bf(v[2]), f2bf(v[3]) };
                *(short4v*)&out_t[((size_t)(lb*16384 + px)) * Cout + co0] = s4;
            }
        }
    }
}

// ---------------- bf16 MFMA conv v3: direct-load, bf16T activations --------
template<int R>
__global__ __launch_bounds__(256) void convmf3_kernel(
    const short* __restrict__ in_t, const short* __restrict__ wbf,
    const float* __restrict__ bias, const float* __restrict__ res,
    float* __restrict__ out, short* __restrict__ out_t,
    int Cin, int Cout, int act, int res_b0, int out_b0)
{
    int y      = blockIdx.x;
    int coBase = blockIdx.y << 7;
    int lb = blockIdx.z;
    int t = threadIdx.x;
    int lane = t & 63;
    int wave = t >> 6;
    int wm = (wave >> 1) << 6;
    int wn = (wave & 1) << 6;
    int lr = lane & 15;
    int kg = (lane >> 4) << 3;

    f32x4 acc[4][4];
    #pragma unroll
    for (int i = 0; i < 4; i++)
        #pragma unroll
        for (int j = 0; j < 4; j++) acc[i][j] = (f32x4){0.f, 0.f, 0.f, 0.f};

    const short* inb = in_t + (((size_t)lb << 14)) * Cin;
    const short8 zero8 = {0,0,0,0,0,0,0,0};

    for (int rr = 0; rr < R*R; rr++) {
        int dy = (R == 3) ? (rr / 3) : 0;
        int dx = (R == 3) ? (rr - dy*3) : 0;
        int yy = (R == 3) ? (y + dy - 1) : y;
        if (R == 3 && (yy < 0 || yy > 127)) continue;
        const short* wrow[4];
        #pragma unroll
        for (int i = 0; i < 4; i++)
            wrow[i] = wbf + ((size_t)rr * Cout + coBase) * Cin
                    + (size_t)(wm + i*16 + lr) * Cin + kg;
        const short* brow_base = inb + ((size_t)(yy << 7)) * Cin;
        const short* brow[4];
        bool bvalid[4];
        #pragma unroll
        for (int j = 0; j < 4; j++) {
            int pxl = wn + j*16 + lr;
            int xx = (R == 3) ? (pxl + dx - 1) : pxl;
            bvalid[j] = !(R == 3 && (xx < 0 || xx > 127));
            brow[j] = brow_base + (size_t)(bvalid[j] ? xx : 0) * Cin + kg;
        }
        #pragma unroll
        for (int ci0 = 0; ci0 < 512; ci0 += 32) {
            if (ci0 >= Cin) break;
            short8 af[4], bf[4];
            #pragma unroll
            for (int i = 0; i < 4; i++)
                af[i] = *(const short8*)&wrow[i][ci0];
            #pragma unroll
            for (int j = 0; j < 4; j++)
                bf[j] = bvalid[j] ? *(const short8*)&brow[j][ci0] : zero8;
            #pragma unroll
            for (int i = 0; i < 4; i++)
                #pragma unroll
                for (int j = 0; j < 4; j++)
                    acc[i][j] = __builtin_amdgcn_mfma_f32_16x16x32_bf16(
                        af[i], bf[j], acc[i][j], 0, 0, 0);
        }
    }

    int pBase = y << 7;
    int mr = (lane >> 4) << 2;
    #pragma unroll
    for (int i = 0; i < 4; i++) {
        int co0 = coBase + wm + i*16 + mr;
        #pragma unroll
        for (int j = 0; j < 4; j++) {
            int px = pBase + wn + j*16 + lr;
            float v[4];
            #pragma unroll
            for (int r = 0; r < 4; r++) {
                float vv = acc[i][j][r] + (bias ? bias[co0 + r] : 0.f);
                if (act == 1) vv = vv / (1.f + expf(-vv));
                if (res) vv += res[(((size_t)(res_b0 + lb) * Cout + co0 + r) << 14) + px];
                v[r] = vv;
            }
            if (out) {
                #pragma unroll
                for (int r = 0; r < 4; r++)
                    out[(((size_t)(out_b0 + lb) * Cout + co0 + r) << 14) + px] = v[r];
            }
            if (out_t) {
                short4v s4 = { f2bf(v[0]), f2bf(v[1]), f2bf(v[2]), f2bf(v[3]) };
                *(short4v*)&out_t[((size_t)(lb*16384 + px)) * Cout + co0] = s4;
            }
        }
    }
}

// ---------------------------------------------------------------------------
extern "C" void kernel_launch(void* const* d_in, const int* in_sizes, int n_in,
                              void* d_out, int out_size, void* d_ws, size_t ws_size,
                              hipStream_t stream) {
    (void)in_sizes; (void)n_in; (void)out_size;
    const float* x    = (const float*)d_in[0];
    const float* gn_w = (const float*)d_in[1];
    const float* gn_b = (const float*)d_in[2];
    const float* dw_w = (const float*)d_in[3];
    const float* pw_w = (const float*)d_in[4];
    const float* pw_b = (const float*)d_in[5];
    const float* ao_w = (const float*)d_in[6];
    const float* ao_b = (const float*)d_in[7];
    const float* f1_w = (const float*)d_in[8];
    const float* f2_w = (const float*)d_in[9];
    const float* f3_w = (const float*)d_in[10];
    const float* f3_b = (const float*)d_in[11];
    float* outp = (float*)d_out;

    // per-batch region sizes in floats
    const size_t F_QKV  = 12582912;   // qkv; later abuf/h1t/h2t (bf16T)
    const size_t F_SLOT = 2129920;
    const size_t F_SPEC = 6 * F_SLOT;
    const size_t F_XN   = 4194304;
    const size_t F_E    = 4259840;    // max(dw; rre+rim)
    const size_t F_SIMP = 262144;     // invn / fp32 simpart
    const size_t F_TOT  = F_QKV + F_SPEC + F_XN + F_E + F_SIMP; // 34,078,720
    const size_t F_WB   = 1552384;    // bf16 weights + fp16 hi/lo tables

    int NB = 0;
    for (int cand : {8, 4, 2, 1}) {
        if (((size_t)cand * F_TOT + F_WB) * 4 <= ws_size) { NB = cand; break; }
    }
    if (NB == 0) return;

    float* wsf  = (float*)d_ws;
    float* qkv  = wsf;
    short* abuf = (short*)wsf;                           // [NB][16384][256]
    short* h1t  = (short*)(wsf + (size_t)NB * 2097152);  // [NB][16384][512]
    short* h2t  = (short*)(wsf + (size_t)NB * 6291456);  // [NB][16384][256]
    float* spec = wsf + (size_t)NB * F_QKV;
    size_t ss   = (size_t)NB * F_SLOT;
    float* tre  = spec + 2*ss;
    float* tim  = spec + 3*ss;
    float* spat = spec + 4*ss;
    float* xn   = spec + 6*ss;
    float* ebuf = xn + (size_t)NB * F_XN;
    float* dw   = ebuf;
    float* rre  = ebuf;
    float* rim  = ebuf + (size_t)NB * 2129920;
    float* simpf = ebuf + (size_t)NB * F_E;
    float* invn  = simpf;
    float* simp  = simpf;
    short* wb    = (short*)(wsf + (size_t)NB * F_TOT);
    short* wb_ao = wb;
    short* wb_f1 = wb + 65536;
    short* wb_f2 = wb + 1245184;
    short* wb_f3 = wb + 2424832;
    _Float16* wb_pw_hi = (_Float16*)(wb + 2490368);
    _Float16* wb_pw_lo = (_Float16*)(wb + 2686976);
    _Float16* wb_tw_hi = (_Float16*)(wb + 2883584);
    _Float16* wb_tw_lo = (_Float16*)(wb + 2904064);
    _Float16* wb_mi_hi = (_Float16*)(wb + 2924544);
    _Float16* wb_mi_lo = (_Float16*)(wb + 2990080);
    _Float16* wb_nr_hi = (_Float16*)(wb + 3055616);
    _Float16* wb_nr_lo = (_Float16*)(wb + 3080192);

    wcvt_kernel<<<256,  256, 0, stream>>>(ao_w, wb_ao, 256, 256, 1);
    wcvt_kernel<<<4608, 256, 0, stream>>>(f1_w, wb_f1, 512, 256, 9);
    wcvt_kernel<<<4608, 256, 0, stream>>>(f2_w, wb_f2, 256, 512, 9);
    wcvt_kernel<<<256,  256, 0, stream>>>(f3_w, wb_f3, 256, 256, 1);
    wcvtpw_kernel<<<768, 256, 0, stream>>>(pw_w, wb_pw_hi, wb_pw_lo, 196608);
    twcvt_kernel<<<80, 256, 0, stream>>>(wb_tw_hi, wb_tw_lo);
    micvt_kernel<<<256, 256, 0, stream>>>(wb_mi_hi, wb_mi_lo);
    nrcvt_kernel<<<96, 256, 0, stream>>>(wb_nr_hi, wb_nr_lo);

    const int passes = 8 / NB;
    for (int p = 0; p < passes; p++) {
        int b0 = p * NB;
        // 1. GroupNorm -> xn
        groupnorm_kernel<<<NB*32, 256, 0, stream>>>(x, gn_w, gn_b, xn, b0);
        // 2. depthwise 3x3 (LDS halo): xn -> dw
        dwconv_kernel<<<NB*256*64, 256, 0, stream>>>(xn, dw_w, dw);
        // 3. pointwise 256->768 (+bias): fp16x2 split MFMA -> qkv
        convpw_kernel<<<dim3(128, 6, NB), 256, 0, stream>>>(
            dw, wb_pw_hi, wb_pw_lo, pw_b, qkv);
        // 4. inverse L2 norms (applied inside fftrow_mfma)
        l2inv_kernel<<<NB*3*64, 256, 0, stream>>>(qkv, invn);
        // 5. rfft2 -> amp/phase spec slots, 3 chunks of NB*256 planes
        for (int chunk = 0; chunk < 3; chunk++) {
            fftrow_mfma_kernel<<<NB*256, 256, 0, stream>>>(
                qkv, invn, wb_tw_hi, wb_tw_lo, rre, rim, chunk*NB*256);
            fft_col_kernel<<<dim3(5, NB*256), 256, 0, stream>>>(
                rre, rim, spec, chunk*NB*256, ss);
        }
        // 6. channel attention (split-K, fp32)
        attn_sim_kernel<<<dim3(16, NB*8), 256, 0, stream>>>(spec + 0*ss, spec + 2*ss, simp);
        attn_out_kernel<<<dim3(33, NB*8), 256, 0, stream>>>(simp, spec + 4*ss, spec + 0*ss);
        attn_sim_kernel<<<dim3(16, NB*8), 256, 0, stream>>>(spec + 1*ss, spec + 3*ss, simp);
        attn_out_kernel<<<dim3(33, NB*8), 256, 0, stream>>>(simp, spec + 5*ss, spec + 1*ss);
        // 7. irfft2: slots 0,1 -> tre/tim (MFMA) -> spat (MFMA)
        ifftcol_mfma_kernel<<<NB*256, 256, 0, stream>>>(
            spec + 0*ss, spec + 1*ss, wb_mi_hi, wb_mi_lo, tre, tim);
        ifftrow_mfma_kernel<<<NB*256, 256, 0, stream>>>(
            tre, tim, wb_nr_hi, wb_nr_lo, spat);
        // 8. ao 1x1 (+bias) + xn residual -> d_out fp32 + abuf bf16T
        convmf2_kernel<<<dim3(128, 2, NB), 256, 0, stream>>>(
            spat, wb_ao, ao_b, xn, outp, abuf, 256, 256, 0, 0, 0, b0);
        // 9. f1 3x3 256->512 + SiLU: abuf -> h1t (bf16T only)   [direct-load]
        convmf3_kernel<3><<<dim3(128, 4, NB), 256, 0, stream>>>(
            abuf, wb_f1, nullptr, nullptr, nullptr, h1t, 256, 512, 1, 0, 0);
        // 10. f2 3x3 512->256: h1t -> h2t                        [direct-load]
        convmf3_kernel<3><<<dim3(128, 2, NB), 256, 0, stream>>>(
            h1t, wb_f2, nullptr, nullptr, nullptr, h2t, 512, 256, 0, 0, 0);
        // 11. f3 1x1 (+bias) + attn residual -> d_out fp32       [direct-load]
        convmf3_kernel<1><<<dim3(128, 2, NB), 256, 0, stream>>>(
            h2t, wb_f3, f3_b, outp, outp, nullptr, 256, 256, 0, b0, b0);
    }
}